// Round 11
// baseline (1711.558 us; speedup 1.0000x reference)
//
#include <hip/hip_runtime.h>
#include <hip/hip_fp16.h>
#include <cfloat>
#include <cstdint>

// Problem constants
#define BB      16      // batch
#define TT      512     // seq
#define DD      512     // d_model
#define HH      8       // heads
#define DHH     64      // head dim
#define FFD     2048    // ff dim
#define BHH     128     // BB*HH
#define NHASH   4
#define NCHUNK  8       // NHASH * N_BUCKETS
#define CHUNKSZ 256
#define NLAYER  4

typedef unsigned short u16;
typedef unsigned int   u32;
typedef __attribute__((ext_vector_type(8))) short bfrag;    // 8 bf16 (4 VGPR)
typedef __attribute__((ext_vector_type(4))) float f4x;      // 4 f32 acc
typedef __attribute__((ext_vector_type(16))) float f16x;    // 16 f32 acc

union FragU { u32 u[4]; uint4 v4; bfrag f; };

__device__ __forceinline__ unsigned pk_bf16(float a, float b) {
    union { float f; unsigned u; } x, y;
    x.f = a; y.f = b;
    unsigned lo = ((x.u + 0x7FFFu + ((x.u >> 16) & 1u)) >> 16) & 0xFFFFu;
    unsigned hi = (y.u + 0x7FFFu + ((y.u >> 16) & 1u)) & 0xFFFF0000u;
    return lo | hi;
}
// HW packed f32->bf16 RTNE (1 VALU op; no builtin on gfx950)
__device__ __forceinline__ unsigned cvt_pk(float a, float b) {
    unsigned r;
    asm("v_cvt_pk_bf16_f32 %0, %1, %2" : "=v"(r) : "v"(a), "v"(b));
    return r;
}
// HW packed f32->f16 (RTZ) — o_hash precision (10-bit mantissa)
__device__ __forceinline__ unsigned pkrtz(float a, float b) {
    unsigned r;
    asm("v_cvt_pkrtz_f16_f32 %0, %1, %2" : "=v"(r) : "v"(a), "v"(b));
    return r;
}
__device__ __forceinline__ u16 bf16_1(float a) {
    union { float f; unsigned u; } x; x.f = a;
    return (u16)((x.u + 0x7FFFu + ((x.u >> 16) & 1u)) >> 16);
}
__device__ __forceinline__ float b2f(u16 h) {
    union { unsigned u; float f; } x; x.u = ((unsigned)h) << 16; return x.f;
}

// async global->LDS, 16B per lane (dest must be linear: base + lane*16)
__device__ __forceinline__ void gload16(const u16* g, u16* l) {
    __builtin_amdgcn_global_load_lds(
        (const __attribute__((address_space(1))) u32*)g,
        (__attribute__((address_space(3))) u32*)l, 16, 0, 0);
}

// ---------------------------------------------------------------------------
// Embedding: h = x @ emb_w + emb_b + pos ; write to both x1 and x2
__global__ __launch_bounds__(256)
void embed_kernel(const float* __restrict__ x, const float* __restrict__ ew,
                  const float* __restrict__ eb, const float* __restrict__ pos,
                  float* __restrict__ x1, float* __restrict__ x2)
{
    const int row = blockIdx.x;          // b*T + t
    const int t = row & (TT - 1);
    __shared__ float xr[32];
    if (threadIdx.x < 32) xr[threadIdx.x] = x[row * 32 + threadIdx.x];
    __syncthreads();
    for (int d = threadIdx.x; d < DD; d += 256) {
        float s = eb[d] + pos[t * DD + d];
        #pragma unroll
        for (int k = 0; k < 32; ++k) s = fmaf(xr[k], ew[k * DD + d], s);
        x1[(size_t)row * DD + d] = s;
        x2[(size_t)row * DD + d] = s;
    }
}

// ---------------------------------------------------------------------------
// LayerNorm over last dim (512); writes bf16 (always) and f32 (if out!=null).
__global__ __launch_bounds__(256)
void ln_kernel(const float* __restrict__ in, const float* __restrict__ g,
               const float* __restrict__ bta, float* __restrict__ out,
               u16* __restrict__ outh)
{
    const int row = blockIdx.x * 4 + (threadIdx.x >> 6);
    const int lane = threadIdx.x & 63;
    const float* r = in + (size_t)row * DD;
    float vals[8];
    float s = 0.0f;
    #pragma unroll
    for (int i = 0; i < 8; ++i) { vals[i] = r[i * 64 + lane]; s += vals[i]; }
    #pragma unroll
    for (int o = 1; o < 64; o <<= 1) s += __shfl_xor(s, o);
    const float mean = s * (1.0f / 512.0f);
    float vs = 0.0f;
    #pragma unroll
    for (int i = 0; i < 8; ++i) { float d = vals[i] - mean; vs += d * d; }
    #pragma unroll
    for (int o = 1; o < 64; o <<= 1) vs += __shfl_xor(vs, o);
    const float rstd = rsqrtf(vs * (1.0f / 512.0f) + 1e-5f);
    u16* hrow = outh + (size_t)row * DD;
    #pragma unroll
    for (int i = 0; i < 8; ++i) {
        const int d = i * 64 + lane;
        const float y = (vals[i] - mean) * rstd * g[d] + bta[d];
        if (out != nullptr) out[(size_t)row * DD + d] = y;
        hrow[d] = bf16_1(y);
    }
}

// ---------------------------------------------------------------------------
// Batched weight prep: transpose+bf16 ALL layers in ONE dispatch.
// wqk+wv go into a CONCATENATED wqkvT [1024][512] per layer.
__global__ __launch_bounds__(256)
void prep_weights(const float* __restrict__ wqk, const float* __restrict__ wv,
                  const float* __restrict__ wo, const float* __restrict__ ffw1,
                  const float* __restrict__ ffw2,
                  u16* __restrict__ wqkvT, u16* __restrict__ woT,
                  u16* __restrict__ w1T, u16* __restrict__ w2T)
{
    const int id = blockIdx.x;
    const float* in; u16* outp; int K, N, kt, nt;
    if (id < 3072) {                       // wqk / wv / wo : 512x512, 256 tiles/L
        const int fam = id >> 10;
        const int r = id & 1023;
        const int L = r >> 8, t = r & 255;
        K = 512; N = 512;
        const size_t off = (size_t)L * 512 * 512;
        in = (fam == 0 ? wqk : fam == 1 ? wv : wo) + off;
        outp = (fam == 2) ? (woT + off)
                          : (wqkvT + (size_t)L * 1024 * 512 + (fam == 1 ? (size_t)512 * 512 : 0));
        kt = (t & 15) << 5; nt = (t >> 4) << 5;
    } else if (id < 7168) {                // ff1: 512x2048, 1024 tiles/L
        const int r = id - 3072;
        const int L = r >> 10, t = r & 1023;
        K = 512; N = 2048;
        in = ffw1 + (size_t)L * 512 * 2048;
        outp = w1T + (size_t)L * 2048 * 512;
        kt = (t & 15) << 5; nt = (t >> 4) << 5;
    } else {                               // ff2: 2048x512, 1024 tiles/L
        const int r = id - 7168;
        const int L = r >> 10, t = r & 1023;
        K = 2048; N = 512;
        in = ffw2 + (size_t)L * 2048 * 512;
        outp = w2T + (size_t)L * 512 * 2048;
        kt = (t & 63) << 5; nt = (t >> 6) << 5;
    }
    __shared__ float tile[32][33];
    const int rr = threadIdx.x >> 3, c4 = (threadIdx.x & 7) * 4;
    const float4 v4 = *(const float4*)(in + (size_t)(kt + rr) * N + nt + c4);
    tile[rr][c4 + 0] = v4.x; tile[rr][c4 + 1] = v4.y;
    tile[rr][c4 + 2] = v4.z; tile[rr][c4 + 3] = v4.w;
    __syncthreads();
    uint2 p;
    p.x = pk_bf16(tile[c4 + 0][rr], tile[c4 + 1][rr]);
    p.y = pk_bf16(tile[c4 + 2][rr], tile[c4 + 3][rr]);
    *(uint2*)(outp + (size_t)(nt + rr) * K + kt + c4) = p;
}

// ---------------------------------------------------------------------------
// wrot[L][f][h*4+hash] = sum_d wqk[L][f][h*64+d] * rot[L][d][hash]
__global__ __launch_bounds__(256)
void wrot_kernel(const float* __restrict__ wqk, const float* __restrict__ rot,
                 float* __restrict__ wrotAll)
{
    const int hh = blockIdx.x, L = blockIdx.y;
    const int head = hh >> 2, h = hh & 3;
    __shared__ float rc[64];
    if (threadIdx.x < 64)
        rc[threadIdx.x] = rot[((size_t)L * 64 + threadIdx.x) * 4 + h];
    __syncthreads();
    for (int f = threadIdx.x; f < 512; f += 256) {
        const float* wrow = wqk + (size_t)L * 512 * 512 + (size_t)f * 512 + head * 64;
        float s = 0.0f;
        #pragma unroll
        for (int d = 0; d < 64; d += 4) {
            const float4 w4 = *(const float4*)(wrow + d);
            s += w4.x * rc[d] + w4.y * rc[d + 1] + w4.z * rc[d + 2] + w4.w * rc[d + 3];
        }
        wrotAll[((size_t)L * 512 + f) * 32 + hh] = s;
    }
}

// ---------------------------------------------------------------------------
// rotated[8192][32] = xn[8192][512] @ wrot[512][32], all f32. grid 128.
__global__ __launch_bounds__(256)
void rot_gemm(const float* __restrict__ A, const float* __restrict__ Wr,
              float* __restrict__ C)
{
    __shared__ float As[64][36];
    __shared__ float Ws[32][36];
    const int m0 = blockIdx.x * 64;
    const int r = threadIdx.x >> 2, cg = threadIdx.x & 3;
    float acc[8] = {};
    for (int f0 = 0; f0 < 512; f0 += 32) {
        __syncthreads();
        {
            const int lr = threadIdx.x >> 2, lc = (threadIdx.x & 3) * 8;
            const float* ap = A + (size_t)(m0 + lr) * 512 + f0 + lc;
            *(float4*)&As[lr][lc]     = ((const float4*)ap)[0];
            *(float4*)&As[lr][lc + 4] = ((const float4*)ap)[1];
            const int wr = threadIdx.x >> 3, wc = (threadIdx.x & 7) * 4;
            *(float4*)&Ws[wr][wc] = *(const float4*)(Wr + (size_t)(f0 + wr) * 32 + wc);
        }
        __syncthreads();
        #pragma unroll
        for (int kk = 0; kk < 32; ++kk) {
            const float a = As[r][kk];
            #pragma unroll
            for (int c = 0; c < 8; ++c)
                acc[c] = fmaf(a, Ws[kk][cg * 8 + c], acc[c]);
        }
    }
    float* crow = C + (size_t)(m0 + r) * 32 + cg * 8;
    *(float4*)crow       = make_float4(acc[0], acc[1], acc[2], acc[3]);
    *(float4*)(crow + 4) = make_float4(acc[4], acc[5], acc[6], acc[7]);
}

// ---------------------------------------------------------------------------
// bf16 MFMA GEMM, templated tile, double-buffered LDS, 2-phase pipeline.
// QKV: merged qk+v output — n0<512 routes to per-head qkh (Cb); n0>=512
// routes to row-major vbh (Cf reinterpreted as u16*).
__device__ __forceinline__ float gelu1(float v) {
    return 0.5f * v * (1.0f + erff(v * 0.70710678118654752440f));
}
__device__ __forceinline__ int swz_row(int r, int BK) {
    return (BK == 32) ? ((r & 3) ^ ((r >> 2) & 3)) : (r & 7);
}

template<int BM, int BN, int BK, bool GELU, bool ADD, bool BIAS, bool OUTBF, bool QKV>
__global__ __launch_bounds__(256)
void gemm_bf16(const u16* __restrict__ A, const u16* __restrict__ WT,
               const float* __restrict__ bias, const float* __restrict__ addsrc,
               float* __restrict__ Cf, u16* __restrict__ Cb,
               int M, int N, int K)
{
    constexpr int NCH = BK / 8;
    constexpr int CPA = BM * NCH / 256;
    constexpr int CPB = BN * NCH / 256;
    constexpr int MR = BM / 32, NR = BN / 32, KR = BK / 32;
    __shared__ __align__(16) u16 Abuf[2][BM * BK];
    __shared__ __align__(16) u16 Bbuf[2][BN * BK];
    const int tid = threadIdx.x;
    const int m0 = blockIdx.x * BM, n0 = blockIdx.y * BN;

    const u16* aSrc[CPA]; const u16* bSrc[CPB];
    #pragma unroll
    for (int i = 0; i < CPA; ++i) {
        const int s = tid + i * 256, row = s / NCH, ch = s % NCH;
        aSrc[i] = A + (size_t)(m0 + row) * K + (ch ^ swz_row(row, BK)) * 8;
    }
    #pragma unroll
    for (int i = 0; i < CPB; ++i) {
        const int s = tid + i * 256, row = s / NCH, ch = s % NCH;
        bSrc[i] = WT + (size_t)(n0 + row) * K + (ch ^ swz_row(row, BK)) * 8;
    }

    auto STAGE = [&](int bufi, int koff) {
        #pragma unroll
        for (int i = 0; i < CPA; ++i)
            gload16(aSrc[i] + koff, &Abuf[bufi][(tid + i * 256) * 8]);
        #pragma unroll
        for (int i = 0; i < CPB; ++i)
            gload16(bSrc[i] + koff, &Bbuf[bufi][(tid + i * 256) * 8]);
    };

    const int l = tid & 63, wv_ = tid >> 6;
    const int wm = (wv_ >> 1) * (BM / 2);
    const int wn = (wv_ & 1) * (BN / 2);
    const int fr = l & 15, fc = l >> 4;

    f4x acc[MR][NR] = {};
    const int nK = K / BK;
    STAGE(0, 0);
    for (int ks = 0; ks < nK; ++ks) {
        __syncthreads();
        if (ks + 1 < nK) STAGE((ks + 1) & 1, (ks + 1) * BK);
        const u16* Ab = Abuf[ks & 1];
        const u16* Bb = Bbuf[ks & 1];
        FragU af[MR][KR], bf_[NR][KR];
        #pragma unroll
        for (int i = 0; i < MR; ++i)
            #pragma unroll
            for (int u = 0; u < KR; ++u) {
                const int r = wm + i * 16 + fr;
                af[i][u].v4 = *(const uint4*)((const char*)Ab +
                    (size_t)r * (2 * BK) + (((u * 4 + fc) ^ swz_row(r, BK)) << 4));
            }
        #pragma unroll
        for (int j = 0; j < NR; ++j)
            #pragma unroll
            for (int u = 0; u < KR; ++u) {
                const int r = wn + j * 16 + fr;
                bf_[j][u].v4 = *(const uint4*)((const char*)Bb +
                    (size_t)r * (2 * BK) + (((u * 4 + fc) ^ swz_row(r, BK)) << 4));
            }
        #pragma unroll
        for (int u = 0; u < KR; ++u)
            #pragma unroll
            for (int i = 0; i < MR; ++i)
                #pragma unroll
                for (int j = 0; j < NR; ++j)
                    acc[i][j] = __builtin_amdgcn_mfma_f32_16x16x32_bf16(
                        af[i][u].f, bf_[j][u].f, acc[i][j], 0, 0, 0);
    }

    #pragma unroll
    for (int i = 0; i < MR; ++i) {
        #pragma unroll
        for (int q = 0; q < 4; ++q) {
            const int row = m0 + wm + i * 16 + fc * 4 + q;
            #pragma unroll
            for (int j = 0; j < NR; ++j) {
                const int col = n0 + wn + j * 16 + fr;
                float vx = acc[i][j][q];
                if constexpr (BIAS) vx += bias[col];
                if constexpr (GELU) vx = gelu1(vx);
                if constexpr (ADD) vx += addsrc[(size_t)row * N + col];
                if constexpr (QKV) {
                    if (n0 < 512) {   // qk half -> per-head layout [(b*8+h)][t][d]
                        const int bq = row >> 9, tq = row & 511;
                        const int hq = col >> 6, dq = col & 63;
                        Cb[(((size_t)(bq * 8 + hq) * 512) + tq) * 64 + dq] = bf16_1(vx);
                    } else {          // v half -> row-major [row][512]
                        ((u16*)Cf)[(size_t)row * 512 + (col - 512)] = bf16_1(vx);
                    }
                } else if constexpr (OUTBF) {
                    Cb[(size_t)row * N + col] = bf16_1(vx);
                } else {
                    Cf[(size_t)row * N + col] = vx;
                }
            }
        }
    }
}

// ---------------------------------------------------------------------------
// K/Q pre-normalization from bf16 qkh: qkn = bf16(row/|row|), qnrm = |row|.
// Also serves as an L2 pre-warm of qkn/qnrm right before the gather-heavy
// attention kernel (R9 lesson: removing this cost attn +17 us/dispatch).
__global__ __launch_bounds__(256)
void knorm_kernel(const u16* __restrict__ qkh, u16* __restrict__ qkn,
                  float* __restrict__ qnrm)
{
    const int g = blockIdx.x * 16 + (threadIdx.x >> 4);  // bh*T + t
    const int li = threadIdx.x & 15;
    const uint2 raw = *(const uint2*)(qkh + (size_t)g * 64 + li * 4);
    const float v0 = b2f((u16)(raw.x & 0xffff)), v1 = b2f((u16)(raw.x >> 16));
    const float v2 = b2f((u16)(raw.y & 0xffff)), v3 = b2f((u16)(raw.y >> 16));
    float ss = v0 * v0 + v1 * v1 + v2 * v2 + v3 * v3;
    ss += __shfl_xor(ss, 1); ss += __shfl_xor(ss, 2);
    ss += __shfl_xor(ss, 4); ss += __shfl_xor(ss, 8);
    const float qn = sqrtf(ss);
    const float rv = 1.0f / fmaxf(qn, 1e-12f);
    uint2 o;
    o.x = cvt_pk(v0 * rv, v1 * rv);
    o.y = cvt_pk(v2 * rv, v3 * rv);
    *(uint2*)(qkn + (size_t)g * 64 + li * 4) = o;
    if (li == 0) qnrm[g] = qn;
}

// ---------------------------------------------------------------------------
// Bucket assignment + stable partition from precomputed rotated (f32)
__global__ __launch_bounds__(512)
void bucket_sort_kernel(const float* __restrict__ rotated, int* __restrict__ st)
{
    const int h = blockIdx.x, bh = blockIdx.y;
    const int b = bh >> 3, head = bh & 7;
    const int t = threadIdx.x;
    __shared__ int zcnt[8];
    const float r = rotated[((size_t)(b * TT + t)) * 32 + head * 4 + h];
    const int bit = (r < 0.0f) ? 1 : 0;
    const int wid = t >> 6, lane = t & 63;
    const unsigned long long zm = __ballot(bit == 0);
    if (lane == 0) zcnt[wid] = __popcll(zm);
    __syncthreads();
    int zoff = 0, Z = 0;
    #pragma unroll
    for (int w = 0; w < 8; ++w) { const int cn = zcnt[w]; if (w < wid) zoff += cn; Z += cn; }
    const int zpre = __popcll(zm & ((1ull << lane) - 1ull));
    const int dst = (bit == 0) ? (zoff + zpre)
                               : (Z + (wid * 64 - zoff) + (lane - zpre));
    st[((size_t)bh * NHASH + h) * TT + dst] = t;
}

// ---------------------------------------------------------------------------
// MFMA LSH attention — 8 waves x 32 queries, double-buffered LDS (1 barrier
// per tile), bit-reversed V^T slot rotation, setprio around MFMA clusters.
__global__ __launch_bounds__(512, 4)
void lsh_attn_mfma(const u16* __restrict__ qkn, const u16* __restrict__ v,
                   const float* __restrict__ qnrm, const int* __restrict__ st,
                   __half* __restrict__ o_hash, float* __restrict__ lse_hash)
{
    const int cc = blockIdx.x, bh = blockIdx.y;
    const int b = bh >> 3, head = bh & 7;
    const int h = cc >> 1, c = cc & 1;
    const int pcc = (cc + 7) & 7;
    const int hp = pcc >> 1, cp = pcc & 1;
    const int tid = threadIdx.x;
    const int w = tid >> 6;          // wave 0..7 -> queries w*32..+32
    const int lane = tid & 63;
    const int l31 = lane & 31;
    const int hi = lane >> 5;
    const int* stb = st + (size_t)bh * (NHASH * TT);
    const size_t vbase = ((size_t)b * TT) * DD + head * DHH;
    const u16* qknb = qkn + (size_t)bh * TT * DHH;

    __shared__ __align__(16) u16 Kbf[2][64 * 64];
    __shared__ __align__(16) u16 VTbf[2][64 * 64];
    __shared__ __align__(16) int ktl[2][64];

    // ---- Q fragment (one query per lane-column) ----
    const int q_t = stb[h * TT + c * CHUNKSZ + w * 32 + l31];
    const float qn = qnrm[(size_t)bh * TT + q_t];
    const float mnat = qn * 0.125f;
    const float aC = qn * 0.1803368801111137f;   // |q| * 0.125 * log2(e)
    uint4 QF4[4];
    {
        const u16* qrow = qknb + (size_t)q_t * DHH;
        #pragma unroll
        for (int ds = 0; ds < 4; ++ds)
            QF4[ds] = *(const uint4*)(qrow + ds * 16 + hi * 8);
    }

    f16x acc[2] = {};           // [dt] O^T tiles (32d x 32q)
    float lac0 = 0.f, lac1 = 0.f;
    const int k8 = tid >> 3;    // key row 0..63 (8 lanes per 128B row)
    const int c8 = tid & 7;     // 16B chunk of the row
    // bit-reversed slot bases (constant per thread)
    const int brc = ((c8 & 1) << 2) | (c8 & 2) | ((c8 & 4) >> 2);   // bitrev3(c8)
    const int wSlot = ((k8 >> 3) + brc) & 7;                        // V write slot
    const int g2 = l31 >> 3;                                        // read row group
    const int brg = ((g2 & 1) << 2) | (g2 & 2);                     // bitrev3(g2), g2<4

    auto gather = [&](int t8, uint4& kc, uint4& vc, int& ktc) {
        const int kj = t8 * 64 + k8;
        const int k_t = (kj < CHUNKSZ) ? stb[h * TT + c * CHUNKSZ + kj]
                                       : stb[hp * TT + cp * CHUNKSZ + (kj - CHUNKSZ)];
        ktc = k_t;
        kc = *(const uint4*)(qknb + (size_t)k_t * DHH + c8 * 8);
        vc = *(const uint4*)(v + vbase + (size_t)k_t * DD + c8 * 8);
    };
    auto writeTile = [&](int bi, const uint4& kc, const uint4& vc, int ktc) {
        *(uint4*)((char*)Kbf[bi] + ((k8 * 128 + c8 * 16) ^ ((k8 & 7) << 4))) = kc;
        const unsigned vu[4] = {vc.x, vc.y, vc.z, vc.w};
        #pragma unroll
        for (int i = 0; i < 8; ++i) {
            const int d = c8 * 8 + i;
            const u16 hv = (u16)((i & 1) ? (vu[i >> 1] >> 16) : (vu[i >> 1] & 0xffff));
            *(u16*)((char*)VTbf[bi] + d * 128 + wSlot * 16 + (k8 & 7) * 2) = hv;
        }
        if (c8 == 0) ktl[bi][k8] = ktc;
    };

    uint4 kc, vc; int ktc;
    gather(0, kc, vc, ktc);
    writeTile(0, kc, vc, ktc);
    __syncthreads();

    for (int kt8 = 0; kt8 < 8; ++kt8) {
        const int cur = kt8 & 1;
        if (kt8 < 7) gather(kt8 + 1, kc, vc, ktc);
        const u16* Kb = Kbf[cur];
        const u16* Vb = VTbf[cur];
        const int* kl = ktl[cur];

        #pragma unroll
        for (int kt = 0; kt < 2; ++kt) {
            int4 kt4[4];
            #pragma unroll
            for (int j = 0; j < 4; ++j)
                kt4[j] = *(const int4*)&kl[kt * 32 + 8 * j + 4 * hi];
            const int* ktvp = (const int*)kt4;
            FragU KA[4];
            #pragma unroll
            for (int ds = 0; ds < 4; ++ds) {
                const int row = kt * 32 + l31;
                KA[ds].v4 = *(const uint4*)((const char*)Kb +
                    ((row * 128 + ds * 32 + hi * 16) ^ ((row & 7) << 4)));
            }
            FragU VA[2][2];
            #pragma unroll
            for (int dt = 0; dt < 2; ++dt)
                #pragma unroll
                for (int u = 0; u < 2; ++u) {
                    const int row = dt * 32 + l31;
                    const int cr = (kt * 2 + u) * 2 + hi;
                    const int slot = (cr + brg + dt) & 7;    // bitrev3(row>>3)=brg+dt
                    VA[dt][u].v4 = *(const uint4*)((const char*)Vb +
                        row * 128 + slot * 16);
                }
            f16x s = {0.f,0.f,0.f,0.f,0.f,0.f,0.f,0.f,
                      0.f,0.f,0.f,0.f,0.f,0.f,0.f,0.f};
            __builtin_amdgcn_s_setprio(1);
            #pragma unroll
            for (int ds = 0; ds < 4; ++ds) {
                FragU qf; qf.v4 = QF4[ds];
                s = __builtin_amdgcn_mfma_f32_32x32x16_bf16(KA[ds].f, qf.f, s, 0, 0, 0);
            }
            __builtin_amdgcn_s_setprio(0);
            float pv[16];
            #pragma unroll
            for (int i = 0; i < 16; i += 2) {
                const float e0 = exp2f(fmaf(s[i],     aC, -aC));
                const float e1 = exp2f(fmaf(s[i + 1], aC, -aC));
                const float p0 = (q_t > ktvp[i])     ? e0 : 0.0f;
                const float p1 = (q_t > ktvp[i + 1]) ? e1 : 0.0f;
                pv[i] = p0; pv[i + 1] = p1;
                lac0 += p0; lac1 += p1;
            }
            unsigned P2[8];
            #pragma unroll
            for (int g = 0; g < 4; ++g) {
                P2[2*g]   = cvt_pk(pv[4*g],   pv[4*g+1]);
                P2[2*g+1] = cvt_pk(pv[4*g+2], pv[4*g+3]);
            }
            #pragma unroll
            for (int u = 0; u < 2; ++u) {
                unsigned a0 = P2[4*u + 0], b0 = P2[4*u + 2];
                unsigned a1 = P2[4*u + 1], b1 = P2[4*u + 3];
                asm("v_permlane32_swap_b32 %0, %1" : "+v"(a0), "+v"(b0));
                asm("v_permlane32_swap_b32 %0, %1" : "+v"(a1), "+v"(b1));
                FragU bfv;
                bfv.u[0] = a0; bfv.u[1] = a1; bfv.u[2] = b0; bfv.u[3] = b1;
                __builtin_amdgcn_s_setprio(1);
                #pragma unroll
                for (int dt = 0; dt < 2; ++dt)
                    acc[dt] = __builtin_amdgcn_mfma_f32_32x32x16_bf16(
                        VA[dt][u].f, bfv.f, acc[dt], 0, 0, 0);
                __builtin_amdgcn_s_setprio(0);
            }
        }

        if (kt8 < 7) {
            writeTile(cur ^ 1, kc, vc, ktc);
            __syncthreads();
        }
    }

    // ---- finalize: l, lse, register-only epilogue ----
    const float lts = lac0 + lac1;
    const float lt = lts + __shfl_xor(lts, 32);
    const float invl = (lt > 0.f) ? 1.0f / lt : 0.0f;
    if (hi == 0) {
        const float lse = (lt > 0.f) ? (mnat + logf(lt)) : -5.0e4f;
        lse_hash[(size_t)(bh * NHASH + h) * TT + q_t] = lse;
    }
    unsigned wa[8], wb[8];
    #pragma unroll
    for (int m = 0; m < 8; ++m) {
        wa[m] = pkrtz(acc[0][2*m] * invl, acc[0][2*m+1] * invl);
        wb[m] = pkrtz(acc[1][2*m] * invl, acc[1][2*m+1] * invl);
    }
    #pragma unroll
    for (int m = 0; m < 8; ++m)
        asm("v_permlane32_swap_b32 %0, %1" : "+v"(wa[m]), "+v"(wb[m]));
    __half* orow = o_hash + ((size_t)(bh * NHASH + h) * TT + q_t) * DHH + hi * 32;
    if (lt > 0.f) {
        #pragma unroll
        for (int g = 0; g < 4; ++g) {
            uint4 o;
            o.x = wa[2*g]; o.y = wa[2*g+1];
            o.z = wb[2*g]; o.w = wb[2*g+1];
            ((uint4*)orow)[g] = o;
        }
    } else {
        const u16* vr = v + vbase + (size_t)q_t * DD + hi * 32;
        #pragma unroll
        for (int g = 0; g < 4; ++g) {
            uint4 o;
            o.x = pkrtz(b2f(vr[8*g+0]), b2f(vr[8*g+1]));
            o.y = pkrtz(b2f(vr[8*g+2]), b2f(vr[8*g+3]));
            o.z = pkrtz(b2f(vr[8*g+4]), b2f(vr[8*g+5]));
            o.w = pkrtz(b2f(vr[8*g+6]), b2f(vr[8*g+7]));
            ((uint4*)orow)[g] = o;
        }
    }
}

// ---------------------------------------------------------------------------
// Combine hash rounds: read o_hash f16, write merged bf16 (wo GEMM A-operand)
__global__ __launch_bounds__(256)
void combine_kernel(const __half* __restrict__ o_hash, const float* __restrict__ lse_hash,
                    u16* __restrict__ am)
{
    const int idx = blockIdx.x * 4 + (threadIdx.x >> 6);
    const int lane = threadIdx.x & 63;
    const int bh = idx >> 9, t = idx & 511;
    const int b = bh >> 3, head = bh & 7;
    const float ls0 = lse_hash[(size_t)(bh * NHASH + 0) * TT + t];
    const float ls1 = lse_hash[(size_t)(bh * NHASH + 1) * TT + t];
    const float ls2 = lse_hash[(size_t)(bh * NHASH + 2) * TT + t];
    const float ls3 = lse_hash[(size_t)(bh * NHASH + 3) * TT + t];
    const float M = fmaxf(fmaxf(ls0, ls1), fmaxf(ls2, ls3));
    const float e0 = __expf(ls0 - M), e1 = __expf(ls1 - M);
    const float e2 = __expf(ls2 - M), e3 = __expf(ls3 - M);
    const float inv = 1.0f / (e0 + e1 + e2 + e3);
    const float o =
        (e0 * __half2float(o_hash[((size_t)((bh * NHASH + 0) * TT + t)) * DHH + lane]) +
         e1 * __half2float(o_hash[((size_t)((bh * NHASH + 1) * TT + t)) * DHH + lane]) +
         e2 * __half2float(o_hash[((size_t)((bh * NHASH + 2) * TT + t)) * DHH + lane]) +
         e3 * __half2float(o_hash[((size_t)((bh * NHASH + 3) * TT + t)) * DHH + lane])) * inv;
    am[((size_t)(b * TT + t)) * DD + head * DHH + lane] = bf16_1(o);
}

// ---------------------------------------------------------------------------
// Final head
__device__ __forceinline__ float block_sum256(float v, volatile float* red)
{
    const int lane = threadIdx.x & 63, wid = threadIdx.x >> 6;
    #pragma unroll
    for (int o = 1; o < 64; o <<= 1) v += __shfl_xor(v, o);
    __syncthreads();
    if (lane == 0) red[wid] = v;
    __syncthreads();
    return red[0] + red[1] + red[2] + red[3];
}

__global__ __launch_bounds__(256)
void head_kernel(const float* __restrict__ x1, const float* __restrict__ x2,
                 const float* __restrict__ lnfg, const float* __restrict__ lnfb,
                 const float* __restrict__ hw1, const float* __restrict__ hb1,
                 const float* __restrict__ hlng, const float* __restrict__ hlnb,
                 const float* __restrict__ hw2, const float* __restrict__ hb2,
                 float* __restrict__ out)
{
    __shared__ float nrow[512];
    __shared__ float red[4];
    const int b = blockIdx.x, tid = threadIdx.x;
    const size_t roff = ((size_t)b * TT + (TT - 1)) * DD;
    const float v0 = 0.5f * (x1[roff + tid] + x2[roff + tid]);
    const float v1 = 0.5f * (x1[roff + 256 + tid] + x2[roff + 256 + tid]);
    const float mean = block_sum256(v0 + v1, red) * (1.0f / 512.0f);
    const float d0 = v0 - mean, d1 = v1 - mean;
    const float var = block_sum256(d0 * d0 + d1 * d1, red) * (1.0f / 512.0f);
    const float rstd = rsqrtf(var + 1e-5f);
    nrow[tid]       = d0 * rstd * lnfg[tid] + lnfb[tid];
    nrow[tid + 256] = d1 * rstd * lnfg[tid + 256] + lnfb[tid + 256];
    __syncthreads();
    float a = hb1[tid];
    for (int k = 0; k < 512; ++k) a = fmaf(nrow[k], hw1[(size_t)k * 256 + tid], a);
    const float m2 = block_sum256(a, red) * (1.0f / 256.0f);
    const float dd = a - m2;
    const float var2 = block_sum256(dd * dd, red) * (1.0f / 256.0f);
    float y = dd * rsqrtf(var2 + 1e-5f) * hlng[tid] + hlnb[tid];
    y = fmaxf(y, 0.0f);
    const float osum = block_sum256(y * hw2[tid], red);
    if (tid == 0) out[b] = osum + hb2[0];
}

// ---------------------------------------------------------------------------
extern "C" void kernel_launch(void* const* d_in, const int* in_sizes, int n_in,
                              void* d_out, int out_size, void* d_ws, size_t ws_size,
                              hipStream_t stream)
{
    (void)in_sizes; (void)n_in; (void)out_size; (void)ws_size;
    const float* x    = (const float*)d_in[0];
    const float* embw = (const float*)d_in[1];
    const float* embb = (const float*)d_in[2];
    const float* pos  = (const float*)d_in[3];
    const float* ln1g = (const float*)d_in[4];
    const float* ln1b = (const float*)d_in[5];
    const float* wqk  = (const float*)d_in[6];
    const float* wv   = (const float*)d_in[7];
    const float* wo   = (const float*)d_in[8];
    const float* wob  = (const float*)d_in[9];
    const float* ln2g = (const float*)d_in[10];
    const float* ln2b = (const float*)d_in[11];
    const float* ffw1 = (const float*)d_in[12];
    const float* ffb1 = (const float*)d_in[13];
    const float* ffw2 = (const float*)d_in[14];
    const float* ffb2 = (const float*)d_in[15];
    const float* rot  = (const float*)d_in[16];
    const float* lnfg = (const float*)d_in[17];
    const float* lnfb = (const float*)d_in[18];
    const float* hw1  = (const float*)d_in[19];
    const float* hb1  = (const float*)d_in[20];
    const float* hlng = (const float*)d_in[21];
    const float* hlnb = (const float*)d_in[22];
    const float* hw2  = (const float*)d_in[23];
    const float* hb2  = (const float*)d_in[24];
    float* out = (float*)d_out;

    const size_t SZ_BTD = (size_t)BB * TT * DD;            // 4,194,304
    const size_t SZ_OH  = (size_t)BHH * NHASH * TT * DHH;  // 16,777,216

    char* p = (char*)d_ws;
    float* x1b = (float*)p;  p += SZ_BTD * 4;
    float* x2b = (float*)p;  p += SZ_BTD * 4;
    float* xnb = (float*)p;  p += SZ_BTD * 4;              // also amb (bf16) late
    u16*   vbh = (u16*)p;    p += SZ_BTD * 2;
    u16*   xnbh = (u16*)p;   p += SZ_BTD * 2;
    u16*   qkh  = (u16*)p;   p += SZ_BTD * 2;              // bf16 qk, per-head layout
    u16*   qknb = (u16*)p;   p += (size_t)BHH * TT * DHH * 2;
    float* qnrm = (float*)p; p += (size_t)BHH * TT * 4;
    float* rotated = (float*)p; p += (size_t)BB * TT * 32 * 4;
    __half* ohash = (__half*)p;                  // 33.5MB region
    u16*    ffmid = (u16*)p;                     // temporal alias (disjoint life)
    p += SZ_OH * 2;
    float* lseb  = (float*)p; p += (size_t)BHH * NHASH * TT * 4;
    int*   stb   = (int*)p;   p += (size_t)BHH * NHASH * TT * 4;
    u16* wqkvT = (u16*)p; p += (size_t)NLAYER * 1024 * 512 * 2;
    u16* woT   = (u16*)p; p += (size_t)NLAYER * DD * DD * 2;
    u16* w1T   = (u16*)p; p += (size_t)NLAYER * DD * FFD * 2;
    u16* w2T   = (u16*)p; p += (size_t)NLAYER * FFD * DD * 2;
    float* wrotAll = (float*)p; p += (size_t)NLAYER * DD * 32 * 4;
    u16* amb = (u16*)xnb;                        // alias (xnb dead after GEMMs)

    // ---- one-time weight prep (all layers) ----
    prep_weights<<<11264, 256, 0, stream>>>(wqk, wv, wo, ffw1, ffw2,
                                            wqkvT, woT, w1T, w2T);
    wrot_kernel<<<dim3(32, NLAYER), 256, 0, stream>>>(wqk, rot, wrotAll);

    embed_kernel<<<BB * TT, 256, 0, stream>>>(x, embw, embb, pos, x1b, x2b);

    for (int L = 0; L < NLAYER; ++L) {
        const size_t w512 = (size_t)L * DD * DD;
        const size_t wff  = (size_t)L * DD * FFD;

        // x1 += attn(ln(x2))
        ln_kernel<<<2048, 256, 0, stream>>>(x2b, ln1g + L * DD, ln1b + L * DD, xnb, xnbh);
        rot_gemm<<<128, 256, 0, stream>>>(xnb, wrotAll + (size_t)L * DD * 32, rotated);
        gemm_bf16<128, 128, 32, false, false, false, false, true><<<dim3(64, 8), 256, 0, stream>>>(
            xnbh, wqkvT + (size_t)L * 1024 * 512, nullptr, nullptr,
            (float*)vbh, qkh, BB * TT, 1024, DD);
        bucket_sort_kernel<<<dim3(NHASH, BHH), 512, 0, stream>>>(rotated, stb);
        knorm_kernel<<<4096, 256, 0, stream>>>(qkh, qknb, qnrm);
        lsh_attn_mfma<<<dim3(NCHUNK, BHH), 512, 0, stream>>>(
            qknb, vbh, qnrm, stb, ohash, lseb);
        combine_kernel<<<16384, 256, 0, stream>>>(ohash, lseb, amb);
        gemm_bf16<128, 64, 64, false, true, true, false, false><<<dim3(64, 8), 256, 0, stream>>>(
            amb, woT + w512, wob + L * DD, x1b, x1b, nullptr, BB * TT, DD, DD);

        // x2 += ff(ln(x1))
        ln_kernel<<<2048, 256, 0, stream>>>(x1b, ln2g + L * DD, ln2b + L * DD, nullptr, xnbh);
        gemm_bf16<128, 128, 32, true, false, true, true, false><<<dim3(64, 16), 256, 0, stream>>>(
            xnbh, w1T + wff, ffb1 + L * FFD, nullptr, nullptr, ffmid, BB * TT, FFD, DD);
        gemm_bf16<128, 64, 64, false, true, true, false, false><<<dim3(64, 8), 256, 0, stream>>>(
            ffmid, w2T + wff, ffb2 + L * DD, x2b, x2b, nullptr, BB * TT, DD, FFD);
    }

    head_kernel<<<16, 256, 0, stream>>>(x1b, x2b, lnfg, lnfb, hw1, hb1,
                                        hlng, hlnb, hw2, hb2, out);
}

// Round 12
// 1004.687 us; speedup vs baseline: 1.7036x; 1.7036x over previous
//
#include <hip/hip_runtime.h>
#include <hip/hip_fp16.h>
#include <cfloat>
#include <cstdint>

// Problem constants
#define BB      16      // batch
#define TT      512     // seq
#define DD      512     // d_model
#define HH      8       // heads
#define DHH     64      // head dim
#define FFD     2048    // ff dim
#define BHH     128     // BB*HH
#define NHASH   4
#define NCHUNK  8       // NHASH * N_BUCKETS
#define CHUNKSZ 256
#define NLAYER  4

typedef unsigned short u16;
typedef unsigned int   u32;
typedef __attribute__((ext_vector_type(8))) short bfrag;    // 8 bf16 (4 VGPR)
typedef __attribute__((ext_vector_type(4))) float f4x;      // 4 f32 acc
typedef __attribute__((ext_vector_type(16))) float f16x;    // 16 f32 acc

union FragU { u32 u[4]; uint4 v4; bfrag f; };

__device__ __forceinline__ unsigned pk_bf16(float a, float b) {
    union { float f; unsigned u; } x, y;
    x.f = a; y.f = b;
    unsigned lo = ((x.u + 0x7FFFu + ((x.u >> 16) & 1u)) >> 16) & 0xFFFFu;
    unsigned hi = (y.u + 0x7FFFu + ((y.u >> 16) & 1u)) & 0xFFFF0000u;
    return lo | hi;
}
// HW packed f32->bf16 RTNE (1 VALU op; no builtin on gfx950)
__device__ __forceinline__ unsigned cvt_pk(float a, float b) {
    unsigned r;
    asm("v_cvt_pk_bf16_f32 %0, %1, %2" : "=v"(r) : "v"(a), "v"(b));
    return r;
}
// HW packed f32->f16 (RTZ) — o_hash precision (10-bit mantissa)
__device__ __forceinline__ unsigned pkrtz(float a, float b) {
    unsigned r;
    asm("v_cvt_pkrtz_f16_f32 %0, %1, %2" : "=v"(r) : "v"(a), "v"(b));
    return r;
}
__device__ __forceinline__ u16 bf16_1(float a) {
    union { float f; unsigned u; } x; x.f = a;
    return (u16)((x.u + 0x7FFFu + ((x.u >> 16) & 1u)) >> 16);
}
__device__ __forceinline__ float b2f(u16 h) {
    union { unsigned u; float f; } x; x.u = ((unsigned)h) << 16; return x.f;
}

// async global->LDS, 16B per lane (dest must be linear: base + lane*16)
__device__ __forceinline__ void gload16(const u16* g, u16* l) {
    __builtin_amdgcn_global_load_lds(
        (const __attribute__((address_space(1))) u32*)g,
        (__attribute__((address_space(3))) u32*)l, 16, 0, 0);
}

// ---------------------------------------------------------------------------
// Embedding: h = x @ emb_w + emb_b + pos ; write to both x1 and x2
__global__ __launch_bounds__(256)
void embed_kernel(const float* __restrict__ x, const float* __restrict__ ew,
                  const float* __restrict__ eb, const float* __restrict__ pos,
                  float* __restrict__ x1, float* __restrict__ x2)
{
    const int row = blockIdx.x;          // b*T + t
    const int t = row & (TT - 1);
    __shared__ float xr[32];
    if (threadIdx.x < 32) xr[threadIdx.x] = x[row * 32 + threadIdx.x];
    __syncthreads();
    for (int d = threadIdx.x; d < DD; d += 256) {
        float s = eb[d] + pos[t * DD + d];
        #pragma unroll
        for (int k = 0; k < 32; ++k) s = fmaf(xr[k], ew[k * DD + d], s);
        x1[(size_t)row * DD + d] = s;
        x2[(size_t)row * DD + d] = s;
    }
}

// ---------------------------------------------------------------------------
// LayerNorm over last dim (512); writes bf16 (always) and f32 (if out!=null).
__global__ __launch_bounds__(256)
void ln_kernel(const float* __restrict__ in, const float* __restrict__ g,
               const float* __restrict__ bta, float* __restrict__ out,
               u16* __restrict__ outh)
{
    const int row = blockIdx.x * 4 + (threadIdx.x >> 6);
    const int lane = threadIdx.x & 63;
    const float* r = in + (size_t)row * DD;
    float vals[8];
    float s = 0.0f;
    #pragma unroll
    for (int i = 0; i < 8; ++i) { vals[i] = r[i * 64 + lane]; s += vals[i]; }
    #pragma unroll
    for (int o = 1; o < 64; o <<= 1) s += __shfl_xor(s, o);
    const float mean = s * (1.0f / 512.0f);
    float vs = 0.0f;
    #pragma unroll
    for (int i = 0; i < 8; ++i) { float d = vals[i] - mean; vs += d * d; }
    #pragma unroll
    for (int o = 1; o < 64; o <<= 1) vs += __shfl_xor(vs, o);
    const float rstd = rsqrtf(vs * (1.0f / 512.0f) + 1e-5f);
    u16* hrow = outh + (size_t)row * DD;
    #pragma unroll
    for (int i = 0; i < 8; ++i) {
        const int d = i * 64 + lane;
        const float y = (vals[i] - mean) * rstd * g[d] + bta[d];
        if (out != nullptr) out[(size_t)row * DD + d] = y;
        hrow[d] = bf16_1(y);
    }
}

// ---------------------------------------------------------------------------
// Batched weight prep: transpose+bf16 ALL layers in ONE dispatch.
// wqk+wv go into a CONCATENATED wqkvT [1024][512] per layer.
__global__ __launch_bounds__(256)
void prep_weights(const float* __restrict__ wqk, const float* __restrict__ wv,
                  const float* __restrict__ wo, const float* __restrict__ ffw1,
                  const float* __restrict__ ffw2,
                  u16* __restrict__ wqkvT, u16* __restrict__ woT,
                  u16* __restrict__ w1T, u16* __restrict__ w2T)
{
    const int id = blockIdx.x;
    const float* in; u16* outp; int K, N, kt, nt;
    if (id < 3072) {                       // wqk / wv / wo : 512x512, 256 tiles/L
        const int fam = id >> 10;
        const int r = id & 1023;
        const int L = r >> 8, t = r & 255;
        K = 512; N = 512;
        const size_t off = (size_t)L * 512 * 512;
        in = (fam == 0 ? wqk : fam == 1 ? wv : wo) + off;
        outp = (fam == 2) ? (woT + off)
                          : (wqkvT + (size_t)L * 1024 * 512 + (fam == 1 ? (size_t)512 * 512 : 0));
        kt = (t & 15) << 5; nt = (t >> 4) << 5;
    } else if (id < 7168) {                // ff1: 512x2048, 1024 tiles/L
        const int r = id - 3072;
        const int L = r >> 10, t = r & 1023;
        K = 512; N = 2048;
        in = ffw1 + (size_t)L * 512 * 2048;
        outp = w1T + (size_t)L * 2048 * 512;
        kt = (t & 15) << 5; nt = (t >> 4) << 5;
    } else {                               // ff2: 2048x512, 1024 tiles/L
        const int r = id - 7168;
        const int L = r >> 10, t = r & 1023;
        K = 2048; N = 512;
        in = ffw2 + (size_t)L * 2048 * 512;
        outp = w2T + (size_t)L * 512 * 2048;
        kt = (t & 63) << 5; nt = (t >> 6) << 5;
    }
    __shared__ float tile[32][33];
    const int rr = threadIdx.x >> 3, c4 = (threadIdx.x & 7) * 4;
    const float4 v4 = *(const float4*)(in + (size_t)(kt + rr) * N + nt + c4);
    tile[rr][c4 + 0] = v4.x; tile[rr][c4 + 1] = v4.y;
    tile[rr][c4 + 2] = v4.z; tile[rr][c4 + 3] = v4.w;
    __syncthreads();
    uint2 p;
    p.x = pk_bf16(tile[c4 + 0][rr], tile[c4 + 1][rr]);
    p.y = pk_bf16(tile[c4 + 2][rr], tile[c4 + 3][rr]);
    *(uint2*)(outp + (size_t)(nt + rr) * K + kt + c4) = p;
}

// ---------------------------------------------------------------------------
// wrot[L][f][h*4+hash] = sum_d wqk[L][f][h*64+d] * rot[L][d][hash]
__global__ __launch_bounds__(256)
void wrot_kernel(const float* __restrict__ wqk, const float* __restrict__ rot,
                 float* __restrict__ wrotAll)
{
    const int hh = blockIdx.x, L = blockIdx.y;
    const int head = hh >> 2, h = hh & 3;
    __shared__ float rc[64];
    if (threadIdx.x < 64)
        rc[threadIdx.x] = rot[((size_t)L * 64 + threadIdx.x) * 4 + h];
    __syncthreads();
    for (int f = threadIdx.x; f < 512; f += 256) {
        const float* wrow = wqk + (size_t)L * 512 * 512 + (size_t)f * 512 + head * 64;
        float s = 0.0f;
        #pragma unroll
        for (int d = 0; d < 64; d += 4) {
            const float4 w4 = *(const float4*)(wrow + d);
            s += w4.x * rc[d] + w4.y * rc[d + 1] + w4.z * rc[d + 2] + w4.w * rc[d + 3];
        }
        wrotAll[((size_t)L * 512 + f) * 32 + hh] = s;
    }
}

// ---------------------------------------------------------------------------
// rotated[8192][32] = xn[8192][512] @ wrot[512][32], all f32. grid 128.
__global__ __launch_bounds__(256)
void rot_gemm(const float* __restrict__ A, const float* __restrict__ Wr,
              float* __restrict__ C)
{
    __shared__ float As[64][36];
    __shared__ float Ws[32][36];
    const int m0 = blockIdx.x * 64;
    const int r = threadIdx.x >> 2, cg = threadIdx.x & 3;
    float acc[8] = {};
    for (int f0 = 0; f0 < 512; f0 += 32) {
        __syncthreads();
        {
            const int lr = threadIdx.x >> 2, lc = (threadIdx.x & 3) * 8;
            const float* ap = A + (size_t)(m0 + lr) * 512 + f0 + lc;
            *(float4*)&As[lr][lc]     = ((const float4*)ap)[0];
            *(float4*)&As[lr][lc + 4] = ((const float4*)ap)[1];
            const int wr = threadIdx.x >> 3, wc = (threadIdx.x & 7) * 4;
            *(float4*)&Ws[wr][wc] = *(const float4*)(Wr + (size_t)(f0 + wr) * 32 + wc);
        }
        __syncthreads();
        #pragma unroll
        for (int kk = 0; kk < 32; ++kk) {
            const float a = As[r][kk];
            #pragma unroll
            for (int c = 0; c < 8; ++c)
                acc[c] = fmaf(a, Ws[kk][cg * 8 + c], acc[c]);
        }
    }
    float* crow = C + (size_t)(m0 + r) * 32 + cg * 8;
    *(float4*)crow       = make_float4(acc[0], acc[1], acc[2], acc[3]);
    *(float4*)(crow + 4) = make_float4(acc[4], acc[5], acc[6], acc[7]);
}

// ---------------------------------------------------------------------------
// bf16 MFMA GEMM, templated tile, double-buffered LDS, 2-phase pipeline.
// QKV: merged qk+v output — n0<512 routes to per-head qkh (Cb); n0>=512
// routes to row-major vbh (Cf reinterpreted as u16*).
__device__ __forceinline__ float gelu1(float v) {
    return 0.5f * v * (1.0f + erff(v * 0.70710678118654752440f));
}
__device__ __forceinline__ int swz_row(int r, int BK) {
    return (BK == 32) ? ((r & 3) ^ ((r >> 2) & 3)) : (r & 7);
}

template<int BM, int BN, int BK, bool GELU, bool ADD, bool BIAS, bool OUTBF, bool QKV>
__global__ __launch_bounds__(256)
void gemm_bf16(const u16* __restrict__ A, const u16* __restrict__ WT,
               const float* __restrict__ bias, const float* __restrict__ addsrc,
               float* __restrict__ Cf, u16* __restrict__ Cb,
               int M, int N, int K)
{
    constexpr int NCH = BK / 8;
    constexpr int CPA = BM * NCH / 256;
    constexpr int CPB = BN * NCH / 256;
    constexpr int MR = BM / 32, NR = BN / 32, KR = BK / 32;
    __shared__ __align__(16) u16 Abuf[2][BM * BK];
    __shared__ __align__(16) u16 Bbuf[2][BN * BK];
    const int tid = threadIdx.x;
    const int m0 = blockIdx.x * BM, n0 = blockIdx.y * BN;

    const u16* aSrc[CPA]; const u16* bSrc[CPB];
    #pragma unroll
    for (int i = 0; i < CPA; ++i) {
        const int s = tid + i * 256, row = s / NCH, ch = s % NCH;
        aSrc[i] = A + (size_t)(m0 + row) * K + (ch ^ swz_row(row, BK)) * 8;
    }
    #pragma unroll
    for (int i = 0; i < CPB; ++i) {
        const int s = tid + i * 256, row = s / NCH, ch = s % NCH;
        bSrc[i] = WT + (size_t)(n0 + row) * K + (ch ^ swz_row(row, BK)) * 8;
    }

    auto STAGE = [&](int bufi, int koff) {
        #pragma unroll
        for (int i = 0; i < CPA; ++i)
            gload16(aSrc[i] + koff, &Abuf[bufi][(tid + i * 256) * 8]);
        #pragma unroll
        for (int i = 0; i < CPB; ++i)
            gload16(bSrc[i] + koff, &Bbuf[bufi][(tid + i * 256) * 8]);
    };

    const int l = tid & 63, wv_ = tid >> 6;
    const int wm = (wv_ >> 1) * (BM / 2);
    const int wn = (wv_ & 1) * (BN / 2);
    const int fr = l & 15, fc = l >> 4;

    f4x acc[MR][NR] = {};
    const int nK = K / BK;
    STAGE(0, 0);
    for (int ks = 0; ks < nK; ++ks) {
        __syncthreads();
        if (ks + 1 < nK) STAGE((ks + 1) & 1, (ks + 1) * BK);
        const u16* Ab = Abuf[ks & 1];
        const u16* Bb = Bbuf[ks & 1];
        FragU af[MR][KR], bf_[NR][KR];
        #pragma unroll
        for (int i = 0; i < MR; ++i)
            #pragma unroll
            for (int u = 0; u < KR; ++u) {
                const int r = wm + i * 16 + fr;
                af[i][u].v4 = *(const uint4*)((const char*)Ab +
                    (size_t)r * (2 * BK) + (((u * 4 + fc) ^ swz_row(r, BK)) << 4));
            }
        #pragma unroll
        for (int j = 0; j < NR; ++j)
            #pragma unroll
            for (int u = 0; u < KR; ++u) {
                const int r = wn + j * 16 + fr;
                bf_[j][u].v4 = *(const uint4*)((const char*)Bb +
                    (size_t)r * (2 * BK) + (((u * 4 + fc) ^ swz_row(r, BK)) << 4));
            }
        #pragma unroll
        for (int u = 0; u < KR; ++u)
            #pragma unroll
            for (int i = 0; i < MR; ++i)
                #pragma unroll
                for (int j = 0; j < NR; ++j)
                    acc[i][j] = __builtin_amdgcn_mfma_f32_16x16x32_bf16(
                        af[i][u].f, bf_[j][u].f, acc[i][j], 0, 0, 0);
    }

    #pragma unroll
    for (int i = 0; i < MR; ++i) {
        #pragma unroll
        for (int q = 0; q < 4; ++q) {
            const int row = m0 + wm + i * 16 + fc * 4 + q;
            #pragma unroll
            for (int j = 0; j < NR; ++j) {
                const int col = n0 + wn + j * 16 + fr;
                float vx = acc[i][j][q];
                if constexpr (BIAS) vx += bias[col];
                if constexpr (GELU) vx = gelu1(vx);
                if constexpr (ADD) vx += addsrc[(size_t)row * N + col];
                if constexpr (QKV) {
                    if (n0 < 512) {   // qk half -> per-head layout [(b*8+h)][t][d]
                        const int bq = row >> 9, tq = row & 511;
                        const int hq = col >> 6, dq = col & 63;
                        Cb[(((size_t)(bq * 8 + hq) * 512) + tq) * 64 + dq] = bf16_1(vx);
                    } else {          // v half -> row-major [row][512]
                        ((u16*)Cf)[(size_t)row * 512 + (col - 512)] = bf16_1(vx);
                    }
                } else if constexpr (OUTBF) {
                    Cb[(size_t)row * N + col] = bf16_1(vx);
                } else {
                    Cf[(size_t)row * N + col] = vx;
                }
            }
        }
    }
}

// ---------------------------------------------------------------------------
// K/Q pre-normalization from bf16 qkh: qkn = bf16(row/|row|), qnrm = |row|.
// Also serves as an L2 pre-warm of qkn/qnrm right before the gather-heavy
// attention kernel (R9 lesson: removing this cost attn +17 us/dispatch).
__global__ __launch_bounds__(256)
void knorm_kernel(const u16* __restrict__ qkh, u16* __restrict__ qkn,
                  float* __restrict__ qnrm)
{
    const int g = blockIdx.x * 16 + (threadIdx.x >> 4);  // bh*T + t
    const int li = threadIdx.x & 15;
    const uint2 raw = *(const uint2*)(qkh + (size_t)g * 64 + li * 4);
    const float v0 = b2f((u16)(raw.x & 0xffff)), v1 = b2f((u16)(raw.x >> 16));
    const float v2 = b2f((u16)(raw.y & 0xffff)), v3 = b2f((u16)(raw.y >> 16));
    float ss = v0 * v0 + v1 * v1 + v2 * v2 + v3 * v3;
    ss += __shfl_xor(ss, 1); ss += __shfl_xor(ss, 2);
    ss += __shfl_xor(ss, 4); ss += __shfl_xor(ss, 8);
    const float qn = sqrtf(ss);
    const float rv = 1.0f / fmaxf(qn, 1e-12f);
    uint2 o;
    o.x = cvt_pk(v0 * rv, v1 * rv);
    o.y = cvt_pk(v2 * rv, v3 * rv);
    *(uint2*)(qkn + (size_t)g * 64 + li * 4) = o;
    if (li == 0) qnrm[g] = qn;
}

// ---------------------------------------------------------------------------
// Bucket assignment + stable partition from precomputed rotated (f32)
__global__ __launch_bounds__(512)
void bucket_sort_kernel(const float* __restrict__ rotated, int* __restrict__ st)
{
    const int h = blockIdx.x, bh = blockIdx.y;
    const int b = bh >> 3, head = bh & 7;
    const int t = threadIdx.x;
    __shared__ int zcnt[8];
    const float r = rotated[((size_t)(b * TT + t)) * 32 + head * 4 + h];
    const int bit = (r < 0.0f) ? 1 : 0;
    const int wid = t >> 6, lane = t & 63;
    const unsigned long long zm = __ballot(bit == 0);
    if (lane == 0) zcnt[wid] = __popcll(zm);
    __syncthreads();
    int zoff = 0, Z = 0;
    #pragma unroll
    for (int w = 0; w < 8; ++w) { const int cn = zcnt[w]; if (w < wid) zoff += cn; Z += cn; }
    const int zpre = __popcll(zm & ((1ull << lane) - 1ull));
    const int dst = (bit == 0) ? (zoff + zpre)
                               : (Z + (wid * 64 - zoff) + (lane - zpre));
    st[((size_t)bh * NHASH + h) * TT + dst] = t;
}

// ---------------------------------------------------------------------------
// MFMA LSH attention — 8 waves x 32 queries, double-buffered LDS (1 barrier
// per tile), bit-reversed V^T slot rotation (conflict-free V writes).
// NOTE: no s_setprio here — R11 showed it triggers accumulator spills
// (~1.1 GB scratch traffic/dispatch) in this register-tight structure.
__global__ __launch_bounds__(512, 4)
void lsh_attn_mfma(const u16* __restrict__ qkn, const u16* __restrict__ v,
                   const float* __restrict__ qnrm, const int* __restrict__ st,
                   __half* __restrict__ o_hash, float* __restrict__ lse_hash)
{
    const int cc = blockIdx.x, bh = blockIdx.y;
    const int b = bh >> 3, head = bh & 7;
    const int h = cc >> 1, c = cc & 1;
    const int pcc = (cc + 7) & 7;
    const int hp = pcc >> 1, cp = pcc & 1;
    const int tid = threadIdx.x;
    const int w = tid >> 6;          // wave 0..7 -> queries w*32..+32
    const int lane = tid & 63;
    const int l31 = lane & 31;
    const int hi = lane >> 5;
    const int* stb = st + (size_t)bh * (NHASH * TT);
    const size_t vbase = ((size_t)b * TT) * DD + head * DHH;
    const u16* qknb = qkn + (size_t)bh * TT * DHH;

    __shared__ __align__(16) u16 Kbf[2][64 * 64];
    __shared__ __align__(16) u16 VTbf[2][64 * 64];
    __shared__ __align__(16) int ktl[2][64];

    // ---- Q fragment (one query per lane-column) ----
    const int q_t = stb[h * TT + c * CHUNKSZ + w * 32 + l31];
    const float qn = qnrm[(size_t)bh * TT + q_t];
    const float mnat = qn * 0.125f;
    const float aC = qn * 0.1803368801111137f;   // |q| * 0.125 * log2(e)
    uint4 QF4[4];
    {
        const u16* qrow = qknb + (size_t)q_t * DHH;
        #pragma unroll
        for (int ds = 0; ds < 4; ++ds)
            QF4[ds] = *(const uint4*)(qrow + ds * 16 + hi * 8);
    }

    f16x acc[2] = {};           // [dt] O^T tiles (32d x 32q)
    float lac0 = 0.f, lac1 = 0.f;
    const int k8 = tid >> 3;    // key row 0..63 (8 lanes per 128B row)
    const int c8 = tid & 7;     // 16B chunk of the row
    // bit-reversed slot bases (constant per thread)
    const int brc = ((c8 & 1) << 2) | (c8 & 2) | ((c8 & 4) >> 2);   // bitrev3(c8)
    const int wSlot = ((k8 >> 3) + brc) & 7;                        // V write slot
    const int g2 = l31 >> 3;                                        // read row group
    const int brg = ((g2 & 1) << 2) | (g2 & 2);                     // bitrev3(g2), g2<4

    auto gather = [&](int t8, uint4& kc, uint4& vc, int& ktc) {
        const int kj = t8 * 64 + k8;
        const int k_t = (kj < CHUNKSZ) ? stb[h * TT + c * CHUNKSZ + kj]
                                       : stb[hp * TT + cp * CHUNKSZ + (kj - CHUNKSZ)];
        ktc = k_t;
        kc = *(const uint4*)(qknb + (size_t)k_t * DHH + c8 * 8);
        vc = *(const uint4*)(v + vbase + (size_t)k_t * DD + c8 * 8);
    };
    auto writeTile = [&](int bi, const uint4& kc, const uint4& vc, int ktc) {
        *(uint4*)((char*)Kbf[bi] + ((k8 * 128 + c8 * 16) ^ ((k8 & 7) << 4))) = kc;
        const unsigned vu[4] = {vc.x, vc.y, vc.z, vc.w};
        #pragma unroll
        for (int i = 0; i < 8; ++i) {
            const int d = c8 * 8 + i;
            const u16 hv = (u16)((i & 1) ? (vu[i >> 1] >> 16) : (vu[i >> 1] & 0xffff));
            *(u16*)((char*)VTbf[bi] + d * 128 + wSlot * 16 + (k8 & 7) * 2) = hv;
        }
        if (c8 == 0) ktl[bi][k8] = ktc;
    };

    uint4 kc, vc; int ktc;
    gather(0, kc, vc, ktc);
    writeTile(0, kc, vc, ktc);
    __syncthreads();

    for (int kt8 = 0; kt8 < 8; ++kt8) {
        const int cur = kt8 & 1;
        if (kt8 < 7) gather(kt8 + 1, kc, vc, ktc);
        const u16* Kb = Kbf[cur];
        const u16* Vb = VTbf[cur];
        const int* kl = ktl[cur];

        #pragma unroll
        for (int kt = 0; kt < 2; ++kt) {
            int4 kt4[4];
            #pragma unroll
            for (int j = 0; j < 4; ++j)
                kt4[j] = *(const int4*)&kl[kt * 32 + 8 * j + 4 * hi];
            const int* ktvp = (const int*)kt4;
            FragU KA[4];
            #pragma unroll
            for (int ds = 0; ds < 4; ++ds) {
                const int row = kt * 32 + l31;
                KA[ds].v4 = *(const uint4*)((const char*)Kb +
                    ((row * 128 + ds * 32 + hi * 16) ^ ((row & 7) << 4)));
            }
            FragU VA[2][2];
            #pragma unroll
            for (int dt = 0; dt < 2; ++dt)
                #pragma unroll
                for (int u = 0; u < 2; ++u) {
                    const int row = dt * 32 + l31;
                    const int cr = (kt * 2 + u) * 2 + hi;
                    const int slot = (cr + brg + dt) & 7;    // bitrev3(row>>3)=brg+dt
                    VA[dt][u].v4 = *(const uint4*)((const char*)Vb +
                        row * 128 + slot * 16);
                }
            f16x s = {0.f,0.f,0.f,0.f,0.f,0.f,0.f,0.f,
                      0.f,0.f,0.f,0.f,0.f,0.f,0.f,0.f};
            #pragma unroll
            for (int ds = 0; ds < 4; ++ds) {
                FragU qf; qf.v4 = QF4[ds];
                s = __builtin_amdgcn_mfma_f32_32x32x16_bf16(KA[ds].f, qf.f, s, 0, 0, 0);
            }
            float pv[16];
            #pragma unroll
            for (int i = 0; i < 16; i += 2) {
                const float e0 = exp2f(fmaf(s[i],     aC, -aC));
                const float e1 = exp2f(fmaf(s[i + 1], aC, -aC));
                const float p0 = (q_t > ktvp[i])     ? e0 : 0.0f;
                const float p1 = (q_t > ktvp[i + 1]) ? e1 : 0.0f;
                pv[i] = p0; pv[i + 1] = p1;
                lac0 += p0; lac1 += p1;
            }
            unsigned P2[8];
            #pragma unroll
            for (int g = 0; g < 4; ++g) {
                P2[2*g]   = cvt_pk(pv[4*g],   pv[4*g+1]);
                P2[2*g+1] = cvt_pk(pv[4*g+2], pv[4*g+3]);
            }
            #pragma unroll
            for (int u = 0; u < 2; ++u) {
                unsigned a0 = P2[4*u + 0], b0 = P2[4*u + 2];
                unsigned a1 = P2[4*u + 1], b1 = P2[4*u + 3];
                asm("v_permlane32_swap_b32 %0, %1" : "+v"(a0), "+v"(b0));
                asm("v_permlane32_swap_b32 %0, %1" : "+v"(a1), "+v"(b1));
                FragU bfv;
                bfv.u[0] = a0; bfv.u[1] = a1; bfv.u[2] = b0; bfv.u[3] = b1;
                #pragma unroll
                for (int dt = 0; dt < 2; ++dt)
                    acc[dt] = __builtin_amdgcn_mfma_f32_32x32x16_bf16(
                        VA[dt][u].f, bfv.f, acc[dt], 0, 0, 0);
            }
        }

        if (kt8 < 7) {
            writeTile(cur ^ 1, kc, vc, ktc);
            __syncthreads();
        }
    }

    // ---- finalize: l, lse, register-only epilogue ----
    const float lts = lac0 + lac1;
    const float lt = lts + __shfl_xor(lts, 32);
    const float invl = (lt > 0.f) ? 1.0f / lt : 0.0f;
    if (hi == 0) {
        const float lse = (lt > 0.f) ? (mnat + logf(lt)) : -5.0e4f;
        lse_hash[(size_t)(bh * NHASH + h) * TT + q_t] = lse;
    }
    unsigned wa[8], wb[8];
    #pragma unroll
    for (int m = 0; m < 8; ++m) {
        wa[m] = pkrtz(acc[0][2*m] * invl, acc[0][2*m+1] * invl);
        wb[m] = pkrtz(acc[1][2*m] * invl, acc[1][2*m+1] * invl);
    }
    #pragma unroll
    for (int m = 0; m < 8; ++m)
        asm("v_permlane32_swap_b32 %0, %1" : "+v"(wa[m]), "+v"(wb[m]));
    __half* orow = o_hash + ((size_t)(bh * NHASH + h) * TT + q_t) * DHH + hi * 32;
    if (lt > 0.f) {
        #pragma unroll
        for (int g = 0; g < 4; ++g) {
            uint4 o;
            o.x = wa[2*g]; o.y = wa[2*g+1];
            o.z = wb[2*g]; o.w = wb[2*g+1];
            ((uint4*)orow)[g] = o;
        }
    } else {
        const u16* vr = v + vbase + (size_t)q_t * DD + hi * 32;
        #pragma unroll
        for (int g = 0; g < 4; ++g) {
            uint4 o;
            o.x = pkrtz(b2f(vr[8*g+0]), b2f(vr[8*g+1]));
            o.y = pkrtz(b2f(vr[8*g+2]), b2f(vr[8*g+3]));
            o.z = pkrtz(b2f(vr[8*g+4]), b2f(vr[8*g+5]));
            o.w = pkrtz(b2f(vr[8*g+6]), b2f(vr[8*g+7]));
            ((uint4*)orow)[g] = o;
        }
    }
}

// ---------------------------------------------------------------------------
// Combine hash rounds: read o_hash f16, write merged bf16 (wo GEMM A-operand)
__global__ __launch_bounds__(256)
void combine_kernel(const __half* __restrict__ o_hash, const float* __restrict__ lse_hash,
                    u16* __restrict__ am)
{
    const int idx = blockIdx.x * 4 + (threadIdx.x >> 6);
    const int lane = threadIdx.x & 63;
    const int bh = idx >> 9, t = idx & 511;
    const int b = bh >> 3, head = bh & 7;
    const float ls0 = lse_hash[(size_t)(bh * NHASH + 0) * TT + t];
    const float ls1 = lse_hash[(size_t)(bh * NHASH + 1) * TT + t];
    const float ls2 = lse_hash[(size_t)(bh * NHASH + 2) * TT + t];
    const float ls3 = lse_hash[(size_t)(bh * NHASH + 3) * TT + t];
    const float M = fmaxf(fmaxf(ls0, ls1), fmaxf(ls2, ls3));
    const float e0 = __expf(ls0 - M), e1 = __expf(ls1 - M);
    const float e2 = __expf(ls2 - M), e3 = __expf(ls3 - M);
    const float inv = 1.0f / (e0 + e1 + e2 + e3);
    const float o =
        (e0 * __half2float(o_hash[((size_t)((bh * NHASH + 0) * TT + t)) * DHH + lane]) +
         e1 * __half2float(o_hash[((size_t)((bh * NHASH + 1) * TT + t)) * DHH + lane]) +
         e2 * __half2float(o_hash[((size_t)((bh * NHASH + 2) * TT + t)) * DHH + lane]) +
         e3 * __half2float(o_hash[((size_t)((bh * NHASH + 3) * TT + t)) * DHH + lane])) * inv;
    am[((size_t)(b * TT + t)) * DD + head * DHH + lane] = bf16_1(o);
}

// ---------------------------------------------------------------------------
// Final head
__device__ __forceinline__ float block_sum256(float v, volatile float* red)
{
    const int lane = threadIdx.x & 63, wid = threadIdx.x >> 6;
    #pragma unroll
    for (int o = 1; o < 64; o <<= 1) v += __shfl_xor(v, o);
    __syncthreads();
    if (lane == 0) red[wid] = v;
    __syncthreads();
    return red[0] + red[1] + red[2] + red[3];
}

__global__ __launch_bounds__(256)
void head_kernel(const float* __restrict__ x1, const float* __restrict__ x2,
                 const float* __restrict__ lnfg, const float* __restrict__ lnfb,
                 const float* __restrict__ hw1, const float* __restrict__ hb1,
                 const float* __restrict__ hlng, const float* __restrict__ hlnb,
                 const float* __restrict__ hw2, const float* __restrict__ hb2,
                 float* __restrict__ out)
{
    __shared__ float nrow[512];
    __shared__ float red[4];
    const int b = blockIdx.x, tid = threadIdx.x;
    const size_t roff = ((size_t)b * TT + (TT - 1)) * DD;
    const float v0 = 0.5f * (x1[roff + tid] + x2[roff + tid]);
    const float v1 = 0.5f * (x1[roff + 256 + tid] + x2[roff + 256 + tid]);
    const float mean = block_sum256(v0 + v1, red) * (1.0f / 512.0f);
    const float d0 = v0 - mean, d1 = v1 - mean;
    const float var = block_sum256(d0 * d0 + d1 * d1, red) * (1.0f / 512.0f);
    const float rstd = rsqrtf(var + 1e-5f);
    nrow[tid]       = d0 * rstd * lnfg[tid] + lnfb[tid];
    nrow[tid + 256] = d1 * rstd * lnfg[tid + 256] + lnfb[tid + 256];
    __syncthreads();
    float a = hb1[tid];
    for (int k = 0; k < 512; ++k) a = fmaf(nrow[k], hw1[(size_t)k * 256 + tid], a);
    const float m2 = block_sum256(a, red) * (1.0f / 256.0f);
    const float dd = a - m2;
    const float var2 = block_sum256(dd * dd, red) * (1.0f / 256.0f);
    float y = dd * rsqrtf(var2 + 1e-5f) * hlng[tid] + hlnb[tid];
    y = fmaxf(y, 0.0f);
    const float osum = block_sum256(y * hw2[tid], red);
    if (tid == 0) out[b] = osum + hb2[0];
}

// ---------------------------------------------------------------------------
extern "C" void kernel_launch(void* const* d_in, const int* in_sizes, int n_in,
                              void* d_out, int out_size, void* d_ws, size_t ws_size,
                              hipStream_t stream)
{
    (void)in_sizes; (void)n_in; (void)out_size; (void)ws_size;
    const float* x    = (const float*)d_in[0];
    const float* embw = (const float*)d_in[1];
    const float* embb = (const float*)d_in[2];
    const float* pos  = (const float*)d_in[3];
    const float* ln1g = (const float*)d_in[4];
    const float* ln1b = (const float*)d_in[5];
    const float* wqk  = (const float*)d_in[6];
    const float* wv   = (const float*)d_in[7];
    const float* wo   = (const float*)d_in[8];
    const float* wob  = (const float*)d_in[9];
    const float* ln2g = (const float*)d_in[10];
    const float* ln2b = (const float*)d_in[11];
    const float* ffw1 = (const float*)d_in[12];
    const float* ffb1 = (const float*)d_in[13];
    const float* ffw2 = (const float*)d_in[14];
    const float* ffb2 = (const float*)d_in[15];
    const float* rot  = (const float*)d_in[16];
    const float* lnfg = (const float*)d_in[17];
    const float* lnfb = (const float*)d_in[18];
    const float* hw1  = (const float*)d_in[19];
    const float* hb1  = (const float*)d_in[20];
    const float* hlng = (const float*)d_in[21];
    const float* hlnb = (const float*)d_in[22];
    const float* hw2  = (const float*)d_in[23];
    const float* hb2  = (const float*)d_in[24];
    float* out = (float*)d_out;

    const size_t SZ_BTD = (size_t)BB * TT * DD;            // 4,194,304
    const size_t SZ_OH  = (size_t)BHH * NHASH * TT * DHH;  // 16,777,216

    char* p = (char*)d_ws;
    float* x1b = (float*)p;  p += SZ_BTD * 4;
    float* x2b = (float*)p;  p += SZ_BTD * 4;
    float* xnb = (float*)p;  p += SZ_BTD * 4;              // also amb (bf16) late
    u16*   vbh = (u16*)p;    p += SZ_BTD * 2;
    u16*   xnbh = (u16*)p;   p += SZ_BTD * 2;
    u16*   qkh  = (u16*)p;   p += SZ_BTD * 2;              // bf16 qk, per-head layout
    u16*   qknb = (u16*)p;   p += (size_t)BHH * TT * DHH * 2;
    float* qnrm = (float*)p; p += (size_t)BHH * TT * 4;
    float* rotated = (float*)p; p += (size_t)BB * TT * 32 * 4;
    __half* ohash = (__half*)p;                  // 33.5MB region
    u16*    ffmid = (u16*)p;                     // temporal alias (disjoint life)
    p += SZ_OH * 2;
    float* lseb  = (float*)p; p += (size_t)BHH * NHASH * TT * 4;
    int*   stb   = (int*)p;   p += (size_t)BHH * NHASH * TT * 4;
    u16* wqkvT = (u16*)p; p += (size_t)NLAYER * 1024 * 512 * 2;
    u16* woT   = (u16*)p; p += (size_t)NLAYER * DD * DD * 2;
    u16* w1T   = (u16*)p; p += (size_t)NLAYER * DD * FFD * 2;
    u16* w2T   = (u16*)p; p += (size_t)NLAYER * FFD * DD * 2;
    float* wrotAll = (float*)p; p += (size_t)NLAYER * DD * 32 * 4;
    u16* amb = (u16*)xnb;                        // alias (xnb dead after GEMMs)

    // ---- one-time weight prep (all layers) ----
    prep_weights<<<11264, 256, 0, stream>>>(wqk, wv, wo, ffw1, ffw2,
                                            wqkvT, woT, w1T, w2T);
    wrot_kernel<<<dim3(32, NLAYER), 256, 0, stream>>>(wqk, rot, wrotAll);

    embed_kernel<<<BB * TT, 256, 0, stream>>>(x, embw, embb, pos, x1b, x2b);

    for (int L = 0; L < NLAYER; ++L) {
        const size_t w512 = (size_t)L * DD * DD;
        const size_t wff  = (size_t)L * DD * FFD;

        // x1 += attn(ln(x2))
        ln_kernel<<<2048, 256, 0, stream>>>(x2b, ln1g + L * DD, ln1b + L * DD, xnb, xnbh);
        rot_gemm<<<128, 256, 0, stream>>>(xnb, wrotAll + (size_t)L * DD * 32, rotated);
        gemm_bf16<128, 128, 32, false, false, false, false, true><<<dim3(64, 8), 256, 0, stream>>>(
            xnbh, wqkvT + (size_t)L * 1024 * 512, nullptr, nullptr,
            (float*)vbh, qkh, BB * TT, 1024, DD);
        bucket_sort_kernel<<<dim3(NHASH, BHH), 512, 0, stream>>>(rotated, stb);
        knorm_kernel<<<4096, 256, 0, stream>>>(qkh, qknb, qnrm);
        lsh_attn_mfma<<<dim3(NCHUNK, BHH), 512, 0, stream>>>(
            qknb, vbh, qnrm, stb, ohash, lseb);
        combine_kernel<<<16384, 256, 0, stream>>>(ohash, lseb, amb);
        gemm_bf16<128, 64, 64, false, true, true, false, false><<<dim3(64, 8), 256, 0, stream>>>(
            amb, woT + w512, wob + L * DD, x1b, x1b, nullptr, BB * TT, DD, DD);

        // x2 += ff(ln(x1))
        ln_kernel<<<2048, 256, 0, stream>>>(x1b, ln2g + L * DD, ln2b + L * DD, nullptr, xnbh);
        gemm_bf16<128, 128, 32, true, false, true, true, false><<<dim3(64, 16), 256, 0, stream>>>(
            xnbh, w1T + wff, ffb1 + L * FFD, nullptr, nullptr, ffmid, BB * TT, FFD, DD);
        gemm_bf16<128, 64, 64, false, true, true, false, false><<<dim3(64, 8), 256, 0, stream>>>(
            ffmid, w2T + wff, ffb2 + L * DD, x2b, x2b, nullptr, BB * TT, DD, FFD);
    }

    head_kernel<<<16, 256, 0, stream>>>(x1b, x2b, lnfg, lnfb, hw1, hb1,
                                        hlng, hlnb, hw2, hb2, out);
}

// Round 13
// 938.679 us; speedup vs baseline: 1.8234x; 1.0703x over previous
//
#include <hip/hip_runtime.h>
#include <hip/hip_fp16.h>
#include <cfloat>
#include <cstdint>

// Problem constants
#define BB      16      // batch
#define TT      512     // seq
#define DD      512     // d_model
#define HH      8       // heads
#define DHH     64      // head dim
#define FFD     2048    // ff dim
#define BHH     128     // BB*HH
#define NHASH   4
#define NCHUNK  8       // NHASH * N_BUCKETS
#define CHUNKSZ 256
#define NLAYER  4

typedef unsigned short u16;
typedef unsigned int   u32;
typedef __attribute__((ext_vector_type(8))) short bfrag;    // 8 bf16 (4 VGPR)
typedef __attribute__((ext_vector_type(4))) float f4x;      // 4 f32 acc
typedef __attribute__((ext_vector_type(16))) float f16x;    // 16 f32 acc

union FragU { u32 u[4]; uint4 v4; bfrag f; };

__device__ __forceinline__ unsigned pk_bf16(float a, float b) {
    union { float f; unsigned u; } x, y;
    x.f = a; y.f = b;
    unsigned lo = ((x.u + 0x7FFFu + ((x.u >> 16) & 1u)) >> 16) & 0xFFFFu;
    unsigned hi = (y.u + 0x7FFFu + ((y.u >> 16) & 1u)) & 0xFFFF0000u;
    return lo | hi;
}
// HW packed f32->bf16 RTNE (1 VALU op; no builtin on gfx950)
__device__ __forceinline__ unsigned cvt_pk(float a, float b) {
    unsigned r;
    asm("v_cvt_pk_bf16_f32 %0, %1, %2" : "=v"(r) : "v"(a), "v"(b));
    return r;
}
// HW packed f32->f16 (RTZ) — o_hash precision (10-bit mantissa)
__device__ __forceinline__ unsigned pkrtz(float a, float b) {
    unsigned r;
    asm("v_cvt_pkrtz_f16_f32 %0, %1, %2" : "=v"(r) : "v"(a), "v"(b));
    return r;
}
__device__ __forceinline__ u16 bf16_1(float a) {
    union { float f; unsigned u; } x; x.f = a;
    return (u16)((x.u + 0x7FFFu + ((x.u >> 16) & 1u)) >> 16);
}
__device__ __forceinline__ float b2f(u16 h) {
    union { unsigned u; float f; } x; x.u = ((unsigned)h) << 16; return x.f;
}

// async global->LDS, 16B per lane (dest must be linear: base + lane*16)
__device__ __forceinline__ void gload16(const u16* g, u16* l) {
    __builtin_amdgcn_global_load_lds(
        (const __attribute__((address_space(1))) u32*)g,
        (__attribute__((address_space(3))) u32*)l, 16, 0, 0);
}

// ---------------------------------------------------------------------------
// Embedding: h = x @ emb_w + emb_b + pos ; write to both x1 and x2
__global__ __launch_bounds__(256)
void embed_kernel(const float* __restrict__ x, const float* __restrict__ ew,
                  const float* __restrict__ eb, const float* __restrict__ pos,
                  float* __restrict__ x1, float* __restrict__ x2)
{
    const int row = blockIdx.x;          // b*T + t
    const int t = row & (TT - 1);
    __shared__ float xr[32];
    if (threadIdx.x < 32) xr[threadIdx.x] = x[row * 32 + threadIdx.x];
    __syncthreads();
    for (int d = threadIdx.x; d < DD; d += 256) {
        float s = eb[d] + pos[t * DD + d];
        #pragma unroll
        for (int k = 0; k < 32; ++k) s = fmaf(xr[k], ew[k * DD + d], s);
        x1[(size_t)row * DD + d] = s;
        x2[(size_t)row * DD + d] = s;
    }
}

// ---------------------------------------------------------------------------
// LayerNorm over last dim (512); writes bf16 (always) and f32 (if out!=null).
__global__ __launch_bounds__(256)
void ln_kernel(const float* __restrict__ in, const float* __restrict__ g,
               const float* __restrict__ bta, float* __restrict__ out,
               u16* __restrict__ outh)
{
    const int row = blockIdx.x * 4 + (threadIdx.x >> 6);
    const int lane = threadIdx.x & 63;
    const float* r = in + (size_t)row * DD;
    float vals[8];
    float s = 0.0f;
    #pragma unroll
    for (int i = 0; i < 8; ++i) { vals[i] = r[i * 64 + lane]; s += vals[i]; }
    #pragma unroll
    for (int o = 1; o < 64; o <<= 1) s += __shfl_xor(s, o);
    const float mean = s * (1.0f / 512.0f);
    float vs = 0.0f;
    #pragma unroll
    for (int i = 0; i < 8; ++i) { float d = vals[i] - mean; vs += d * d; }
    #pragma unroll
    for (int o = 1; o < 64; o <<= 1) vs += __shfl_xor(vs, o);
    const float rstd = rsqrtf(vs * (1.0f / 512.0f) + 1e-5f);
    u16* hrow = outh + (size_t)row * DD;
    #pragma unroll
    for (int i = 0; i < 8; ++i) {
        const int d = i * 64 + lane;
        const float y = (vals[i] - mean) * rstd * g[d] + bta[d];
        if (out != nullptr) out[(size_t)row * DD + d] = y;
        hrow[d] = bf16_1(y);
    }
}

// ---------------------------------------------------------------------------
// Batched weight prep: transpose+bf16 ALL layers in ONE dispatch.
// wqk+wv go into a CONCATENATED wqkvT [1024][512] per layer.
__global__ __launch_bounds__(256)
void prep_weights(const float* __restrict__ wqk, const float* __restrict__ wv,
                  const float* __restrict__ wo, const float* __restrict__ ffw1,
                  const float* __restrict__ ffw2,
                  u16* __restrict__ wqkvT, u16* __restrict__ woT,
                  u16* __restrict__ w1T, u16* __restrict__ w2T)
{
    const int id = blockIdx.x;
    const float* in; u16* outp; int K, N, kt, nt;
    if (id < 3072) {                       // wqk / wv / wo : 512x512, 256 tiles/L
        const int fam = id >> 10;
        const int r = id & 1023;
        const int L = r >> 8, t = r & 255;
        K = 512; N = 512;
        const size_t off = (size_t)L * 512 * 512;
        in = (fam == 0 ? wqk : fam == 1 ? wv : wo) + off;
        outp = (fam == 2) ? (woT + off)
                          : (wqkvT + (size_t)L * 1024 * 512 + (fam == 1 ? (size_t)512 * 512 : 0));
        kt = (t & 15) << 5; nt = (t >> 4) << 5;
    } else if (id < 7168) {                // ff1: 512x2048, 1024 tiles/L
        const int r = id - 3072;
        const int L = r >> 10, t = r & 1023;
        K = 512; N = 2048;
        in = ffw1 + (size_t)L * 512 * 2048;
        outp = w1T + (size_t)L * 2048 * 512;
        kt = (t & 15) << 5; nt = (t >> 4) << 5;
    } else {                               // ff2: 2048x512, 1024 tiles/L
        const int r = id - 7168;
        const int L = r >> 10, t = r & 1023;
        K = 2048; N = 512;
        in = ffw2 + (size_t)L * 2048 * 512;
        outp = w2T + (size_t)L * 512 * 2048;
        kt = (t & 63) << 5; nt = (t >> 6) << 5;
    }
    __shared__ float tile[32][33];
    const int rr = threadIdx.x >> 3, c4 = (threadIdx.x & 7) * 4;
    const float4 v4 = *(const float4*)(in + (size_t)(kt + rr) * N + nt + c4);
    tile[rr][c4 + 0] = v4.x; tile[rr][c4 + 1] = v4.y;
    tile[rr][c4 + 2] = v4.z; tile[rr][c4 + 3] = v4.w;
    __syncthreads();
    uint2 p;
    p.x = pk_bf16(tile[c4 + 0][rr], tile[c4 + 1][rr]);
    p.y = pk_bf16(tile[c4 + 2][rr], tile[c4 + 3][rr]);
    *(uint2*)(outp + (size_t)(nt + rr) * K + kt + c4) = p;
}

// ---------------------------------------------------------------------------
// wrot[L][f][h*4+hash] = sum_d wqk[L][f][h*64+d] * rot[L][d][hash]
__global__ __launch_bounds__(256)
void wrot_kernel(const float* __restrict__ wqk, const float* __restrict__ rot,
                 float* __restrict__ wrotAll)
{
    const int hh = blockIdx.x, L = blockIdx.y;
    const int head = hh >> 2, h = hh & 3;
    __shared__ float rc[64];
    if (threadIdx.x < 64)
        rc[threadIdx.x] = rot[((size_t)L * 64 + threadIdx.x) * 4 + h];
    __syncthreads();
    for (int f = threadIdx.x; f < 512; f += 256) {
        const float* wrow = wqk + (size_t)L * 512 * 512 + (size_t)f * 512 + head * 64;
        float s = 0.0f;
        #pragma unroll
        for (int d = 0; d < 64; d += 4) {
            const float4 w4 = *(const float4*)(wrow + d);
            s += w4.x * rc[d] + w4.y * rc[d + 1] + w4.z * rc[d + 2] + w4.w * rc[d + 3];
        }
        wrotAll[((size_t)L * 512 + f) * 32 + hh] = s;
    }
}

// ---------------------------------------------------------------------------
// rotated[8192][32] = xn[8192][512] @ wrot[512][32], all f32. grid 128.
__global__ __launch_bounds__(256)
void rot_gemm(const float* __restrict__ A, const float* __restrict__ Wr,
              float* __restrict__ C)
{
    __shared__ float As[64][36];
    __shared__ float Ws[32][36];
    const int m0 = blockIdx.x * 64;
    const int r = threadIdx.x >> 2, cg = threadIdx.x & 3;
    float acc[8] = {};
    for (int f0 = 0; f0 < 512; f0 += 32) {
        __syncthreads();
        {
            const int lr = threadIdx.x >> 2, lc = (threadIdx.x & 3) * 8;
            const float* ap = A + (size_t)(m0 + lr) * 512 + f0 + lc;
            *(float4*)&As[lr][lc]     = ((const float4*)ap)[0];
            *(float4*)&As[lr][lc + 4] = ((const float4*)ap)[1];
            const int wr = threadIdx.x >> 3, wc = (threadIdx.x & 7) * 4;
            *(float4*)&Ws[wr][wc] = *(const float4*)(Wr + (size_t)(f0 + wr) * 32 + wc);
        }
        __syncthreads();
        #pragma unroll
        for (int kk = 0; kk < 32; ++kk) {
            const float a = As[r][kk];
            #pragma unroll
            for (int c = 0; c < 8; ++c)
                acc[c] = fmaf(a, Ws[kk][cg * 8 + c], acc[c]);
        }
    }
    float* crow = C + (size_t)(m0 + r) * 32 + cg * 8;
    *(float4*)crow       = make_float4(acc[0], acc[1], acc[2], acc[3]);
    *(float4*)(crow + 4) = make_float4(acc[4], acc[5], acc[6], acc[7]);
}

// ---------------------------------------------------------------------------
// bf16 MFMA GEMM, templated tile, double-buffered LDS, 2-phase pipeline.
// QKV: merged qk+v output — n0<512 routes to per-head qkh (Cb); n0>=512
// routes to row-major vbh (Cf reinterpreted as u16*).
__device__ __forceinline__ float gelu1(float v) {
    return 0.5f * v * (1.0f + erff(v * 0.70710678118654752440f));
}
__device__ __forceinline__ int swz_row(int r, int BK) {
    return (BK == 32) ? ((r & 3) ^ ((r >> 2) & 3)) : (r & 7);
}

template<int BM, int BN, int BK, bool GELU, bool ADD, bool BIAS, bool OUTBF, bool QKV>
__global__ __launch_bounds__(256)
void gemm_bf16(const u16* __restrict__ A, const u16* __restrict__ WT,
               const float* __restrict__ bias, const float* __restrict__ addsrc,
               float* __restrict__ Cf, u16* __restrict__ Cb,
               int M, int N, int K)
{
    constexpr int NCH = BK / 8;
    constexpr int CPA = BM * NCH / 256;
    constexpr int CPB = BN * NCH / 256;
    constexpr int MR = BM / 32, NR = BN / 32, KR = BK / 32;
    __shared__ __align__(16) u16 Abuf[2][BM * BK];
    __shared__ __align__(16) u16 Bbuf[2][BN * BK];
    const int tid = threadIdx.x;
    const int m0 = blockIdx.x * BM, n0 = blockIdx.y * BN;

    const u16* aSrc[CPA]; const u16* bSrc[CPB];
    #pragma unroll
    for (int i = 0; i < CPA; ++i) {
        const int s = tid + i * 256, row = s / NCH, ch = s % NCH;
        aSrc[i] = A + (size_t)(m0 + row) * K + (ch ^ swz_row(row, BK)) * 8;
    }
    #pragma unroll
    for (int i = 0; i < CPB; ++i) {
        const int s = tid + i * 256, row = s / NCH, ch = s % NCH;
        bSrc[i] = WT + (size_t)(n0 + row) * K + (ch ^ swz_row(row, BK)) * 8;
    }

    auto STAGE = [&](int bufi, int koff) {
        #pragma unroll
        for (int i = 0; i < CPA; ++i)
            gload16(aSrc[i] + koff, &Abuf[bufi][(tid + i * 256) * 8]);
        #pragma unroll
        for (int i = 0; i < CPB; ++i)
            gload16(bSrc[i] + koff, &Bbuf[bufi][(tid + i * 256) * 8]);
    };

    const int l = tid & 63, wv_ = tid >> 6;
    const int wm = (wv_ >> 1) * (BM / 2);
    const int wn = (wv_ & 1) * (BN / 2);
    const int fr = l & 15, fc = l >> 4;

    f4x acc[MR][NR] = {};
    const int nK = K / BK;
    STAGE(0, 0);
    for (int ks = 0; ks < nK; ++ks) {
        __syncthreads();
        if (ks + 1 < nK) STAGE((ks + 1) & 1, (ks + 1) * BK);
        const u16* Ab = Abuf[ks & 1];
        const u16* Bb = Bbuf[ks & 1];
        FragU af[MR][KR], bf_[NR][KR];
        #pragma unroll
        for (int i = 0; i < MR; ++i)
            #pragma unroll
            for (int u = 0; u < KR; ++u) {
                const int r = wm + i * 16 + fr;
                af[i][u].v4 = *(const uint4*)((const char*)Ab +
                    (size_t)r * (2 * BK) + (((u * 4 + fc) ^ swz_row(r, BK)) << 4));
            }
        #pragma unroll
        for (int j = 0; j < NR; ++j)
            #pragma unroll
            for (int u = 0; u < KR; ++u) {
                const int r = wn + j * 16 + fr;
                bf_[j][u].v4 = *(const uint4*)((const char*)Bb +
                    (size_t)r * (2 * BK) + (((u * 4 + fc) ^ swz_row(r, BK)) << 4));
            }
        #pragma unroll
        for (int u = 0; u < KR; ++u)
            #pragma unroll
            for (int i = 0; i < MR; ++i)
                #pragma unroll
                for (int j = 0; j < NR; ++j)
                    acc[i][j] = __builtin_amdgcn_mfma_f32_16x16x32_bf16(
                        af[i][u].f, bf_[j][u].f, acc[i][j], 0, 0, 0);
    }

    #pragma unroll
    for (int i = 0; i < MR; ++i) {
        #pragma unroll
        for (int q = 0; q < 4; ++q) {
            const int row = m0 + wm + i * 16 + fc * 4 + q;
            #pragma unroll
            for (int j = 0; j < NR; ++j) {
                const int col = n0 + wn + j * 16 + fr;
                float vx = acc[i][j][q];
                if constexpr (BIAS) vx += bias[col];
                if constexpr (GELU) vx = gelu1(vx);
                if constexpr (ADD) vx += addsrc[(size_t)row * N + col];
                if constexpr (QKV) {
                    if (n0 < 512) {   // qk half -> per-head layout [(b*8+h)][t][d]
                        const int bq = row >> 9, tq = row & 511;
                        const int hq = col >> 6, dq = col & 63;
                        Cb[(((size_t)(bq * 8 + hq) * 512) + tq) * 64 + dq] = bf16_1(vx);
                    } else {          // v half -> row-major [row][512]
                        ((u16*)Cf)[(size_t)row * 512 + (col - 512)] = bf16_1(vx);
                    }
                } else if constexpr (OUTBF) {
                    Cb[(size_t)row * N + col] = bf16_1(vx);
                } else {
                    Cf[(size_t)row * N + col] = vx;
                }
            }
        }
    }
}

// ---------------------------------------------------------------------------
// K/Q pre-normalization from bf16 qkh: qkn = bf16(row/|row|), qnrm = |row|.
__global__ __launch_bounds__(256)
void knorm_kernel(const u16* __restrict__ qkh, u16* __restrict__ qkn,
                  float* __restrict__ qnrm)
{
    const int g = blockIdx.x * 16 + (threadIdx.x >> 4);  // bh*T + t
    const int li = threadIdx.x & 15;
    const uint2 raw = *(const uint2*)(qkh + (size_t)g * 64 + li * 4);
    const float v0 = b2f((u16)(raw.x & 0xffff)), v1 = b2f((u16)(raw.x >> 16));
    const float v2 = b2f((u16)(raw.y & 0xffff)), v3 = b2f((u16)(raw.y >> 16));
    float ss = v0 * v0 + v1 * v1 + v2 * v2 + v3 * v3;
    ss += __shfl_xor(ss, 1); ss += __shfl_xor(ss, 2);
    ss += __shfl_xor(ss, 4); ss += __shfl_xor(ss, 8);
    const float qn = sqrtf(ss);
    const float rv = 1.0f / fmaxf(qn, 1e-12f);
    uint2 o;
    o.x = cvt_pk(v0 * rv, v1 * rv);
    o.y = cvt_pk(v2 * rv, v3 * rv);
    *(uint2*)(qkn + (size_t)g * 64 + li * 4) = o;
    if (li == 0) qnrm[g] = qn;
}

// ---------------------------------------------------------------------------
// Bucket assignment + stable partition from precomputed rotated (f32)
__global__ __launch_bounds__(512)
void bucket_sort_kernel(const float* __restrict__ rotated, int* __restrict__ st)
{
    const int h = blockIdx.x, bh = blockIdx.y;
    const int b = bh >> 3, head = bh & 7;
    const int t = threadIdx.x;
    __shared__ int zcnt[8];
    const float r = rotated[((size_t)(b * TT + t)) * 32 + head * 4 + h];
    const int bit = (r < 0.0f) ? 1 : 0;
    const int wid = t >> 6, lane = t & 63;
    const unsigned long long zm = __ballot(bit == 0);
    if (lane == 0) zcnt[wid] = __popcll(zm);
    __syncthreads();
    int zoff = 0, Z = 0;
    #pragma unroll
    for (int w = 0; w < 8; ++w) { const int cn = zcnt[w]; if (w < wid) zoff += cn; Z += cn; }
    const int zpre = __popcll(zm & ((1ull << lane) - 1ull));
    const int dst = (bit == 0) ? (zoff + zpre)
                               : (Z + (wid * 64 - zoff) + (lane - zpre));
    st[((size_t)bh * NHASH + h) * TT + dst] = t;
}

// ---------------------------------------------------------------------------
// MFMA LSH attention — EXACT R8 body (924us best): 8 waves x 32 queries,
// double-buffered LDS (1 barrier/tile), bit-reversed V^T slot rotation,
// single lacc accumulator (R9's lac0/lac1 split caused scratch spills:
// +34MB traffic/dispatch), no setprio (R11: spill trigger).
__global__ __launch_bounds__(512, 4)
void lsh_attn_mfma(const u16* __restrict__ qkn, const u16* __restrict__ v,
                   const float* __restrict__ qnrm, const int* __restrict__ st,
                   __half* __restrict__ o_hash, float* __restrict__ lse_hash)
{
    const int cc = blockIdx.x, bh = blockIdx.y;
    const int b = bh >> 3, head = bh & 7;
    const int h = cc >> 1, c = cc & 1;
    const int pcc = (cc + 7) & 7;
    const int hp = pcc >> 1, cp = pcc & 1;
    const int tid = threadIdx.x;
    const int w = tid >> 6;          // wave 0..7 -> queries w*32..+32
    const int lane = tid & 63;
    const int l31 = lane & 31;
    const int hi = lane >> 5;
    const int* stb = st + (size_t)bh * (NHASH * TT);
    const size_t vbase = ((size_t)b * TT) * DD + head * DHH;
    const u16* qknb = qkn + (size_t)bh * TT * DHH;

    __shared__ __align__(16) u16 Kbf[2][64 * 64];
    __shared__ __align__(16) u16 VTbf[2][64 * 64];
    __shared__ __align__(16) int ktl[2][64];

    // ---- Q fragment (one query per lane-column) ----
    const int q_t = stb[h * TT + c * CHUNKSZ + w * 32 + l31];
    const float qn = qnrm[(size_t)bh * TT + q_t];
    const float mnat = qn * 0.125f;
    const float aC = qn * 0.1803368801111137f;   // |q| * 0.125 * log2(e)
    uint4 QF4[4];
    {
        const u16* qrow = qknb + (size_t)q_t * DHH;
        #pragma unroll
        for (int ds = 0; ds < 4; ++ds)
            QF4[ds] = *(const uint4*)(qrow + ds * 16 + hi * 8);
    }

    f16x acc[2] = {};           // [dt] O^T tiles (32d x 32q)
    float lacc = 0.f;
    const int k8 = tid >> 3;    // key row 0..63 (8 lanes per 128B row)
    const int c8 = tid & 7;     // 16B chunk of the row
    // bit-reversed slot bases (constant per thread)
    const int brc = ((c8 & 1) << 2) | (c8 & 2) | ((c8 & 4) >> 2);   // bitrev3(c8)
    const int wSlot = ((k8 >> 3) + brc) & 7;                        // V write slot
    const int g2 = l31 >> 3;                                        // read row group
    const int brg = ((g2 & 1) << 2) | (g2 & 2);                     // bitrev3(g2), g2<4

    auto gather = [&](int t8, uint4& kc, uint4& vc, int& ktc) {
        const int kj = t8 * 64 + k8;
        const int k_t = (kj < CHUNKSZ) ? stb[h * TT + c * CHUNKSZ + kj]
                                       : stb[hp * TT + cp * CHUNKSZ + (kj - CHUNKSZ)];
        ktc = k_t;
        kc = *(const uint4*)(qknb + (size_t)k_t * DHH + c8 * 8);
        vc = *(const uint4*)(v + vbase + (size_t)k_t * DD + c8 * 8);
    };
    auto writeTile = [&](int bi, const uint4& kc, const uint4& vc, int ktc) {
        *(uint4*)((char*)Kbf[bi] + ((k8 * 128 + c8 * 16) ^ ((k8 & 7) << 4))) = kc;
        const unsigned vu[4] = {vc.x, vc.y, vc.z, vc.w};
        #pragma unroll
        for (int i = 0; i < 8; ++i) {
            const int d = c8 * 8 + i;
            const u16 hv = (u16)((i & 1) ? (vu[i >> 1] >> 16) : (vu[i >> 1] & 0xffff));
            *(u16*)((char*)VTbf[bi] + d * 128 + wSlot * 16 + (k8 & 7) * 2) = hv;
        }
        if (c8 == 0) ktl[bi][k8] = ktc;
    };

    uint4 kc, vc; int ktc;
    gather(0, kc, vc, ktc);
    writeTile(0, kc, vc, ktc);
    __syncthreads();

    for (int kt8 = 0; kt8 < 8; ++kt8) {
        const int cur = kt8 & 1;
        if (kt8 < 7) gather(kt8 + 1, kc, vc, ktc);
        const u16* Kb = Kbf[cur];
        const u16* Vb = VTbf[cur];
        const int* kl = ktl[cur];

        #pragma unroll
        for (int kt = 0; kt < 2; ++kt) {
            int4 kt4[4];
            #pragma unroll
            for (int j = 0; j < 4; ++j)
                kt4[j] = *(const int4*)&kl[kt * 32 + 8 * j + 4 * hi];
            const int* ktvp = (const int*)kt4;
            FragU KA[4];
            #pragma unroll
            for (int ds = 0; ds < 4; ++ds) {
                const int row = kt * 32 + l31;
                KA[ds].v4 = *(const uint4*)((const char*)Kb +
                    ((row * 128 + ds * 32 + hi * 16) ^ ((row & 7) << 4)));
            }
            FragU VA[2][2];
            #pragma unroll
            for (int dt = 0; dt < 2; ++dt)
                #pragma unroll
                for (int u = 0; u < 2; ++u) {
                    const int row = dt * 32 + l31;
                    const int cr = (kt * 2 + u) * 2 + hi;
                    const int slot = (cr + brg + dt) & 7;    // bitrev3(row>>3)=brg+dt
                    VA[dt][u].v4 = *(const uint4*)((const char*)Vb +
                        row * 128 + slot * 16);
                }
            f16x s = {0.f,0.f,0.f,0.f,0.f,0.f,0.f,0.f,
                      0.f,0.f,0.f,0.f,0.f,0.f,0.f,0.f};
            #pragma unroll
            for (int ds = 0; ds < 4; ++ds) {
                FragU qf; qf.v4 = QF4[ds];
                s = __builtin_amdgcn_mfma_f32_32x32x16_bf16(KA[ds].f, qf.f, s, 0, 0, 0);
            }
            float pv[16];
            #pragma unroll
            for (int i = 0; i < 16; ++i) {
                const float e = exp2f(fmaf(s[i], aC, -aC));   // exp(qn/8*(s-1))
                const float p = (q_t > ktvp[i]) ? e : 0.0f;
                pv[i] = p;
                lacc += p;
            }
            unsigned P2[8];
            #pragma unroll
            for (int g = 0; g < 4; ++g) {
                P2[2*g]   = cvt_pk(pv[4*g],   pv[4*g+1]);
                P2[2*g+1] = cvt_pk(pv[4*g+2], pv[4*g+3]);
            }
            #pragma unroll
            for (int u = 0; u < 2; ++u) {
                unsigned a0 = P2[4*u + 0], b0 = P2[4*u + 2];
                unsigned a1 = P2[4*u + 1], b1 = P2[4*u + 3];
                asm("v_permlane32_swap_b32 %0, %1" : "+v"(a0), "+v"(b0));
                asm("v_permlane32_swap_b32 %0, %1" : "+v"(a1), "+v"(b1));
                FragU bfv;
                bfv.u[0] = a0; bfv.u[1] = a1; bfv.u[2] = b0; bfv.u[3] = b1;
                #pragma unroll
                for (int dt = 0; dt < 2; ++dt)
                    acc[dt] = __builtin_amdgcn_mfma_f32_32x32x16_bf16(
                        VA[dt][u].f, bfv.f, acc[dt], 0, 0, 0);
            }
        }

        if (kt8 < 7) {
            writeTile(cur ^ 1, kc, vc, ktc);
            __syncthreads();
        }
    }

    // ---- finalize: l, lse, register-only epilogue ----
    const float lt = lacc + __shfl_xor(lacc, 32);
    const float invl = (lt > 0.f) ? 1.0f / lt : 0.0f;
    if (hi == 0) {
        const float lse = (lt > 0.f) ? (mnat + logf(lt)) : -5.0e4f;
        lse_hash[(size_t)(bh * NHASH + h) * TT + q_t] = lse;
    }
    unsigned wa[8], wb[8];
    #pragma unroll
    for (int m = 0; m < 8; ++m) {
        wa[m] = pkrtz(acc[0][2*m] * invl, acc[0][2*m+1] * invl);
        wb[m] = pkrtz(acc[1][2*m] * invl, acc[1][2*m+1] * invl);
    }
    #pragma unroll
    for (int m = 0; m < 8; ++m)
        asm("v_permlane32_swap_b32 %0, %1" : "+v"(wa[m]), "+v"(wb[m]));
    __half* orow = o_hash + ((size_t)(bh * NHASH + h) * TT + q_t) * DHH + hi * 32;
    if (lt > 0.f) {
        #pragma unroll
        for (int g = 0; g < 4; ++g) {
            uint4 o;
            o.x = wa[2*g]; o.y = wa[2*g+1];
            o.z = wb[2*g]; o.w = wb[2*g+1];
            ((uint4*)orow)[g] = o;
        }
    } else {
        const u16* vr = v + vbase + (size_t)q_t * DD + hi * 32;
        #pragma unroll
        for (int g = 0; g < 4; ++g) {
            uint4 o;
            o.x = pkrtz(b2f(vr[8*g+0]), b2f(vr[8*g+1]));
            o.y = pkrtz(b2f(vr[8*g+2]), b2f(vr[8*g+3]));
            o.z = pkrtz(b2f(vr[8*g+4]), b2f(vr[8*g+5]));
            o.w = pkrtz(b2f(vr[8*g+6]), b2f(vr[8*g+7]));
            ((uint4*)orow)[g] = o;
        }
    }
}

// ---------------------------------------------------------------------------
// Combine hash rounds: read o_hash f16, write merged bf16 (wo GEMM A-operand)
__global__ __launch_bounds__(256)
void combine_kernel(const __half* __restrict__ o_hash, const float* __restrict__ lse_hash,
                    u16* __restrict__ am)
{
    const int idx = blockIdx.x * 4 + (threadIdx.x >> 6);
    const int lane = threadIdx.x & 63;
    const int bh = idx >> 9, t = idx & 511;
    const int b = bh >> 3, head = bh & 7;
    const float ls0 = lse_hash[(size_t)(bh * NHASH + 0) * TT + t];
    const float ls1 = lse_hash[(size_t)(bh * NHASH + 1) * TT + t];
    const float ls2 = lse_hash[(size_t)(bh * NHASH + 2) * TT + t];
    const float ls3 = lse_hash[(size_t)(bh * NHASH + 3) * TT + t];
    const float M = fmaxf(fmaxf(ls0, ls1), fmaxf(ls2, ls3));
    const float e0 = __expf(ls0 - M), e1 = __expf(ls1 - M);
    const float e2 = __expf(ls2 - M), e3 = __expf(ls3 - M);
    const float inv = 1.0f / (e0 + e1 + e2 + e3);
    const float o =
        (e0 * __half2float(o_hash[((size_t)((bh * NHASH + 0) * TT + t)) * DHH + lane]) +
         e1 * __half2float(o_hash[((size_t)((bh * NHASH + 1) * TT + t)) * DHH + lane]) +
         e2 * __half2float(o_hash[((size_t)((bh * NHASH + 2) * TT + t)) * DHH + lane]) +
         e3 * __half2float(o_hash[((size_t)((bh * NHASH + 3) * TT + t)) * DHH + lane])) * inv;
    am[((size_t)(b * TT + t)) * DD + head * DHH + lane] = bf16_1(o);
}

// ---------------------------------------------------------------------------
// Final head
__device__ __forceinline__ float block_sum256(float v, volatile float* red)
{
    const int lane = threadIdx.x & 63, wid = threadIdx.x >> 6;
    #pragma unroll
    for (int o = 1; o < 64; o <<= 1) v += __shfl_xor(v, o);
    __syncthreads();
    if (lane == 0) red[wid] = v;
    __syncthreads();
    return red[0] + red[1] + red[2] + red[3];
}

__global__ __launch_bounds__(256)
void head_kernel(const float* __restrict__ x1, const float* __restrict__ x2,
                 const float* __restrict__ lnfg, const float* __restrict__ lnfb,
                 const float* __restrict__ hw1, const float* __restrict__ hb1,
                 const float* __restrict__ hlng, const float* __restrict__ hlnb,
                 const float* __restrict__ hw2, const float* __restrict__ hb2,
                 float* __restrict__ out)
{
    __shared__ float nrow[512];
    __shared__ float red[4];
    const int b = blockIdx.x, tid = threadIdx.x;
    const size_t roff = ((size_t)b * TT + (TT - 1)) * DD;
    const float v0 = 0.5f * (x1[roff + tid] + x2[roff + tid]);
    const float v1 = 0.5f * (x1[roff + 256 + tid] + x2[roff + 256 + tid]);
    const float mean = block_sum256(v0 + v1, red) * (1.0f / 512.0f);
    const float d0 = v0 - mean, d1 = v1 - mean;
    const float var = block_sum256(d0 * d0 + d1 * d1, red) * (1.0f / 512.0f);
    const float rstd = rsqrtf(var + 1e-5f);
    nrow[tid]       = d0 * rstd * lnfg[tid] + lnfb[tid];
    nrow[tid + 256] = d1 * rstd * lnfg[tid + 256] + lnfb[tid + 256];
    __syncthreads();
    float a = hb1[tid];
    for (int k = 0; k < 512; ++k) a = fmaf(nrow[k], hw1[(size_t)k * 256 + tid], a);
    const float m2 = block_sum256(a, red) * (1.0f / 256.0f);
    const float dd = a - m2;
    const float var2 = block_sum256(dd * dd, red) * (1.0f / 256.0f);
    float y = dd * rsqrtf(var2 + 1e-5f) * hlng[tid] + hlnb[tid];
    y = fmaxf(y, 0.0f);
    const float osum = block_sum256(y * hw2[tid], red);
    if (tid == 0) out[b] = osum + hb2[0];
}

// ---------------------------------------------------------------------------
extern "C" void kernel_launch(void* const* d_in, const int* in_sizes, int n_in,
                              void* d_out, int out_size, void* d_ws, size_t ws_size,
                              hipStream_t stream)
{
    (void)in_sizes; (void)n_in; (void)out_size; (void)ws_size;
    const float* x    = (const float*)d_in[0];
    const float* embw = (const float*)d_in[1];
    const float* embb = (const float*)d_in[2];
    const float* pos  = (const float*)d_in[3];
    const float* ln1g = (const float*)d_in[4];
    const float* ln1b = (const float*)d_in[5];
    const float* wqk  = (const float*)d_in[6];
    const float* wv   = (const float*)d_in[7];
    const float* wo   = (const float*)d_in[8];
    const float* wob  = (const float*)d_in[9];
    const float* ln2g = (const float*)d_in[10];
    const float* ln2b = (const float*)d_in[11];
    const float* ffw1 = (const float*)d_in[12];
    const float* ffb1 = (const float*)d_in[13];
    const float* ffw2 = (const float*)d_in[14];
    const float* ffb2 = (const float*)d_in[15];
    const float* rot  = (const float*)d_in[16];
    const float* lnfg = (const float*)d_in[17];
    const float* lnfb = (const float*)d_in[18];
    const float* hw1  = (const float*)d_in[19];
    const float* hb1  = (const float*)d_in[20];
    const float* hlng = (const float*)d_in[21];
    const float* hlnb = (const float*)d_in[22];
    const float* hw2  = (const float*)d_in[23];
    const float* hb2  = (const float*)d_in[24];
    float* out = (float*)d_out;

    const size_t SZ_BTD = (size_t)BB * TT * DD;            // 4,194,304
    const size_t SZ_OH  = (size_t)BHH * NHASH * TT * DHH;  // 16,777,216

    char* p = (char*)d_ws;
    float* x1b = (float*)p;  p += SZ_BTD * 4;
    float* x2b = (float*)p;  p += SZ_BTD * 4;
    float* xnb = (float*)p;  p += SZ_BTD * 4;              // also amb (bf16) late
    u16*   vbh = (u16*)p;    p += SZ_BTD * 2;
    u16*   xnbh = (u16*)p;   p += SZ_BTD * 2;
    u16*   qkh  = (u16*)p;   p += SZ_BTD * 2;              // bf16 qk, per-head layout
    u16*   qknb = (u16*)p;   p += (size_t)BHH * TT * DHH * 2;
    float* qnrm = (float*)p; p += (size_t)BHH * TT * 4;
    float* rotated = (float*)p; p += (size_t)BB * TT * 32 * 4;
    __half* ohash = (__half*)p;                  // 33.5MB region
    u16*    ffmid = (u16*)p;                     // temporal alias (disjoint life)
    p += SZ_OH * 2;
    float* lseb  = (float*)p; p += (size_t)BHH * NHASH * TT * 4;
    int*   stb   = (int*)p;   p += (size_t)BHH * NHASH * TT * 4;
    u16* wqkvT = (u16*)p; p += (size_t)NLAYER * 1024 * 512 * 2;
    u16* woT   = (u16*)p; p += (size_t)NLAYER * DD * DD * 2;
    u16* w1T   = (u16*)p; p += (size_t)NLAYER * DD * FFD * 2;
    u16* w2T   = (u16*)p; p += (size_t)NLAYER * FFD * DD * 2;
    float* wrotAll = (float*)p; p += (size_t)NLAYER * DD * 32 * 4;
    u16* amb = (u16*)xnb;                        // alias (xnb dead after GEMMs)

    // ---- one-time weight prep (all layers) ----
    prep_weights<<<11264, 256, 0, stream>>>(wqk, wv, wo, ffw1, ffw2,
                                            wqkvT, woT, w1T, w2T);
    wrot_kernel<<<dim3(32, NLAYER), 256, 0, stream>>>(wqk, rot, wrotAll);

    embed_kernel<<<BB * TT, 256, 0, stream>>>(x, embw, embb, pos, x1b, x2b);

    for (int L = 0; L < NLAYER; ++L) {
        const size_t w512 = (size_t)L * DD * DD;
        const size_t wff  = (size_t)L * DD * FFD;

        // x1 += attn(ln(x2))
        ln_kernel<<<2048, 256, 0, stream>>>(x2b, ln1g + L * DD, ln1b + L * DD, xnb, xnbh);
        rot_gemm<<<128, 256, 0, stream>>>(xnb, wrotAll + (size_t)L * DD * 32, rotated);
        gemm_bf16<128, 128, 32, false, false, false, false, true><<<dim3(64, 8), 256, 0, stream>>>(
            xnbh, wqkvT + (size_t)L * 1024 * 512, nullptr, nullptr,
            (float*)vbh, qkh, BB * TT, 1024, DD);
        bucket_sort_kernel<<<dim3(NHASH, BHH), 512, 0, stream>>>(rotated, stb);
        knorm_kernel<<<4096, 256, 0, stream>>>(qkh, qknb, qnrm);
        lsh_attn_mfma<<<dim3(NCHUNK, BHH), 512, 0, stream>>>(
            qknb, vbh, qnrm, stb, ohash, lseb);
        combine_kernel<<<16384, 256, 0, stream>>>(ohash, lseb, amb);
        gemm_bf16<128, 64, 64, false, true, true, false, false><<<dim3(64, 8), 256, 0, stream>>>(
            amb, woT + w512, wob + L * DD, x1b, x1b, nullptr, BB * TT, DD, DD);

        // x2 += ff(ln(x1))
        ln_kernel<<<2048, 256, 0, stream>>>(x1b, ln2g + L * DD, ln2b + L * DD, nullptr, xnbh);
        gemm_bf16<128, 128, 32, true, false, true, true, false><<<dim3(64, 16), 256, 0, stream>>>(
            xnbh, w1T + wff, ffb1 + L * FFD, nullptr, nullptr, ffmid, BB * TT, FFD, DD);
        gemm_bf16<128, 64, 64, false, true, true, false, false><<<dim3(64, 8), 256, 0, stream>>>(
            ffmid, w2T + wff, ffb2 + L * DD, x2b, x2b, nullptr, BB * TT, DD, FFD);
    }

    head_kernel<<<16, 256, 0, stream>>>(x1b, x2b, lnfg, lnfb, hw1, hb1,
                                        hlng, hlnb, hw2, hb2, out);
}

// Round 14
// 918.888 us; speedup vs baseline: 1.8626x; 1.0215x over previous
//
#include <hip/hip_runtime.h>
#include <hip/hip_fp16.h>
#include <cfloat>
#include <cstdint>

// Problem constants
#define BB      16      // batch
#define TT      512     // seq
#define DD      512     // d_model
#define HH      8       // heads
#define DHH     64      // head dim
#define FFD     2048    // ff dim
#define BHH     128     // BB*HH
#define NHASH   4
#define NCHUNK  8       // NHASH * N_BUCKETS
#define CHUNKSZ 256
#define NLAYER  4

typedef unsigned short u16;
typedef unsigned int   u32;
typedef __attribute__((ext_vector_type(8))) short bfrag;    // 8 bf16 (4 VGPR)
typedef __attribute__((ext_vector_type(4))) float f4x;      // 4 f32 acc
typedef __attribute__((ext_vector_type(16))) float f16x;    // 16 f32 acc

union FragU { u32 u[4]; uint4 v4; bfrag f; };

__device__ __forceinline__ unsigned pk_bf16(float a, float b) {
    union { float f; unsigned u; } x, y;
    x.f = a; y.f = b;
    unsigned lo = ((x.u + 0x7FFFu + ((x.u >> 16) & 1u)) >> 16) & 0xFFFFu;
    unsigned hi = (y.u + 0x7FFFu + ((y.u >> 16) & 1u)) & 0xFFFF0000u;
    return lo | hi;
}
// HW packed f32->bf16 RTNE (1 VALU op; no builtin on gfx950)
__device__ __forceinline__ unsigned cvt_pk(float a, float b) {
    unsigned r;
    asm("v_cvt_pk_bf16_f32 %0, %1, %2" : "=v"(r) : "v"(a), "v"(b));
    return r;
}
// HW packed f32->f16 (RTZ) — o_hash precision (10-bit mantissa)
__device__ __forceinline__ unsigned pkrtz(float a, float b) {
    unsigned r;
    asm("v_cvt_pkrtz_f16_f32 %0, %1, %2" : "=v"(r) : "v"(a), "v"(b));
    return r;
}
__device__ __forceinline__ u16 bf16_1(float a) {
    union { float f; unsigned u; } x; x.f = a;
    return (u16)((x.u + 0x7FFFu + ((x.u >> 16) & 1u)) >> 16);
}
__device__ __forceinline__ float b2f(u16 h) {
    union { unsigned u; float f; } x; x.u = ((unsigned)h) << 16; return x.f;
}

// async global->LDS, 16B per lane (dest must be linear: base + lane*16)
__device__ __forceinline__ void gload16(const u16* g, u16* l) {
    __builtin_amdgcn_global_load_lds(
        (const __attribute__((address_space(1))) u32*)g,
        (__attribute__((address_space(3))) u32*)l, 16, 0, 0);
}

// ---------------------------------------------------------------------------
// Embedding: h = x @ emb_w + emb_b + pos ; write to both x1 and x2
__global__ __launch_bounds__(256)
void embed_kernel(const float* __restrict__ x, const float* __restrict__ ew,
                  const float* __restrict__ eb, const float* __restrict__ pos,
                  float* __restrict__ x1, float* __restrict__ x2)
{
    const int row = blockIdx.x;          // b*T + t
    const int t = row & (TT - 1);
    __shared__ float xr[32];
    if (threadIdx.x < 32) xr[threadIdx.x] = x[row * 32 + threadIdx.x];
    __syncthreads();
    for (int d = threadIdx.x; d < DD; d += 256) {
        float s = eb[d] + pos[t * DD + d];
        #pragma unroll
        for (int k = 0; k < 32; ++k) s = fmaf(xr[k], ew[k * DD + d], s);
        x1[(size_t)row * DD + d] = s;
        x2[(size_t)row * DD + d] = s;
    }
}

// ---------------------------------------------------------------------------
// LayerNorm over last dim (512); writes bf16 (always) and f32 (if out!=null).
__global__ __launch_bounds__(256)
void ln_kernel(const float* __restrict__ in, const float* __restrict__ g,
               const float* __restrict__ bta, float* __restrict__ out,
               u16* __restrict__ outh)
{
    const int row = blockIdx.x * 4 + (threadIdx.x >> 6);
    const int lane = threadIdx.x & 63;
    const float* r = in + (size_t)row * DD;
    float vals[8];
    float s = 0.0f;
    #pragma unroll
    for (int i = 0; i < 8; ++i) { vals[i] = r[i * 64 + lane]; s += vals[i]; }
    #pragma unroll
    for (int o = 1; o < 64; o <<= 1) s += __shfl_xor(s, o);
    const float mean = s * (1.0f / 512.0f);
    float vs = 0.0f;
    #pragma unroll
    for (int i = 0; i < 8; ++i) { float d = vals[i] - mean; vs += d * d; }
    #pragma unroll
    for (int o = 1; o < 64; o <<= 1) vs += __shfl_xor(vs, o);
    const float rstd = rsqrtf(vs * (1.0f / 512.0f) + 1e-5f);
    u16* hrow = outh + (size_t)row * DD;
    #pragma unroll
    for (int i = 0; i < 8; ++i) {
        const int d = i * 64 + lane;
        const float y = (vals[i] - mean) * rstd * g[d] + bta[d];
        if (out != nullptr) out[(size_t)row * DD + d] = y;
        hrow[d] = bf16_1(y);
    }
}

// ---------------------------------------------------------------------------
// Batched weight prep: transpose+bf16 ALL layers in ONE dispatch.
// wqk+wv go into a CONCATENATED wqkvT [1024][512] per layer.
__global__ __launch_bounds__(256)
void prep_weights(const float* __restrict__ wqk, const float* __restrict__ wv,
                  const float* __restrict__ wo, const float* __restrict__ ffw1,
                  const float* __restrict__ ffw2,
                  u16* __restrict__ wqkvT, u16* __restrict__ woT,
                  u16* __restrict__ w1T, u16* __restrict__ w2T)
{
    const int id = blockIdx.x;
    const float* in; u16* outp; int K, N, kt, nt;
    if (id < 3072) {                       // wqk / wv / wo : 512x512, 256 tiles/L
        const int fam = id >> 10;
        const int r = id & 1023;
        const int L = r >> 8, t = r & 255;
        K = 512; N = 512;
        const size_t off = (size_t)L * 512 * 512;
        in = (fam == 0 ? wqk : fam == 1 ? wv : wo) + off;
        outp = (fam == 2) ? (woT + off)
                          : (wqkvT + (size_t)L * 1024 * 512 + (fam == 1 ? (size_t)512 * 512 : 0));
        kt = (t & 15) << 5; nt = (t >> 4) << 5;
    } else if (id < 7168) {                // ff1: 512x2048, 1024 tiles/L
        const int r = id - 3072;
        const int L = r >> 10, t = r & 1023;
        K = 512; N = 2048;
        in = ffw1 + (size_t)L * 512 * 2048;
        outp = w1T + (size_t)L * 2048 * 512;
        kt = (t & 15) << 5; nt = (t >> 4) << 5;
    } else {                               // ff2: 2048x512, 1024 tiles/L
        const int r = id - 7168;
        const int L = r >> 10, t = r & 1023;
        K = 2048; N = 512;
        in = ffw2 + (size_t)L * 2048 * 512;
        outp = w2T + (size_t)L * 512 * 2048;
        kt = (t & 63) << 5; nt = (t >> 6) << 5;
    }
    __shared__ float tile[32][33];
    const int rr = threadIdx.x >> 3, c4 = (threadIdx.x & 7) * 4;
    const float4 v4 = *(const float4*)(in + (size_t)(kt + rr) * N + nt + c4);
    tile[rr][c4 + 0] = v4.x; tile[rr][c4 + 1] = v4.y;
    tile[rr][c4 + 2] = v4.z; tile[rr][c4 + 3] = v4.w;
    __syncthreads();
    uint2 p;
    p.x = pk_bf16(tile[c4 + 0][rr], tile[c4 + 1][rr]);
    p.y = pk_bf16(tile[c4 + 2][rr], tile[c4 + 3][rr]);
    *(uint2*)(outp + (size_t)(nt + rr) * K + kt + c4) = p;
}

// ---------------------------------------------------------------------------
// wrot[L][f][h*4+hash] = sum_d wqk[L][f][h*64+d] * rot[L][d][hash]
__global__ __launch_bounds__(256)
void wrot_kernel(const float* __restrict__ wqk, const float* __restrict__ rot,
                 float* __restrict__ wrotAll)
{
    const int hh = blockIdx.x, L = blockIdx.y;
    const int head = hh >> 2, h = hh & 3;
    __shared__ float rc[64];
    if (threadIdx.x < 64)
        rc[threadIdx.x] = rot[((size_t)L * 64 + threadIdx.x) * 4 + h];
    __syncthreads();
    for (int f = threadIdx.x; f < 512; f += 256) {
        const float* wrow = wqk + (size_t)L * 512 * 512 + (size_t)f * 512 + head * 64;
        float s = 0.0f;
        #pragma unroll
        for (int d = 0; d < 64; d += 4) {
            const float4 w4 = *(const float4*)(wrow + d);
            s += w4.x * rc[d] + w4.y * rc[d + 1] + w4.z * rc[d + 2] + w4.w * rc[d + 3];
        }
        wrotAll[((size_t)L * 512 + f) * 32 + hh] = s;
    }
}

// ---------------------------------------------------------------------------
// rotated[8192][32] = xn[8192][512] @ wrot[512][32], all f32. grid 128.
__global__ __launch_bounds__(256)
void rot_gemm(const float* __restrict__ A, const float* __restrict__ Wr,
              float* __restrict__ C)
{
    __shared__ float As[64][36];
    __shared__ float Ws[32][36];
    const int m0 = blockIdx.x * 64;
    const int r = threadIdx.x >> 2, cg = threadIdx.x & 3;
    float acc[8] = {};
    for (int f0 = 0; f0 < 512; f0 += 32) {
        __syncthreads();
        {
            const int lr = threadIdx.x >> 2, lc = (threadIdx.x & 3) * 8;
            const float* ap = A + (size_t)(m0 + lr) * 512 + f0 + lc;
            *(float4*)&As[lr][lc]     = ((const float4*)ap)[0];
            *(float4*)&As[lr][lc + 4] = ((const float4*)ap)[1];
            const int wr = threadIdx.x >> 3, wc = (threadIdx.x & 7) * 4;
            *(float4*)&Ws[wr][wc] = *(const float4*)(Wr + (size_t)(f0 + wr) * 32 + wc);
        }
        __syncthreads();
        #pragma unroll
        for (int kk = 0; kk < 32; ++kk) {
            const float a = As[r][kk];
            #pragma unroll
            for (int c = 0; c < 8; ++c)
                acc[c] = fmaf(a, Ws[kk][cg * 8 + c], acc[c]);
        }
    }
    float* crow = C + (size_t)(m0 + r) * 32 + cg * 8;
    *(float4*)crow       = make_float4(acc[0], acc[1], acc[2], acc[3]);
    *(float4*)(crow + 4) = make_float4(acc[4], acc[5], acc[6], acc[7]);
}

// ---------------------------------------------------------------------------
// bf16 MFMA GEMM, templated tile, double-buffered LDS, 2-phase pipeline.
// QKV: merged qk+v output — n0<512 routes to per-head qkh (Cb); n0>=512
// routes to row-major vbh (Cf reinterpreted as u16*).
__device__ __forceinline__ float gelu1(float v) {
    return 0.5f * v * (1.0f + erff(v * 0.70710678118654752440f));
}
__device__ __forceinline__ int swz_row(int r, int BK) {
    return (BK == 32) ? ((r & 3) ^ ((r >> 2) & 3)) : (r & 7);
}

template<int BM, int BN, int BK, bool GELU, bool ADD, bool BIAS, bool OUTBF, bool QKV>
__global__ __launch_bounds__(256)
void gemm_bf16(const u16* __restrict__ A, const u16* __restrict__ WT,
               const float* __restrict__ bias, const float* __restrict__ addsrc,
               float* __restrict__ Cf, u16* __restrict__ Cb,
               int M, int N, int K)
{
    constexpr int NCH = BK / 8;
    constexpr int CPA = BM * NCH / 256;
    constexpr int CPB = BN * NCH / 256;
    constexpr int MR = BM / 32, NR = BN / 32, KR = BK / 32;
    __shared__ __align__(16) u16 Abuf[2][BM * BK];
    __shared__ __align__(16) u16 Bbuf[2][BN * BK];
    const int tid = threadIdx.x;
    const int m0 = blockIdx.x * BM, n0 = blockIdx.y * BN;

    const u16* aSrc[CPA]; const u16* bSrc[CPB];
    #pragma unroll
    for (int i = 0; i < CPA; ++i) {
        const int s = tid + i * 256, row = s / NCH, ch = s % NCH;
        aSrc[i] = A + (size_t)(m0 + row) * K + (ch ^ swz_row(row, BK)) * 8;
    }
    #pragma unroll
    for (int i = 0; i < CPB; ++i) {
        const int s = tid + i * 256, row = s / NCH, ch = s % NCH;
        bSrc[i] = WT + (size_t)(n0 + row) * K + (ch ^ swz_row(row, BK)) * 8;
    }

    auto STAGE = [&](int bufi, int koff) {
        #pragma unroll
        for (int i = 0; i < CPA; ++i)
            gload16(aSrc[i] + koff, &Abuf[bufi][(tid + i * 256) * 8]);
        #pragma unroll
        for (int i = 0; i < CPB; ++i)
            gload16(bSrc[i] + koff, &Bbuf[bufi][(tid + i * 256) * 8]);
    };

    const int l = tid & 63, wv_ = tid >> 6;
    const int wm = (wv_ >> 1) * (BM / 2);
    const int wn = (wv_ & 1) * (BN / 2);
    const int fr = l & 15, fc = l >> 4;

    f4x acc[MR][NR] = {};
    const int nK = K / BK;
    STAGE(0, 0);
    for (int ks = 0; ks < nK; ++ks) {
        __syncthreads();
        if (ks + 1 < nK) STAGE((ks + 1) & 1, (ks + 1) * BK);
        const u16* Ab = Abuf[ks & 1];
        const u16* Bb = Bbuf[ks & 1];
        FragU af[MR][KR], bf_[NR][KR];
        #pragma unroll
        for (int i = 0; i < MR; ++i)
            #pragma unroll
            for (int u = 0; u < KR; ++u) {
                const int r = wm + i * 16 + fr;
                af[i][u].v4 = *(const uint4*)((const char*)Ab +
                    (size_t)r * (2 * BK) + (((u * 4 + fc) ^ swz_row(r, BK)) << 4));
            }
        #pragma unroll
        for (int j = 0; j < NR; ++j)
            #pragma unroll
            for (int u = 0; u < KR; ++u) {
                const int r = wn + j * 16 + fr;
                bf_[j][u].v4 = *(const uint4*)((const char*)Bb +
                    (size_t)r * (2 * BK) + (((u * 4 + fc) ^ swz_row(r, BK)) << 4));
            }
        #pragma unroll
        for (int u = 0; u < KR; ++u)
            #pragma unroll
            for (int i = 0; i < MR; ++i)
                #pragma unroll
                for (int j = 0; j < NR; ++j)
                    acc[i][j] = __builtin_amdgcn_mfma_f32_16x16x32_bf16(
                        af[i][u].f, bf_[j][u].f, acc[i][j], 0, 0, 0);
    }

    #pragma unroll
    for (int i = 0; i < MR; ++i) {
        #pragma unroll
        for (int q = 0; q < 4; ++q) {
            const int row = m0 + wm + i * 16 + fc * 4 + q;
            #pragma unroll
            for (int j = 0; j < NR; ++j) {
                const int col = n0 + wn + j * 16 + fr;
                float vx = acc[i][j][q];
                if constexpr (BIAS) vx += bias[col];
                if constexpr (GELU) vx = gelu1(vx);
                if constexpr (ADD) vx += addsrc[(size_t)row * N + col];
                if constexpr (QKV) {
                    if (n0 < 512) {   // qk half -> per-head layout [(b*8+h)][t][d]
                        const int bq = row >> 9, tq = row & 511;
                        const int hq = col >> 6, dq = col & 63;
                        Cb[(((size_t)(bq * 8 + hq) * 512) + tq) * 64 + dq] = bf16_1(vx);
                    } else {          // v half -> row-major [row][512]
                        ((u16*)Cf)[(size_t)row * 512 + (col - 512)] = bf16_1(vx);
                    }
                } else if constexpr (OUTBF) {
                    Cb[(size_t)row * N + col] = bf16_1(vx);
                } else {
                    Cf[(size_t)row * N + col] = vx;
                }
            }
        }
    }
}

// ---------------------------------------------------------------------------
// K/Q pre-normalization from bf16 qkh: qkn = bf16(row/|row|), qnrm = |row|.
__global__ __launch_bounds__(256)
void knorm_kernel(const u16* __restrict__ qkh, u16* __restrict__ qkn,
                  float* __restrict__ qnrm)
{
    const int g = blockIdx.x * 16 + (threadIdx.x >> 4);  // bh*T + t
    const int li = threadIdx.x & 15;
    const uint2 raw = *(const uint2*)(qkh + (size_t)g * 64 + li * 4);
    const float v0 = b2f((u16)(raw.x & 0xffff)), v1 = b2f((u16)(raw.x >> 16));
    const float v2 = b2f((u16)(raw.y & 0xffff)), v3 = b2f((u16)(raw.y >> 16));
    float ss = v0 * v0 + v1 * v1 + v2 * v2 + v3 * v3;
    ss += __shfl_xor(ss, 1); ss += __shfl_xor(ss, 2);
    ss += __shfl_xor(ss, 4); ss += __shfl_xor(ss, 8);
    const float qn = sqrtf(ss);
    const float rv = 1.0f / fmaxf(qn, 1e-12f);
    uint2 o;
    o.x = cvt_pk(v0 * rv, v1 * rv);
    o.y = cvt_pk(v2 * rv, v3 * rv);
    *(uint2*)(qkn + (size_t)g * 64 + li * 4) = o;
    if (li == 0) qnrm[g] = qn;
}

// ---------------------------------------------------------------------------
// Bucket assignment + stable partition from precomputed rotated (f32)
__global__ __launch_bounds__(512)
void bucket_sort_kernel(const float* __restrict__ rotated, int* __restrict__ st)
{
    const int h = blockIdx.x, bh = blockIdx.y;
    const int b = bh >> 3, head = bh & 7;
    const int t = threadIdx.x;
    __shared__ int zcnt[8];
    const float r = rotated[((size_t)(b * TT + t)) * 32 + head * 4 + h];
    const int bit = (r < 0.0f) ? 1 : 0;
    const int wid = t >> 6, lane = t & 63;
    const unsigned long long zm = __ballot(bit == 0);
    if (lane == 0) zcnt[wid] = __popcll(zm);
    __syncthreads();
    int zoff = 0, Z = 0;
    #pragma unroll
    for (int w = 0; w < 8; ++w) { const int cn = zcnt[w]; if (w < wid) zoff += cn; Z += cn; }
    const int zpre = __popcll(zm & ((1ull << lane) - 1ull));
    const int dst = (bit == 0) ? (zoff + zpre)
                               : (Z + (wid * 64 - zoff) + (lane - zpre));
    st[((size_t)bh * NHASH + h) * TT + dst] = t;
}

// ---------------------------------------------------------------------------
// MFMA LSH attention — R13 body + XCD-aware block remap: grid is flat 1024;
// XCD x (= id&7, round-robin dispatch) handles bh in [16x,16x+16) for ALL
// chunks, so the per-XCD K/V working set is ~2.1MB < 4MB L2 (was 17MB ->
// thrash, FETCH 68MB vs compulsory ~17MB). Perf-only remap (G16-safe).
__global__ __launch_bounds__(512, 4)
void lsh_attn_mfma(const u16* __restrict__ qkn, const u16* __restrict__ v,
                   const float* __restrict__ qnrm, const int* __restrict__ st,
                   __half* __restrict__ o_hash, float* __restrict__ lse_hash)
{
    const int lin = blockIdx.x;            // 0..1023
    const int xcd = lin & 7, slot = lin >> 3;
    const int bh = xcd * 16 + (slot & 15); // 16 bh per XCD
    const int cc = slot >> 4;              // chunk 0..7
    const int b = bh >> 3, head = bh & 7;
    const int h = cc >> 1, c = cc & 1;
    const int pcc = (cc + 7) & 7;
    const int hp = pcc >> 1, cp = pcc & 1;
    const int tid = threadIdx.x;
    const int w = tid >> 6;          // wave 0..7 -> queries w*32..+32
    const int lane = tid & 63;
    const int l31 = lane & 31;
    const int hi = lane >> 5;
    const int* stb = st + (size_t)bh * (NHASH * TT);
    const size_t vbase = ((size_t)b * TT) * DD + head * DHH;
    const u16* qknb = qkn + (size_t)bh * TT * DHH;

    __shared__ __align__(16) u16 Kbf[2][64 * 64];
    __shared__ __align__(16) u16 VTbf[2][64 * 64];
    __shared__ __align__(16) int ktl[2][64];

    // ---- Q fragment (one query per lane-column) ----
    const int q_t = stb[h * TT + c * CHUNKSZ + w * 32 + l31];
    const float qn = qnrm[(size_t)bh * TT + q_t];
    const float mnat = qn * 0.125f;
    const float aC = qn * 0.1803368801111137f;   // |q| * 0.125 * log2(e)
    uint4 QF4[4];
    {
        const u16* qrow = qknb + (size_t)q_t * DHH;
        #pragma unroll
        for (int ds = 0; ds < 4; ++ds)
            QF4[ds] = *(const uint4*)(qrow + ds * 16 + hi * 8);
    }

    f16x acc[2] = {};           // [dt] O^T tiles (32d x 32q)
    float lacc = 0.f;
    const int k8 = tid >> 3;    // key row 0..63 (8 lanes per 128B row)
    const int c8 = tid & 7;     // 16B chunk of the row
    // bit-reversed slot bases (constant per thread)
    const int brc = ((c8 & 1) << 2) | (c8 & 2) | ((c8 & 4) >> 2);   // bitrev3(c8)
    const int wSlot = ((k8 >> 3) + brc) & 7;                        // V write slot
    const int g2 = l31 >> 3;                                        // read row group
    const int brg = ((g2 & 1) << 2) | (g2 & 2);                     // bitrev3(g2), g2<4

    auto gather = [&](int t8, uint4& kc, uint4& vc, int& ktc) {
        const int kj = t8 * 64 + k8;
        const int k_t = (kj < CHUNKSZ) ? stb[h * TT + c * CHUNKSZ + kj]
                                       : stb[hp * TT + cp * CHUNKSZ + (kj - CHUNKSZ)];
        ktc = k_t;
        kc = *(const uint4*)(qknb + (size_t)k_t * DHH + c8 * 8);
        vc = *(const uint4*)(v + vbase + (size_t)k_t * DD + c8 * 8);
    };
    auto writeTile = [&](int bi, const uint4& kc, const uint4& vc, int ktc) {
        *(uint4*)((char*)Kbf[bi] + ((k8 * 128 + c8 * 16) ^ ((k8 & 7) << 4))) = kc;
        const unsigned vu[4] = {vc.x, vc.y, vc.z, vc.w};
        #pragma unroll
        for (int i = 0; i < 8; ++i) {
            const int d = c8 * 8 + i;
            const u16 hv = (u16)((i & 1) ? (vu[i >> 1] >> 16) : (vu[i >> 1] & 0xffff));
            *(u16*)((char*)VTbf[bi] + d * 128 + wSlot * 16 + (k8 & 7) * 2) = hv;
        }
        if (c8 == 0) ktl[bi][k8] = ktc;
    };

    uint4 kc, vc; int ktc;
    gather(0, kc, vc, ktc);
    writeTile(0, kc, vc, ktc);
    __syncthreads();

    for (int kt8 = 0; kt8 < 8; ++kt8) {
        const int cur = kt8 & 1;
        if (kt8 < 7) gather(kt8 + 1, kc, vc, ktc);
        const u16* Kb = Kbf[cur];
        const u16* Vb = VTbf[cur];
        const int* kl = ktl[cur];

        #pragma unroll
        for (int kt = 0; kt < 2; ++kt) {
            int4 kt4[4];
            #pragma unroll
            for (int j = 0; j < 4; ++j)
                kt4[j] = *(const int4*)&kl[kt * 32 + 8 * j + 4 * hi];
            const int* ktvp = (const int*)kt4;
            FragU KA[4];
            #pragma unroll
            for (int ds = 0; ds < 4; ++ds) {
                const int row = kt * 32 + l31;
                KA[ds].v4 = *(const uint4*)((const char*)Kb +
                    ((row * 128 + ds * 32 + hi * 16) ^ ((row & 7) << 4)));
            }
            FragU VA[2][2];
            #pragma unroll
            for (int dt = 0; dt < 2; ++dt)
                #pragma unroll
                for (int u = 0; u < 2; ++u) {
                    const int row = dt * 32 + l31;
                    const int cr = (kt * 2 + u) * 2 + hi;
                    const int slot = (cr + brg + dt) & 7;    // bitrev3(row>>3)=brg+dt
                    VA[dt][u].v4 = *(const uint4*)((const char*)Vb +
                        row * 128 + slot * 16);
                }
            f16x s = {0.f,0.f,0.f,0.f,0.f,0.f,0.f,0.f,
                      0.f,0.f,0.f,0.f,0.f,0.f,0.f,0.f};
            #pragma unroll
            for (int ds = 0; ds < 4; ++ds) {
                FragU qf; qf.v4 = QF4[ds];
                s = __builtin_amdgcn_mfma_f32_32x32x16_bf16(KA[ds].f, qf.f, s, 0, 0, 0);
            }
            float pv[16];
            #pragma unroll
            for (int i = 0; i < 16; ++i) {
                const float e = exp2f(fmaf(s[i], aC, -aC));   // exp(qn/8*(s-1))
                const float p = (q_t > ktvp[i]) ? e : 0.0f;
                pv[i] = p;
                lacc += p;
            }
            unsigned P2[8];
            #pragma unroll
            for (int g = 0; g < 4; ++g) {
                P2[2*g]   = cvt_pk(pv[4*g],   pv[4*g+1]);
                P2[2*g+1] = cvt_pk(pv[4*g+2], pv[4*g+3]);
            }
            #pragma unroll
            for (int u = 0; u < 2; ++u) {
                unsigned a0 = P2[4*u + 0], b0 = P2[4*u + 2];
                unsigned a1 = P2[4*u + 1], b1 = P2[4*u + 3];
                asm("v_permlane32_swap_b32 %0, %1" : "+v"(a0), "+v"(b0));
                asm("v_permlane32_swap_b32 %0, %1" : "+v"(a1), "+v"(b1));
                FragU bfv;
                bfv.u[0] = a0; bfv.u[1] = a1; bfv.u[2] = b0; bfv.u[3] = b1;
                #pragma unroll
                for (int dt = 0; dt < 2; ++dt)
                    acc[dt] = __builtin_amdgcn_mfma_f32_32x32x16_bf16(
                        VA[dt][u].f, bfv.f, acc[dt], 0, 0, 0);
            }
        }

        if (kt8 < 7) {
            writeTile(cur ^ 1, kc, vc, ktc);
            __syncthreads();
        }
    }

    // ---- finalize: l, lse, register-only epilogue ----
    const float lt = lacc + __shfl_xor(lacc, 32);
    const float invl = (lt > 0.f) ? 1.0f / lt : 0.0f;
    if (hi == 0) {
        const float lse = (lt > 0.f) ? (mnat + logf(lt)) : -5.0e4f;
        lse_hash[(size_t)(bh * NHASH + h) * TT + q_t] = lse;
    }
    unsigned wa[8], wb[8];
    #pragma unroll
    for (int m = 0; m < 8; ++m) {
        wa[m] = pkrtz(acc[0][2*m] * invl, acc[0][2*m+1] * invl);
        wb[m] = pkrtz(acc[1][2*m] * invl, acc[1][2*m+1] * invl);
    }
    #pragma unroll
    for (int m = 0; m < 8; ++m)
        asm("v_permlane32_swap_b32 %0, %1" : "+v"(wa[m]), "+v"(wb[m]));
    __half* orow = o_hash + ((size_t)(bh * NHASH + h) * TT + q_t) * DHH + hi * 32;
    if (lt > 0.f) {
        #pragma unroll
        for (int g = 0; g < 4; ++g) {
            uint4 o;
            o.x = wa[2*g]; o.y = wa[2*g+1];
            o.z = wb[2*g]; o.w = wb[2*g+1];
            ((uint4*)orow)[g] = o;
        }
    } else {
        const u16* vr = v + vbase + (size_t)q_t * DD + hi * 32;
        #pragma unroll
        for (int g = 0; g < 4; ++g) {
            uint4 o;
            o.x = pkrtz(b2f(vr[8*g+0]), b2f(vr[8*g+1]));
            o.y = pkrtz(b2f(vr[8*g+2]), b2f(vr[8*g+3]));
            o.z = pkrtz(b2f(vr[8*g+4]), b2f(vr[8*g+5]));
            o.w = pkrtz(b2f(vr[8*g+6]), b2f(vr[8*g+7]));
            ((uint4*)orow)[g] = o;
        }
    }
}

// ---------------------------------------------------------------------------
// Combine hash rounds: read o_hash f16, write merged bf16 (wo GEMM A-operand)
__global__ __launch_bounds__(256)
void combine_kernel(const __half* __restrict__ o_hash, const float* __restrict__ lse_hash,
                    u16* __restrict__ am)
{
    const int idx = blockIdx.x * 4 + (threadIdx.x >> 6);
    const int lane = threadIdx.x & 63;
    const int bh = idx >> 9, t = idx & 511;
    const int b = bh >> 3, head = bh & 7;
    const float ls0 = lse_hash[(size_t)(bh * NHASH + 0) * TT + t];
    const float ls1 = lse_hash[(size_t)(bh * NHASH + 1) * TT + t];
    const float ls2 = lse_hash[(size_t)(bh * NHASH + 2) * TT + t];
    const float ls3 = lse_hash[(size_t)(bh * NHASH + 3) * TT + t];
    const float M = fmaxf(fmaxf(ls0, ls1), fmaxf(ls2, ls3));
    const float e0 = __expf(ls0 - M), e1 = __expf(ls1 - M);
    const float e2 = __expf(ls2 - M), e3 = __expf(ls3 - M);
    const float inv = 1.0f / (e0 + e1 + e2 + e3);
    const float o =
        (e0 * __half2float(o_hash[((size_t)((bh * NHASH + 0) * TT + t)) * DHH + lane]) +
         e1 * __half2float(o_hash[((size_t)((bh * NHASH + 1) * TT + t)) * DHH + lane]) +
         e2 * __half2float(o_hash[((size_t)((bh * NHASH + 2) * TT + t)) * DHH + lane]) +
         e3 * __half2float(o_hash[((size_t)((bh * NHASH + 3) * TT + t)) * DHH + lane])) * inv;
    am[((size_t)(b * TT + t)) * DD + head * DHH + lane] = bf16_1(o);
}

// ---------------------------------------------------------------------------
// Final head
__device__ __forceinline__ float block_sum256(float v, volatile float* red)
{
    const int lane = threadIdx.x & 63, wid = threadIdx.x >> 6;
    #pragma unroll
    for (int o = 1; o < 64; o <<= 1) v += __shfl_xor(v, o);
    __syncthreads();
    if (lane == 0) red[wid] = v;
    __syncthreads();
    return red[0] + red[1] + red[2] + red[3];
}

__global__ __launch_bounds__(256)
void head_kernel(const float* __restrict__ x1, const float* __restrict__ x2,
                 const float* __restrict__ lnfg, const float* __restrict__ lnfb,
                 const float* __restrict__ hw1, const float* __restrict__ hb1,
                 const float* __restrict__ hlng, const float* __restrict__ hlnb,
                 const float* __restrict__ hw2, const float* __restrict__ hb2,
                 float* __restrict__ out)
{
    __shared__ float nrow[512];
    __shared__ float red[4];
    const int b = blockIdx.x, tid = threadIdx.x;
    const size_t roff = ((size_t)b * TT + (TT - 1)) * DD;
    const float v0 = 0.5f * (x1[roff + tid] + x2[roff + tid]);
    const float v1 = 0.5f * (x1[roff + 256 + tid] + x2[roff + 256 + tid]);
    const float mean = block_sum256(v0 + v1, red) * (1.0f / 512.0f);
    const float d0 = v0 - mean, d1 = v1 - mean;
    const float var = block_sum256(d0 * d0 + d1 * d1, red) * (1.0f / 512.0f);
    const float rstd = rsqrtf(var + 1e-5f);
    nrow[tid]       = d0 * rstd * lnfg[tid] + lnfb[tid];
    nrow[tid + 256] = d1 * rstd * lnfg[tid + 256] + lnfb[tid + 256];
    __syncthreads();
    float a = hb1[tid];
    for (int k = 0; k < 512; ++k) a = fmaf(nrow[k], hw1[(size_t)k * 256 + tid], a);
    const float m2 = block_sum256(a, red) * (1.0f / 256.0f);
    const float dd = a - m2;
    const float var2 = block_sum256(dd * dd, red) * (1.0f / 256.0f);
    float y = dd * rsqrtf(var2 + 1e-5f) * hlng[tid] + hlnb[tid];
    y = fmaxf(y, 0.0f);
    const float osum = block_sum256(y * hw2[tid], red);
    if (tid == 0) out[b] = osum + hb2[0];
}

// ---------------------------------------------------------------------------
extern "C" void kernel_launch(void* const* d_in, const int* in_sizes, int n_in,
                              void* d_out, int out_size, void* d_ws, size_t ws_size,
                              hipStream_t stream)
{
    (void)in_sizes; (void)n_in; (void)out_size; (void)ws_size;
    const float* x    = (const float*)d_in[0];
    const float* embw = (const float*)d_in[1];
    const float* embb = (const float*)d_in[2];
    const float* pos  = (const float*)d_in[3];
    const float* ln1g = (const float*)d_in[4];
    const float* ln1b = (const float*)d_in[5];
    const float* wqk  = (const float*)d_in[6];
    const float* wv   = (const float*)d_in[7];
    const float* wo   = (const float*)d_in[8];
    const float* wob  = (const float*)d_in[9];
    const float* ln2g = (const float*)d_in[10];
    const float* ln2b = (const float*)d_in[11];
    const float* ffw1 = (const float*)d_in[12];
    const float* ffb1 = (const float*)d_in[13];
    const float* ffw2 = (const float*)d_in[14];
    const float* ffb2 = (const float*)d_in[15];
    const float* rot  = (const float*)d_in[16];
    const float* lnfg = (const float*)d_in[17];
    const float* lnfb = (const float*)d_in[18];
    const float* hw1  = (const float*)d_in[19];
    const float* hb1  = (const float*)d_in[20];
    const float* hlng = (const float*)d_in[21];
    const float* hlnb = (const float*)d_in[22];
    const float* hw2  = (const float*)d_in[23];
    const float* hb2  = (const float*)d_in[24];
    float* out = (float*)d_out;

    const size_t SZ_BTD = (size_t)BB * TT * DD;            // 4,194,304
    const size_t SZ_OH  = (size_t)BHH * NHASH * TT * DHH;  // 16,777,216

    char* p = (char*)d_ws;
    float* x1b = (float*)p;  p += SZ_BTD * 4;
    float* x2b = (float*)p;  p += SZ_BTD * 4;
    float* xnb = (float*)p;  p += SZ_BTD * 4;              // also amb (bf16) late
    u16*   vbh = (u16*)p;    p += SZ_BTD * 2;
    u16*   xnbh = (u16*)p;   p += SZ_BTD * 2;
    u16*   qkh  = (u16*)p;   p += SZ_BTD * 2;              // bf16 qk, per-head layout
    u16*   qknb = (u16*)p;   p += (size_t)BHH * TT * DHH * 2;
    float* qnrm = (float*)p; p += (size_t)BHH * TT * 4;
    float* rotated = (float*)p; p += (size_t)BB * TT * 32 * 4;
    __half* ohash = (__half*)p;                  // 33.5MB region
    u16*    ffmid = (u16*)p;                     // temporal alias (disjoint life)
    p += SZ_OH * 2;
    float* lseb  = (float*)p; p += (size_t)BHH * NHASH * TT * 4;
    int*   stb   = (int*)p;   p += (size_t)BHH * NHASH * TT * 4;
    u16* wqkvT = (u16*)p; p += (size_t)NLAYER * 1024 * 512 * 2;
    u16* woT   = (u16*)p; p += (size_t)NLAYER * DD * DD * 2;
    u16* w1T   = (u16*)p; p += (size_t)NLAYER * DD * FFD * 2;
    u16* w2T   = (u16*)p; p += (size_t)NLAYER * FFD * DD * 2;
    float* wrotAll = (float*)p; p += (size_t)NLAYER * DD * 32 * 4;
    u16* amb = (u16*)xnb;                        // alias (xnb dead after GEMMs)

    // ---- one-time weight prep (all layers) ----
    prep_weights<<<11264, 256, 0, stream>>>(wqk, wv, wo, ffw1, ffw2,
                                            wqkvT, woT, w1T, w2T);
    wrot_kernel<<<dim3(32, NLAYER), 256, 0, stream>>>(wqk, rot, wrotAll);

    embed_kernel<<<BB * TT, 256, 0, stream>>>(x, embw, embb, pos, x1b, x2b);

    for (int L = 0; L < NLAYER; ++L) {
        const size_t w512 = (size_t)L * DD * DD;
        const size_t wff  = (size_t)L * DD * FFD;

        // x1 += attn(ln(x2))
        ln_kernel<<<2048, 256, 0, stream>>>(x2b, ln1g + L * DD, ln1b + L * DD, xnb, xnbh);
        rot_gemm<<<128, 256, 0, stream>>>(xnb, wrotAll + (size_t)L * DD * 32, rotated);
        gemm_bf16<128, 128, 32, false, false, false, false, true><<<dim3(64, 8), 256, 0, stream>>>(
            xnbh, wqkvT + (size_t)L * 1024 * 512, nullptr, nullptr,
            (float*)vbh, qkh, BB * TT, 1024, DD);
        bucket_sort_kernel<<<dim3(NHASH, BHH), 512, 0, stream>>>(rotated, stb);
        knorm_kernel<<<4096, 256, 0, stream>>>(qkh, qknb, qnrm);
        lsh_attn_mfma<<<1024, 512, 0, stream>>>(
            qknb, vbh, qnrm, stb, ohash, lseb);
        combine_kernel<<<16384, 256, 0, stream>>>(ohash, lseb, amb);
        gemm_bf16<128, 64, 64, false, true, true, false, false><<<dim3(64, 8), 256, 0, stream>>>(
            amb, woT + w512, wob + L * DD, x1b, x1b, nullptr, BB * TT, DD, DD);

        // x2 += ff(ln(x1))
        ln_kernel<<<2048, 256, 0, stream>>>(x1b, ln2g + L * DD, ln2b + L * DD, nullptr, xnbh);
        gemm_bf16<128, 128, 32, true, false, true, true, false><<<dim3(64, 16), 256, 0, stream>>>(
            xnbh, w1T + wff, ffb1 + L * FFD, nullptr, nullptr, ffmid, BB * TT, FFD, DD);
        gemm_bf16<128, 64, 64, false, true, true, false, false><<<dim3(64, 8), 256, 0, stream>>>(
            ffmid, w2T + wff, ffb2 + L * DD, x2b, x2b, nullptr, BB * TT, DD, FFD);
    }

    head_kernel<<<16, 256, 0, stream>>>(x1b, x2b, lnfg, lnfb, hw1, hb1,
                                        hlng, hlnb, hw2, hb2, out);
}

// Round 15
// 905.974 us; speedup vs baseline: 1.8892x; 1.0143x over previous
//
#include <hip/hip_runtime.h>
#include <hip/hip_fp16.h>
#include <cfloat>
#include <cstdint>

// Problem constants
#define BB      16      // batch
#define TT      512     // seq
#define DD      512     // d_model
#define HH      8       // heads
#define DHH     64      // head dim
#define FFD     2048    // ff dim
#define BHH     128     // BB*HH
#define NHASH   4
#define NCHUNK  8       // NHASH * N_BUCKETS
#define CHUNKSZ 256
#define NLAYER  4

typedef unsigned short u16;
typedef unsigned int   u32;
typedef __attribute__((ext_vector_type(8))) short bfrag;    // 8 bf16 (4 VGPR)
typedef __attribute__((ext_vector_type(4))) float f4x;      // 4 f32 acc
typedef __attribute__((ext_vector_type(16))) float f16x;    // 16 f32 acc

union FragU { u32 u[4]; uint4 v4; bfrag f; };

__device__ __forceinline__ unsigned pk_bf16(float a, float b) {
    union { float f; unsigned u; } x, y;
    x.f = a; y.f = b;
    unsigned lo = ((x.u + 0x7FFFu + ((x.u >> 16) & 1u)) >> 16) & 0xFFFFu;
    unsigned hi = (y.u + 0x7FFFu + ((y.u >> 16) & 1u)) & 0xFFFF0000u;
    return lo | hi;
}
// HW packed f32->bf16 RTNE (1 VALU op; no builtin on gfx950)
__device__ __forceinline__ unsigned cvt_pk(float a, float b) {
    unsigned r;
    asm("v_cvt_pk_bf16_f32 %0, %1, %2" : "=v"(r) : "v"(a), "v"(b));
    return r;
}
// HW packed f32->f16 (RTZ) — o_hash precision (10-bit mantissa)
__device__ __forceinline__ unsigned pkrtz(float a, float b) {
    unsigned r;
    asm("v_cvt_pkrtz_f16_f32 %0, %1, %2" : "=v"(r) : "v"(a), "v"(b));
    return r;
}
__device__ __forceinline__ u16 bf16_1(float a) {
    union { float f; unsigned u; } x; x.f = a;
    return (u16)((x.u + 0x7FFFu + ((x.u >> 16) & 1u)) >> 16);
}
__device__ __forceinline__ float b2f(u16 h) {
    union { unsigned u; float f; } x; x.u = ((unsigned)h) << 16; return x.f;
}
__device__ __forceinline__ float h2f(u16 h) {
    __half hv; *(u16*)&hv = h; return __half2float(hv);
}

// async global->LDS, 16B per lane (dest must be linear: base + lane*16)
__device__ __forceinline__ void gload16(const u16* g, u16* l) {
    __builtin_amdgcn_global_load_lds(
        (const __attribute__((address_space(1))) u32*)g,
        (__attribute__((address_space(3))) u32*)l, 16, 0, 0);
}

// ---------------------------------------------------------------------------
// Embedding: h = x @ emb_w + emb_b + pos ; write to both x1 and x2
__global__ __launch_bounds__(256)
void embed_kernel(const float* __restrict__ x, const float* __restrict__ ew,
                  const float* __restrict__ eb, const float* __restrict__ pos,
                  float* __restrict__ x1, float* __restrict__ x2)
{
    const int row = blockIdx.x;          // b*T + t
    const int t = row & (TT - 1);
    __shared__ float xr[32];
    if (threadIdx.x < 32) xr[threadIdx.x] = x[row * 32 + threadIdx.x];
    __syncthreads();
    for (int d = threadIdx.x; d < DD; d += 256) {
        float s = eb[d] + pos[t * DD + d];
        #pragma unroll
        for (int k = 0; k < 32; ++k) s = fmaf(xr[k], ew[k * DD + d], s);
        x1[(size_t)row * DD + d] = s;
        x2[(size_t)row * DD + d] = s;
    }
}

// ---------------------------------------------------------------------------
// LayerNorm over last dim (512); writes bf16 (always) and f32 (if out!=null).
__global__ __launch_bounds__(256)
void ln_kernel(const float* __restrict__ in, const float* __restrict__ g,
               const float* __restrict__ bta, float* __restrict__ out,
               u16* __restrict__ outh)
{
    const int row = blockIdx.x * 4 + (threadIdx.x >> 6);
    const int lane = threadIdx.x & 63;
    const float* r = in + (size_t)row * DD;
    float vals[8];
    float s = 0.0f;
    #pragma unroll
    for (int i = 0; i < 8; ++i) { vals[i] = r[i * 64 + lane]; s += vals[i]; }
    #pragma unroll
    for (int o = 1; o < 64; o <<= 1) s += __shfl_xor(s, o);
    const float mean = s * (1.0f / 512.0f);
    float vs = 0.0f;
    #pragma unroll
    for (int i = 0; i < 8; ++i) { float d = vals[i] - mean; vs += d * d; }
    #pragma unroll
    for (int o = 1; o < 64; o <<= 1) vs += __shfl_xor(vs, o);
    const float rstd = rsqrtf(vs * (1.0f / 512.0f) + 1e-5f);
    u16* hrow = outh + (size_t)row * DD;
    #pragma unroll
    for (int i = 0; i < 8; ++i) {
        const int d = i * 64 + lane;
        const float y = (vals[i] - mean) * rstd * g[d] + bta[d];
        if (out != nullptr) out[(size_t)row * DD + d] = y;
        hrow[d] = bf16_1(y);
    }
}

// ---------------------------------------------------------------------------
// Batched weight prep: transpose+bf16 ALL layers in ONE dispatch.
// wqk+wv go into a CONCATENATED wqkvT [1024][512] per layer.
__global__ __launch_bounds__(256)
void prep_weights(const float* __restrict__ wqk, const float* __restrict__ wv,
                  const float* __restrict__ wo, const float* __restrict__ ffw1,
                  const float* __restrict__ ffw2,
                  u16* __restrict__ wqkvT, u16* __restrict__ woT,
                  u16* __restrict__ w1T, u16* __restrict__ w2T)
{
    const int id = blockIdx.x;
    const float* in; u16* outp; int K, N, kt, nt;
    if (id < 3072) {                       // wqk / wv / wo : 512x512, 256 tiles/L
        const int fam = id >> 10;
        const int r = id & 1023;
        const int L = r >> 8, t = r & 255;
        K = 512; N = 512;
        const size_t off = (size_t)L * 512 * 512;
        in = (fam == 0 ? wqk : fam == 1 ? wv : wo) + off;
        outp = (fam == 2) ? (woT + off)
                          : (wqkvT + (size_t)L * 1024 * 512 + (fam == 1 ? (size_t)512 * 512 : 0));
        kt = (t & 15) << 5; nt = (t >> 4) << 5;
    } else if (id < 7168) {                // ff1: 512x2048, 1024 tiles/L
        const int r = id - 3072;
        const int L = r >> 10, t = r & 1023;
        K = 512; N = 2048;
        in = ffw1 + (size_t)L * 512 * 2048;
        outp = w1T + (size_t)L * 2048 * 512;
        kt = (t & 15) << 5; nt = (t >> 4) << 5;
    } else {                               // ff2: 2048x512, 1024 tiles/L
        const int r = id - 7168;
        const int L = r >> 10, t = r & 1023;
        K = 2048; N = 512;
        in = ffw2 + (size_t)L * 2048 * 512;
        outp = w2T + (size_t)L * 512 * 2048;
        kt = (t & 63) << 5; nt = (t >> 6) << 5;
    }
    __shared__ float tile[32][33];
    const int rr = threadIdx.x >> 3, c4 = (threadIdx.x & 7) * 4;
    const float4 v4 = *(const float4*)(in + (size_t)(kt + rr) * N + nt + c4);
    tile[rr][c4 + 0] = v4.x; tile[rr][c4 + 1] = v4.y;
    tile[rr][c4 + 2] = v4.z; tile[rr][c4 + 3] = v4.w;
    __syncthreads();
    uint2 p;
    p.x = pk_bf16(tile[c4 + 0][rr], tile[c4 + 1][rr]);
    p.y = pk_bf16(tile[c4 + 2][rr], tile[c4 + 3][rr]);
    *(uint2*)(outp + (size_t)(nt + rr) * K + kt + c4) = p;
}

// ---------------------------------------------------------------------------
// wrot[L][f][h*4+hash] = sum_d wqk[L][f][h*64+d] * rot[L][d][hash]
__global__ __launch_bounds__(256)
void wrot_kernel(const float* __restrict__ wqk, const float* __restrict__ rot,
                 float* __restrict__ wrotAll)
{
    const int hh = blockIdx.x, L = blockIdx.y;
    const int head = hh >> 2, h = hh & 3;
    __shared__ float rc[64];
    if (threadIdx.x < 64)
        rc[threadIdx.x] = rot[((size_t)L * 64 + threadIdx.x) * 4 + h];
    __syncthreads();
    for (int f = threadIdx.x; f < 512; f += 256) {
        const float* wrow = wqk + (size_t)L * 512 * 512 + (size_t)f * 512 + head * 64;
        float s = 0.0f;
        #pragma unroll
        for (int d = 0; d < 64; d += 4) {
            const float4 w4 = *(const float4*)(wrow + d);
            s += w4.x * rc[d] + w4.y * rc[d + 1] + w4.z * rc[d + 2] + w4.w * rc[d + 3];
        }
        wrotAll[((size_t)L * 512 + f) * 32 + hh] = s;
    }
}

// ---------------------------------------------------------------------------
// rotated[8192][32] = xn[8192][512] @ wrot[512][32], all f32. grid 128.
__global__ __launch_bounds__(256)
void rot_gemm(const float* __restrict__ A, const float* __restrict__ Wr,
              float* __restrict__ C)
{
    __shared__ float As[64][36];
    __shared__ float Ws[32][36];
    const int m0 = blockIdx.x * 64;
    const int r = threadIdx.x >> 2, cg = threadIdx.x & 3;
    float acc[8] = {};
    for (int f0 = 0; f0 < 512; f0 += 32) {
        __syncthreads();
        {
            const int lr = threadIdx.x >> 2, lc = (threadIdx.x & 3) * 8;
            const float* ap = A + (size_t)(m0 + lr) * 512 + f0 + lc;
            *(float4*)&As[lr][lc]     = ((const float4*)ap)[0];
            *(float4*)&As[lr][lc + 4] = ((const float4*)ap)[1];
            const int wr = threadIdx.x >> 3, wc = (threadIdx.x & 7) * 4;
            *(float4*)&Ws[wr][wc] = *(const float4*)(Wr + (size_t)(f0 + wr) * 32 + wc);
        }
        __syncthreads();
        #pragma unroll
        for (int kk = 0; kk < 32; ++kk) {
            const float a = As[r][kk];
            #pragma unroll
            for (int c = 0; c < 8; ++c)
                acc[c] = fmaf(a, Ws[kk][cg * 8 + c], acc[c]);
        }
    }
    float* crow = C + (size_t)(m0 + r) * 32 + cg * 8;
    *(float4*)crow       = make_float4(acc[0], acc[1], acc[2], acc[3]);
    *(float4*)(crow + 4) = make_float4(acc[4], acc[5], acc[6], acc[7]);
}

// ---------------------------------------------------------------------------
// bf16 MFMA GEMM, templated tile, double-buffered LDS, 2-phase pipeline.
// QKV: merged qk+v output — n0<512 routes to per-head qkh (Cb); n0>=512
// routes to row-major vbh (Cf reinterpreted as u16*).
__device__ __forceinline__ float gelu1(float v) {
    return 0.5f * v * (1.0f + erff(v * 0.70710678118654752440f));
}
__device__ __forceinline__ int swz_row(int r, int BK) {
    return (BK == 32) ? ((r & 3) ^ ((r >> 2) & 3)) : (r & 7);
}

template<int BM, int BN, int BK, bool GELU, bool ADD, bool BIAS, bool OUTBF, bool QKV>
__global__ __launch_bounds__(256)
void gemm_bf16(const u16* __restrict__ A, const u16* __restrict__ WT,
               const float* __restrict__ bias, const float* __restrict__ addsrc,
               float* __restrict__ Cf, u16* __restrict__ Cb,
               int M, int N, int K)
{
    constexpr int NCH = BK / 8;
    constexpr int CPA = BM * NCH / 256;
    constexpr int CPB = BN * NCH / 256;
    constexpr int MR = BM / 32, NR = BN / 32, KR = BK / 32;
    __shared__ __align__(16) u16 Abuf[2][BM * BK];
    __shared__ __align__(16) u16 Bbuf[2][BN * BK];
    const int tid = threadIdx.x;
    const int m0 = blockIdx.x * BM, n0 = blockIdx.y * BN;

    const u16* aSrc[CPA]; const u16* bSrc[CPB];
    #pragma unroll
    for (int i = 0; i < CPA; ++i) {
        const int s = tid + i * 256, row = s / NCH, ch = s % NCH;
        aSrc[i] = A + (size_t)(m0 + row) * K + (ch ^ swz_row(row, BK)) * 8;
    }
    #pragma unroll
    for (int i = 0; i < CPB; ++i) {
        const int s = tid + i * 256, row = s / NCH, ch = s % NCH;
        bSrc[i] = WT + (size_t)(n0 + row) * K + (ch ^ swz_row(row, BK)) * 8;
    }

    auto STAGE = [&](int bufi, int koff) {
        #pragma unroll
        for (int i = 0; i < CPA; ++i)
            gload16(aSrc[i] + koff, &Abuf[bufi][(tid + i * 256) * 8]);
        #pragma unroll
        for (int i = 0; i < CPB; ++i)
            gload16(bSrc[i] + koff, &Bbuf[bufi][(tid + i * 256) * 8]);
    };

    const int l = tid & 63, wv_ = tid >> 6;
    const int wm = (wv_ >> 1) * (BM / 2);
    const int wn = (wv_ & 1) * (BN / 2);
    const int fr = l & 15, fc = l >> 4;

    f4x acc[MR][NR] = {};
    const int nK = K / BK;
    STAGE(0, 0);
    for (int ks = 0; ks < nK; ++ks) {
        __syncthreads();
        if (ks + 1 < nK) STAGE((ks + 1) & 1, (ks + 1) * BK);
        const u16* Ab = Abuf[ks & 1];
        const u16* Bb = Bbuf[ks & 1];
        FragU af[MR][KR], bf_[NR][KR];
        #pragma unroll
        for (int i = 0; i < MR; ++i)
            #pragma unroll
            for (int u = 0; u < KR; ++u) {
                const int r = wm + i * 16 + fr;
                af[i][u].v4 = *(const uint4*)((const char*)Ab +
                    (size_t)r * (2 * BK) + (((u * 4 + fc) ^ swz_row(r, BK)) << 4));
            }
        #pragma unroll
        for (int j = 0; j < NR; ++j)
            #pragma unroll
            for (int u = 0; u < KR; ++u) {
                const int r = wn + j * 16 + fr;
                bf_[j][u].v4 = *(const uint4*)((const char*)Bb +
                    (size_t)r * (2 * BK) + (((u * 4 + fc) ^ swz_row(r, BK)) << 4));
            }
        #pragma unroll
        for (int u = 0; u < KR; ++u)
            #pragma unroll
            for (int i = 0; i < MR; ++i)
                #pragma unroll
                for (int j = 0; j < NR; ++j)
                    acc[i][j] = __builtin_amdgcn_mfma_f32_16x16x32_bf16(
                        af[i][u].f, bf_[j][u].f, acc[i][j], 0, 0, 0);
    }

    #pragma unroll
    for (int i = 0; i < MR; ++i) {
        #pragma unroll
        for (int q = 0; q < 4; ++q) {
            const int row = m0 + wm + i * 16 + fc * 4 + q;
            #pragma unroll
            for (int j = 0; j < NR; ++j) {
                const int col = n0 + wn + j * 16 + fr;
                float vx = acc[i][j][q];
                if constexpr (BIAS) vx += bias[col];
                if constexpr (GELU) vx = gelu1(vx);
                if constexpr (ADD) vx += addsrc[(size_t)row * N + col];
                if constexpr (QKV) {
                    if (n0 < 512) {   // qk half -> per-head layout [(b*8+h)][t][d]
                        const int bq = row >> 9, tq = row & 511;
                        const int hq = col >> 6, dq = col & 63;
                        Cb[(((size_t)(bq * 8 + hq) * 512) + tq) * 64 + dq] = bf16_1(vx);
                    } else {          // v half -> row-major [row][512]
                        ((u16*)Cf)[(size_t)row * 512 + (col - 512)] = bf16_1(vx);
                    }
                } else if constexpr (OUTBF) {
                    Cb[(size_t)row * N + col] = bf16_1(vx);
                } else {
                    Cf[(size_t)row * N + col] = vx;
                }
            }
        }
    }
}

// ---------------------------------------------------------------------------
// K/Q pre-normalization from bf16 qkh: qkn = bf16(row/|row|), qnrm = |row|.
__global__ __launch_bounds__(256)
void knorm_kernel(const u16* __restrict__ qkh, u16* __restrict__ qkn,
                  float* __restrict__ qnrm)
{
    const int g = blockIdx.x * 16 + (threadIdx.x >> 4);  // bh*T + t
    const int li = threadIdx.x & 15;
    const uint2 raw = *(const uint2*)(qkh + (size_t)g * 64 + li * 4);
    const float v0 = b2f((u16)(raw.x & 0xffff)), v1 = b2f((u16)(raw.x >> 16));
    const float v2 = b2f((u16)(raw.y & 0xffff)), v3 = b2f((u16)(raw.y >> 16));
    float ss = v0 * v0 + v1 * v1 + v2 * v2 + v3 * v3;
    ss += __shfl_xor(ss, 1); ss += __shfl_xor(ss, 2);
    ss += __shfl_xor(ss, 4); ss += __shfl_xor(ss, 8);
    const float qn = sqrtf(ss);
    const float rv = 1.0f / fmaxf(qn, 1e-12f);
    uint2 o;
    o.x = cvt_pk(v0 * rv, v1 * rv);
    o.y = cvt_pk(v2 * rv, v3 * rv);
    *(uint2*)(qkn + (size_t)g * 64 + li * 4) = o;
    if (li == 0) qnrm[g] = qn;
}

// ---------------------------------------------------------------------------
// Bucket assignment + stable partition from precomputed rotated (f32)
__global__ __launch_bounds__(512)
void bucket_sort_kernel(const float* __restrict__ rotated, int* __restrict__ st)
{
    const int h = blockIdx.x, bh = blockIdx.y;
    const int b = bh >> 3, head = bh & 7;
    const int t = threadIdx.x;
    __shared__ int zcnt[8];
    const float r = rotated[((size_t)(b * TT + t)) * 32 + head * 4 + h];
    const int bit = (r < 0.0f) ? 1 : 0;
    const int wid = t >> 6, lane = t & 63;
    const unsigned long long zm = __ballot(bit == 0);
    if (lane == 0) zcnt[wid] = __popcll(zm);
    __syncthreads();
    int zoff = 0, Z = 0;
    #pragma unroll
    for (int w = 0; w < 8; ++w) { const int cn = zcnt[w]; if (w < wid) zoff += cn; Z += cn; }
    const int zpre = __popcll(zm & ((1ull << lane) - 1ull));
    const int dst = (bit == 0) ? (zoff + zpre)
                               : (Z + (wid * 64 - zoff) + (lane - zpre));
    st[((size_t)bh * NHASH + h) * TT + dst] = t;
}

// ---------------------------------------------------------------------------
// MFMA LSH attention — R13 body + XCD-aware block remap (R14: FETCH 68->10MB).
__global__ __launch_bounds__(512, 4)
void lsh_attn_mfma(const u16* __restrict__ qkn, const u16* __restrict__ v,
                   const float* __restrict__ qnrm, const int* __restrict__ st,
                   __half* __restrict__ o_hash, float* __restrict__ lse_hash)
{
    const int lin = blockIdx.x;            // 0..1023
    const int xcd = lin & 7, slot = lin >> 3;
    const int bh = xcd * 16 + (slot & 15); // 16 bh per XCD
    const int cc = slot >> 4;              // chunk 0..7
    const int b = bh >> 3, head = bh & 7;
    const int h = cc >> 1, c = cc & 1;
    const int pcc = (cc + 7) & 7;
    const int hp = pcc >> 1, cp = pcc & 1;
    const int tid = threadIdx.x;
    const int w = tid >> 6;          // wave 0..7 -> queries w*32..+32
    const int lane = tid & 63;
    const int l31 = lane & 31;
    const int hi = lane >> 5;
    const int* stb = st + (size_t)bh * (NHASH * TT);
    const size_t vbase = ((size_t)b * TT) * DD + head * DHH;
    const u16* qknb = qkn + (size_t)bh * TT * DHH;

    __shared__ __align__(16) u16 Kbf[2][64 * 64];
    __shared__ __align__(16) u16 VTbf[2][64 * 64];
    __shared__ __align__(16) int ktl[2][64];

    // ---- Q fragment (one query per lane-column) ----
    const int q_t = stb[h * TT + c * CHUNKSZ + w * 32 + l31];
    const float qn = qnrm[(size_t)bh * TT + q_t];
    const float mnat = qn * 0.125f;
    const float aC = qn * 0.1803368801111137f;   // |q| * 0.125 * log2(e)
    uint4 QF4[4];
    {
        const u16* qrow = qknb + (size_t)q_t * DHH;
        #pragma unroll
        for (int ds = 0; ds < 4; ++ds)
            QF4[ds] = *(const uint4*)(qrow + ds * 16 + hi * 8);
    }

    f16x acc[2] = {};           // [dt] O^T tiles (32d x 32q)
    float lacc = 0.f;
    const int k8 = tid >> 3;    // key row 0..63 (8 lanes per 128B row)
    const int c8 = tid & 7;     // 16B chunk of the row
    // bit-reversed slot bases (constant per thread)
    const int brc = ((c8 & 1) << 2) | (c8 & 2) | ((c8 & 4) >> 2);   // bitrev3(c8)
    const int wSlot = ((k8 >> 3) + brc) & 7;                        // V write slot
    const int g2 = l31 >> 3;                                        // read row group
    const int brg = ((g2 & 1) << 2) | (g2 & 2);                     // bitrev3(g2), g2<4

    auto gather = [&](int t8, uint4& kc, uint4& vc, int& ktc) {
        const int kj = t8 * 64 + k8;
        const int k_t = (kj < CHUNKSZ) ? stb[h * TT + c * CHUNKSZ + kj]
                                       : stb[hp * TT + cp * CHUNKSZ + (kj - CHUNKSZ)];
        ktc = k_t;
        kc = *(const uint4*)(qknb + (size_t)k_t * DHH + c8 * 8);
        vc = *(const uint4*)(v + vbase + (size_t)k_t * DD + c8 * 8);
    };
    auto writeTile = [&](int bi, const uint4& kc, const uint4& vc, int ktc) {
        *(uint4*)((char*)Kbf[bi] + ((k8 * 128 + c8 * 16) ^ ((k8 & 7) << 4))) = kc;
        const unsigned vu[4] = {vc.x, vc.y, vc.z, vc.w};
        #pragma unroll
        for (int i = 0; i < 8; ++i) {
            const int d = c8 * 8 + i;
            const u16 hv = (u16)((i & 1) ? (vu[i >> 1] >> 16) : (vu[i >> 1] & 0xffff));
            *(u16*)((char*)VTbf[bi] + d * 128 + wSlot * 16 + (k8 & 7) * 2) = hv;
        }
        if (c8 == 0) ktl[bi][k8] = ktc;
    };

    uint4 kc, vc; int ktc;
    gather(0, kc, vc, ktc);
    writeTile(0, kc, vc, ktc);
    __syncthreads();

    for (int kt8 = 0; kt8 < 8; ++kt8) {
        const int cur = kt8 & 1;
        if (kt8 < 7) gather(kt8 + 1, kc, vc, ktc);
        const u16* Kb = Kbf[cur];
        const u16* Vb = VTbf[cur];
        const int* kl = ktl[cur];

        #pragma unroll
        for (int kt = 0; kt < 2; ++kt) {
            int4 kt4[4];
            #pragma unroll
            for (int j = 0; j < 4; ++j)
                kt4[j] = *(const int4*)&kl[kt * 32 + 8 * j + 4 * hi];
            const int* ktvp = (const int*)kt4;
            FragU KA[4];
            #pragma unroll
            for (int ds = 0; ds < 4; ++ds) {
                const int row = kt * 32 + l31;
                KA[ds].v4 = *(const uint4*)((const char*)Kb +
                    ((row * 128 + ds * 32 + hi * 16) ^ ((row & 7) << 4)));
            }
            FragU VA[2][2];
            #pragma unroll
            for (int dt = 0; dt < 2; ++dt)
                #pragma unroll
                for (int u = 0; u < 2; ++u) {
                    const int row = dt * 32 + l31;
                    const int cr = (kt * 2 + u) * 2 + hi;
                    const int slot = (cr + brg + dt) & 7;    // bitrev3(row>>3)=brg+dt
                    VA[dt][u].v4 = *(const uint4*)((const char*)Vb +
                        row * 128 + slot * 16);
                }
            f16x s = {0.f,0.f,0.f,0.f,0.f,0.f,0.f,0.f,
                      0.f,0.f,0.f,0.f,0.f,0.f,0.f,0.f};
            #pragma unroll
            for (int ds = 0; ds < 4; ++ds) {
                FragU qf; qf.v4 = QF4[ds];
                s = __builtin_amdgcn_mfma_f32_32x32x16_bf16(KA[ds].f, qf.f, s, 0, 0, 0);
            }
            float pv[16];
            #pragma unroll
            for (int i = 0; i < 16; ++i) {
                const float e = exp2f(fmaf(s[i], aC, -aC));   // exp(qn/8*(s-1))
                const float p = (q_t > ktvp[i]) ? e : 0.0f;
                pv[i] = p;
                lacc += p;
            }
            unsigned P2[8];
            #pragma unroll
            for (int g = 0; g < 4; ++g) {
                P2[2*g]   = cvt_pk(pv[4*g],   pv[4*g+1]);
                P2[2*g+1] = cvt_pk(pv[4*g+2], pv[4*g+3]);
            }
            #pragma unroll
            for (int u = 0; u < 2; ++u) {
                unsigned a0 = P2[4*u + 0], b0 = P2[4*u + 2];
                unsigned a1 = P2[4*u + 1], b1 = P2[4*u + 3];
                asm("v_permlane32_swap_b32 %0, %1" : "+v"(a0), "+v"(b0));
                asm("v_permlane32_swap_b32 %0, %1" : "+v"(a1), "+v"(b1));
                FragU bfv;
                bfv.u[0] = a0; bfv.u[1] = a1; bfv.u[2] = b0; bfv.u[3] = b1;
                #pragma unroll
                for (int dt = 0; dt < 2; ++dt)
                    acc[dt] = __builtin_amdgcn_mfma_f32_32x32x16_bf16(
                        VA[dt][u].f, bfv.f, acc[dt], 0, 0, 0);
            }
        }

        if (kt8 < 7) {
            writeTile(cur ^ 1, kc, vc, ktc);
            __syncthreads();
        }
    }

    // ---- finalize: l, lse, register-only epilogue ----
    const float lt = lacc + __shfl_xor(lacc, 32);
    const float invl = (lt > 0.f) ? 1.0f / lt : 0.0f;
    if (hi == 0) {
        const float lse = (lt > 0.f) ? (mnat + logf(lt)) : -5.0e4f;
        lse_hash[(size_t)(bh * NHASH + h) * TT + q_t] = lse;
    }
    unsigned wa[8], wb[8];
    #pragma unroll
    for (int m = 0; m < 8; ++m) {
        wa[m] = pkrtz(acc[0][2*m] * invl, acc[0][2*m+1] * invl);
        wb[m] = pkrtz(acc[1][2*m] * invl, acc[1][2*m+1] * invl);
    }
    #pragma unroll
    for (int m = 0; m < 8; ++m)
        asm("v_permlane32_swap_b32 %0, %1" : "+v"(wa[m]), "+v"(wb[m]));
    __half* orow = o_hash + ((size_t)(bh * NHASH + h) * TT + q_t) * DHH + hi * 32;
    if (lt > 0.f) {
        #pragma unroll
        for (int g = 0; g < 4; ++g) {
            uint4 o;
            o.x = wa[2*g]; o.y = wa[2*g+1];
            o.z = wb[2*g]; o.w = wb[2*g+1];
            ((uint4*)orow)[g] = o;
        }
    } else {
        const u16* vr = v + vbase + (size_t)q_t * DD + hi * 32;
        #pragma unroll
        for (int g = 0; g < 4; ++g) {
            uint4 o;
            o.x = pkrtz(b2f(vr[8*g+0]), b2f(vr[8*g+1]));
            o.y = pkrtz(b2f(vr[8*g+2]), b2f(vr[8*g+3]));
            o.z = pkrtz(b2f(vr[8*g+4]), b2f(vr[8*g+5]));
            o.w = pkrtz(b2f(vr[8*g+6]), b2f(vr[8*g+7]));
            ((uint4*)orow)[g] = o;
        }
    }
}

// ---------------------------------------------------------------------------
// Combine hash rounds — VECTORIZED (G13): 8 channels/thread via uint4 f16
// loads; per-channel math identical to scalar version (bit-exact output).
// grid 2048 x 256.
__global__ __launch_bounds__(256)
void combine_kernel(const __half* __restrict__ o_hash, const float* __restrict__ lse_hash,
                    u16* __restrict__ am)
{
    const int gt = blockIdx.x * 256 + threadIdx.x;
    const int row = gt >> 3;               // bh*T + t
    const int seg = (gt & 7) * 8;          // channel start
    const int bh = row >> 9, t = row & 511;
    const int b = bh >> 3, head = bh & 7;
    const float ls0 = lse_hash[(size_t)(bh * NHASH + 0) * TT + t];
    const float ls1 = lse_hash[(size_t)(bh * NHASH + 1) * TT + t];
    const float ls2 = lse_hash[(size_t)(bh * NHASH + 2) * TT + t];
    const float ls3 = lse_hash[(size_t)(bh * NHASH + 3) * TT + t];
    const float M = fmaxf(fmaxf(ls0, ls1), fmaxf(ls2, ls3));
    const float e0 = __expf(ls0 - M), e1 = __expf(ls1 - M);
    const float e2 = __expf(ls2 - M), e3 = __expf(ls3 - M);
    const float inv = 1.0f / (e0 + e1 + e2 + e3);
    const size_t base = (size_t)(bh * NHASH) * TT * DHH + (size_t)t * DHH + seg;
    const uint4 r0 = *(const uint4*)((const u16*)o_hash + base);
    const uint4 r1 = *(const uint4*)((const u16*)o_hash + base + (size_t)TT * DHH);
    const uint4 r2 = *(const uint4*)((const u16*)o_hash + base + (size_t)2 * TT * DHH);
    const uint4 r3 = *(const uint4*)((const u16*)o_hash + base + (size_t)3 * TT * DHH);
    const unsigned w0[4] = {r0.x, r0.y, r0.z, r0.w};
    const unsigned w1[4] = {r1.x, r1.y, r1.z, r1.w};
    const unsigned w2[4] = {r2.x, r2.y, r2.z, r2.w};
    const unsigned w3[4] = {r3.x, r3.y, r3.z, r3.w};
    unsigned outw[4];
    #pragma unroll
    for (int j = 0; j < 4; ++j) {
        const float alo = (e0 * h2f((u16)(w0[j] & 0xffff)) +
                           e1 * h2f((u16)(w1[j] & 0xffff)) +
                           e2 * h2f((u16)(w2[j] & 0xffff)) +
                           e3 * h2f((u16)(w3[j] & 0xffff))) * inv;
        const float ahi = (e0 * h2f((u16)(w0[j] >> 16)) +
                           e1 * h2f((u16)(w1[j] >> 16)) +
                           e2 * h2f((u16)(w2[j] >> 16)) +
                           e3 * h2f((u16)(w3[j] >> 16))) * inv;
        outw[j] = (unsigned)bf16_1(alo) | ((unsigned)bf16_1(ahi) << 16);
    }
    uint4 ov; ov.x = outw[0]; ov.y = outw[1]; ov.z = outw[2]; ov.w = outw[3];
    *(uint4*)(am + ((size_t)(b * TT + t)) * DD + head * DHH + seg) = ov;
}

// ---------------------------------------------------------------------------
// Final head
__device__ __forceinline__ float block_sum256(float v, volatile float* red)
{
    const int lane = threadIdx.x & 63, wid = threadIdx.x >> 6;
    #pragma unroll
    for (int o = 1; o < 64; o <<= 1) v += __shfl_xor(v, o);
    __syncthreads();
    if (lane == 0) red[wid] = v;
    __syncthreads();
    return red[0] + red[1] + red[2] + red[3];
}

__global__ __launch_bounds__(256)
void head_kernel(const float* __restrict__ x1, const float* __restrict__ x2,
                 const float* __restrict__ lnfg, const float* __restrict__ lnfb,
                 const float* __restrict__ hw1, const float* __restrict__ hb1,
                 const float* __restrict__ hlng, const float* __restrict__ hlnb,
                 const float* __restrict__ hw2, const float* __restrict__ hb2,
                 float* __restrict__ out)
{
    __shared__ float nrow[512];
    __shared__ float red[4];
    const int b = blockIdx.x, tid = threadIdx.x;
    const size_t roff = ((size_t)b * TT + (TT - 1)) * DD;
    const float v0 = 0.5f * (x1[roff + tid] + x2[roff + tid]);
    const float v1 = 0.5f * (x1[roff + 256 + tid] + x2[roff + 256 + tid]);
    const float mean = block_sum256(v0 + v1, red) * (1.0f / 512.0f);
    const float d0 = v0 - mean, d1 = v1 - mean;
    const float var = block_sum256(d0 * d0 + d1 * d1, red) * (1.0f / 512.0f);
    const float rstd = rsqrtf(var + 1e-5f);
    nrow[tid]       = d0 * rstd * lnfg[tid] + lnfb[tid];
    nrow[tid + 256] = d1 * rstd * lnfg[tid + 256] + lnfb[tid + 256];
    __syncthreads();
    float a = hb1[tid];
    for (int k = 0; k < 512; ++k) a = fmaf(nrow[k], hw1[(size_t)k * 256 + tid], a);
    const float m2 = block_sum256(a, red) * (1.0f / 256.0f);
    const float dd = a - m2;
    const float var2 = block_sum256(dd * dd, red) * (1.0f / 256.0f);
    float y = dd * rsqrtf(var2 + 1e-5f) * hlng[tid] + hlnb[tid];
    y = fmaxf(y, 0.0f);
    const float osum = block_sum256(y * hw2[tid], red);
    if (tid == 0) out[b] = osum + hb2[0];
}

// ---------------------------------------------------------------------------
extern "C" void kernel_launch(void* const* d_in, const int* in_sizes, int n_in,
                              void* d_out, int out_size, void* d_ws, size_t ws_size,
                              hipStream_t stream)
{
    (void)in_sizes; (void)n_in; (void)out_size; (void)ws_size;
    const float* x    = (const float*)d_in[0];
    const float* embw = (const float*)d_in[1];
    const float* embb = (const float*)d_in[2];
    const float* pos  = (const float*)d_in[3];
    const float* ln1g = (const float*)d_in[4];
    const float* ln1b = (const float*)d_in[5];
    const float* wqk  = (const float*)d_in[6];
    const float* wv   = (const float*)d_in[7];
    const float* wo   = (const float*)d_in[8];
    const float* wob  = (const float*)d_in[9];
    const float* ln2g = (const float*)d_in[10];
    const float* ln2b = (const float*)d_in[11];
    const float* ffw1 = (const float*)d_in[12];
    const float* ffb1 = (const float*)d_in[13];
    const float* ffw2 = (const float*)d_in[14];
    const float* ffb2 = (const float*)d_in[15];
    const float* rot  = (const float*)d_in[16];
    const float* lnfg = (const float*)d_in[17];
    const float* lnfb = (const float*)d_in[18];
    const float* hw1  = (const float*)d_in[19];
    const float* hb1  = (const float*)d_in[20];
    const float* hlng = (const float*)d_in[21];
    const float* hlnb = (const float*)d_in[22];
    const float* hw2  = (const float*)d_in[23];
    const float* hb2  = (const float*)d_in[24];
    float* out = (float*)d_out;

    const size_t SZ_BTD = (size_t)BB * TT * DD;            // 4,194,304
    const size_t SZ_OH  = (size_t)BHH * NHASH * TT * DHH;  // 16,777,216

    char* p = (char*)d_ws;
    float* x1b = (float*)p;  p += SZ_BTD * 4;
    float* x2b = (float*)p;  p += SZ_BTD * 4;
    float* xnb = (float*)p;  p += SZ_BTD * 4;              // also amb (bf16) late
    u16*   vbh = (u16*)p;    p += SZ_BTD * 2;
    u16*   xnbh = (u16*)p;   p += SZ_BTD * 2;
    u16*   qkh  = (u16*)p;   p += SZ_BTD * 2;              // bf16 qk, per-head layout
    u16*   qknb = (u16*)p;   p += (size_t)BHH * TT * DHH * 2;
    float* qnrm = (float*)p; p += (size_t)BHH * TT * 4;
    float* rotated = (float*)p; p += (size_t)BB * TT * 32 * 4;
    __half* ohash = (__half*)p;                  // 33.5MB region
    u16*    ffmid = (u16*)p;                     // temporal alias (disjoint life)
    p += SZ_OH * 2;
    float* lseb  = (float*)p; p += (size_t)BHH * NHASH * TT * 4;
    int*   stb   = (int*)p;   p += (size_t)BHH * NHASH * TT * 4;
    u16* wqkvT = (u16*)p; p += (size_t)NLAYER * 1024 * 512 * 2;
    u16* woT   = (u16*)p; p += (size_t)NLAYER * DD * DD * 2;
    u16* w1T   = (u16*)p; p += (size_t)NLAYER * DD * FFD * 2;
    u16* w2T   = (u16*)p; p += (size_t)NLAYER * FFD * DD * 2;
    float* wrotAll = (float*)p; p += (size_t)NLAYER * DD * 32 * 4;
    u16* amb = (u16*)xnb;                        // alias (xnb dead after GEMMs)

    // ---- one-time weight prep (all layers) ----
    prep_weights<<<11264, 256, 0, stream>>>(wqk, wv, wo, ffw1, ffw2,
                                            wqkvT, woT, w1T, w2T);
    wrot_kernel<<<dim3(32, NLAYER), 256, 0, stream>>>(wqk, rot, wrotAll);

    embed_kernel<<<BB * TT, 256, 0, stream>>>(x, embw, embb, pos, x1b, x2b);

    for (int L = 0; L < NLAYER; ++L) {
        const size_t w512 = (size_t)L * DD * DD;
        const size_t wff  = (size_t)L * DD * FFD;

        // x1 += attn(ln(x2))
        ln_kernel<<<2048, 256, 0, stream>>>(x2b, ln1g + L * DD, ln1b + L * DD, xnb, xnbh);
        rot_gemm<<<128, 256, 0, stream>>>(xnb, wrotAll + (size_t)L * DD * 32, rotated);
        gemm_bf16<128, 128, 32, false, false, false, false, true><<<dim3(64, 8), 256, 0, stream>>>(
            xnbh, wqkvT + (size_t)L * 1024 * 512, nullptr, nullptr,
            (float*)vbh, qkh, BB * TT, 1024, DD);
        bucket_sort_kernel<<<dim3(NHASH, BHH), 512, 0, stream>>>(rotated, stb);
        knorm_kernel<<<4096, 256, 0, stream>>>(qkh, qknb, qnrm);
        lsh_attn_mfma<<<1024, 512, 0, stream>>>(
            qknb, vbh, qnrm, stb, ohash, lseb);
        combine_kernel<<<2048, 256, 0, stream>>>(ohash, lseb, amb);
        gemm_bf16<128, 64, 64, false, true, true, false, false><<<dim3(64, 8), 256, 0, stream>>>(
            amb, woT + w512, wob + L * DD, x1b, x1b, nullptr, BB * TT, DD, DD);

        // x2 += ff(ln(x1))
        ln_kernel<<<2048, 256, 0, stream>>>(x1b, ln2g + L * DD, ln2b + L * DD, nullptr, xnbh);
        gemm_bf16<128, 128, 32, true, false, true, true, false><<<dim3(64, 16), 256, 0, stream>>>(
            xnbh, w1T + wff, ffb1 + L * FFD, nullptr, nullptr, ffmid, BB * TT, FFD, DD);
        gemm_bf16<128, 64, 64, false, true, true, false, false><<<dim3(64, 8), 256, 0, stream>>>(
            ffmid, w2T + wff, ffb2 + L * DD, x2b, x2b, nullptr, BB * TT, DD, FFD);
    }

    head_kernel<<<16, 256, 0, stream>>>(x1b, x2b, lnfg, lnfb, hw1, hb1,
                                        hlng, hlnb, hw2, hb2, out);
}

// Round 16
// 892.648 us; speedup vs baseline: 1.9174x; 1.0149x over previous
//
#include <hip/hip_runtime.h>
#include <hip/hip_fp16.h>
#include <cfloat>
#include <cstdint>

// Problem constants
#define BB      16      // batch
#define TT      512     // seq
#define DD      512     // d_model
#define HH      8       // heads
#define DHH     64      // head dim
#define FFD     2048    // ff dim
#define BHH     128     // BB*HH
#define NHASH   4
#define NCHUNK  8       // NHASH * N_BUCKETS
#define CHUNKSZ 256
#define NLAYER  4

typedef unsigned short u16;
typedef unsigned int   u32;
typedef __attribute__((ext_vector_type(8))) short bfrag;    // 8 bf16 (4 VGPR)
typedef __attribute__((ext_vector_type(4))) float f4x;      // 4 f32 acc
typedef __attribute__((ext_vector_type(16))) float f16x;    // 16 f32 acc

union FragU { u32 u[4]; uint4 v4; bfrag f; };

__device__ __forceinline__ unsigned pk_bf16(float a, float b) {
    union { float f; unsigned u; } x, y;
    x.f = a; y.f = b;
    unsigned lo = ((x.u + 0x7FFFu + ((x.u >> 16) & 1u)) >> 16) & 0xFFFFu;
    unsigned hi = (y.u + 0x7FFFu + ((y.u >> 16) & 1u)) & 0xFFFF0000u;
    return lo | hi;
}
// HW packed f32->bf16 RTNE (1 VALU op; no builtin on gfx950)
__device__ __forceinline__ unsigned cvt_pk(float a, float b) {
    unsigned r;
    asm("v_cvt_pk_bf16_f32 %0, %1, %2" : "=v"(r) : "v"(a), "v"(b));
    return r;
}
// HW packed f32->f16 (RTZ) — o_hash precision (10-bit mantissa)
__device__ __forceinline__ unsigned pkrtz(float a, float b) {
    unsigned r;
    asm("v_cvt_pkrtz_f16_f32 %0, %1, %2" : "=v"(r) : "v"(a), "v"(b));
    return r;
}
__device__ __forceinline__ u16 bf16_1(float a) {
    union { float f; unsigned u; } x; x.f = a;
    return (u16)((x.u + 0x7FFFu + ((x.u >> 16) & 1u)) >> 16);
}
__device__ __forceinline__ float b2f(u16 h) {
    union { unsigned u; float f; } x; x.u = ((unsigned)h) << 16; return x.f;
}
__device__ __forceinline__ float h2f(u16 h) {
    __half hv; *(u16*)&hv = h; return __half2float(hv);
}

// async global->LDS, 16B per lane (dest must be linear: base + lane*16)
__device__ __forceinline__ void gload16(const u16* g, u16* l) {
    __builtin_amdgcn_global_load_lds(
        (const __attribute__((address_space(1))) u32*)g,
        (__attribute__((address_space(3))) u32*)l, 16, 0, 0);
}

// ---------------------------------------------------------------------------
// Embedding: h = x @ emb_w + emb_b + pos ; write to both x1 and x2
__global__ __launch_bounds__(256)
void embed_kernel(const float* __restrict__ x, const float* __restrict__ ew,
                  const float* __restrict__ eb, const float* __restrict__ pos,
                  float* __restrict__ x1, float* __restrict__ x2)
{
    const int row = blockIdx.x;          // b*T + t
    const int t = row & (TT - 1);
    __shared__ float xr[32];
    if (threadIdx.x < 32) xr[threadIdx.x] = x[row * 32 + threadIdx.x];
    __syncthreads();
    for (int d = threadIdx.x; d < DD; d += 256) {
        float s = eb[d] + pos[t * DD + d];
        #pragma unroll
        for (int k = 0; k < 32; ++k) s = fmaf(xr[k], ew[k * DD + d], s);
        x1[(size_t)row * DD + d] = s;
        x2[(size_t)row * DD + d] = s;
    }
}

// ---------------------------------------------------------------------------
// LayerNorm over last dim (512).
// VEC=false (ln1): exact scalar order (feeds f32 bucket path), writes f32+bf16.
// VEC=true  (ln2): float4 loads + uint2 bf16 stores, bf16 out only.
template<bool VEC>
__global__ __launch_bounds__(256)
void ln_kernel(const float* __restrict__ in, const float* __restrict__ g,
               const float* __restrict__ bta, float* __restrict__ out,
               u16* __restrict__ outh)
{
    const int row = blockIdx.x * 4 + (threadIdx.x >> 6);
    const int lane = threadIdx.x & 63;
    const float* r = in + (size_t)row * DD;
    float vals[8];
    float s = 0.0f;
    if constexpr (VEC) {
        const float4 a = *(const float4*)(r + lane * 4);
        const float4 b = *(const float4*)(r + 256 + lane * 4);
        vals[0] = a.x; vals[1] = a.y; vals[2] = a.z; vals[3] = a.w;
        vals[4] = b.x; vals[5] = b.y; vals[6] = b.z; vals[7] = b.w;
        #pragma unroll
        for (int i = 0; i < 8; ++i) s += vals[i];
    } else {
        #pragma unroll
        for (int i = 0; i < 8; ++i) { vals[i] = r[i * 64 + lane]; s += vals[i]; }
    }
    #pragma unroll
    for (int o = 1; o < 64; o <<= 1) s += __shfl_xor(s, o);
    const float mean = s * (1.0f / 512.0f);
    float vs = 0.0f;
    #pragma unroll
    for (int i = 0; i < 8; ++i) { float d = vals[i] - mean; vs += d * d; }
    #pragma unroll
    for (int o = 1; o < 64; o <<= 1) vs += __shfl_xor(vs, o);
    const float rstd = rsqrtf(vs * (1.0f / 512.0f) + 1e-5f);
    u16* hrow = outh + (size_t)row * DD;
    if constexpr (VEC) {
        const float4 g0 = *(const float4*)(g + lane * 4);
        const float4 g1 = *(const float4*)(g + 256 + lane * 4);
        const float4 b0 = *(const float4*)(bta + lane * 4);
        const float4 b1 = *(const float4*)(bta + 256 + lane * 4);
        const float y0 = (vals[0] - mean) * rstd * g0.x + b0.x;
        const float y1 = (vals[1] - mean) * rstd * g0.y + b0.y;
        const float y2 = (vals[2] - mean) * rstd * g0.z + b0.z;
        const float y3 = (vals[3] - mean) * rstd * g0.w + b0.w;
        const float y4 = (vals[4] - mean) * rstd * g1.x + b1.x;
        const float y5 = (vals[5] - mean) * rstd * g1.y + b1.y;
        const float y6 = (vals[6] - mean) * rstd * g1.z + b1.z;
        const float y7 = (vals[7] - mean) * rstd * g1.w + b1.w;
        uint2 o0, o1;
        o0.x = cvt_pk(y0, y1); o0.y = cvt_pk(y2, y3);
        o1.x = cvt_pk(y4, y5); o1.y = cvt_pk(y6, y7);
        *(uint2*)(hrow + lane * 4) = o0;
        *(uint2*)(hrow + 256 + lane * 4) = o1;
    } else {
        #pragma unroll
        for (int i = 0; i < 8; ++i) {
            const int d = i * 64 + lane;
            const float y = (vals[i] - mean) * rstd * g[d] + bta[d];
            if (out != nullptr) out[(size_t)row * DD + d] = y;
            hrow[d] = bf16_1(y);
        }
    }
}

// ---------------------------------------------------------------------------
// Batched weight prep: transpose+bf16 ALL layers in ONE dispatch.
// wqk+wv go into a CONCATENATED wqkvT [1024][512] per layer.
__global__ __launch_bounds__(256)
void prep_weights(const float* __restrict__ wqk, const float* __restrict__ wv,
                  const float* __restrict__ wo, const float* __restrict__ ffw1,
                  const float* __restrict__ ffw2,
                  u16* __restrict__ wqkvT, u16* __restrict__ woT,
                  u16* __restrict__ w1T, u16* __restrict__ w2T)
{
    const int id = blockIdx.x;
    const float* in; u16* outp; int K, N, kt, nt;
    if (id < 3072) {                       // wqk / wv / wo : 512x512, 256 tiles/L
        const int fam = id >> 10;
        const int r = id & 1023;
        const int L = r >> 8, t = r & 255;
        K = 512; N = 512;
        const size_t off = (size_t)L * 512 * 512;
        in = (fam == 0 ? wqk : fam == 1 ? wv : wo) + off;
        outp = (fam == 2) ? (woT + off)
                          : (wqkvT + (size_t)L * 1024 * 512 + (fam == 1 ? (size_t)512 * 512 : 0));
        kt = (t & 15) << 5; nt = (t >> 4) << 5;
    } else if (id < 7168) {                // ff1: 512x2048, 1024 tiles/L
        const int r = id - 3072;
        const int L = r >> 10, t = r & 1023;
        K = 512; N = 2048;
        in = ffw1 + (size_t)L * 512 * 2048;
        outp = w1T + (size_t)L * 2048 * 512;
        kt = (t & 15) << 5; nt = (t >> 4) << 5;
    } else {                               // ff2: 2048x512, 1024 tiles/L
        const int r = id - 7168;
        const int L = r >> 10, t = r & 1023;
        K = 2048; N = 512;
        in = ffw2 + (size_t)L * 2048 * 512;
        outp = w2T + (size_t)L * 512 * 2048;
        kt = (t & 63) << 5; nt = (t >> 6) << 5;
    }
    __shared__ float tile[32][33];
    const int rr = threadIdx.x >> 3, c4 = (threadIdx.x & 7) * 4;
    const float4 v4 = *(const float4*)(in + (size_t)(kt + rr) * N + nt + c4);
    tile[rr][c4 + 0] = v4.x; tile[rr][c4 + 1] = v4.y;
    tile[rr][c4 + 2] = v4.z; tile[rr][c4 + 3] = v4.w;
    __syncthreads();
    uint2 p;
    p.x = pk_bf16(tile[c4 + 0][rr], tile[c4 + 1][rr]);
    p.y = pk_bf16(tile[c4 + 2][rr], tile[c4 + 3][rr]);
    *(uint2*)(outp + (size_t)(nt + rr) * K + kt + c4) = p;
}

// ---------------------------------------------------------------------------
// wrot[L][f][h*4+hash] = sum_d wqk[L][f][h*64+d] * rot[L][d][hash]
__global__ __launch_bounds__(256)
void wrot_kernel(const float* __restrict__ wqk, const float* __restrict__ rot,
                 float* __restrict__ wrotAll)
{
    const int hh = blockIdx.x, L = blockIdx.y;
    const int head = hh >> 2, h = hh & 3;
    __shared__ float rc[64];
    if (threadIdx.x < 64)
        rc[threadIdx.x] = rot[((size_t)L * 64 + threadIdx.x) * 4 + h];
    __syncthreads();
    for (int f = threadIdx.x; f < 512; f += 256) {
        const float* wrow = wqk + (size_t)L * 512 * 512 + (size_t)f * 512 + head * 64;
        float s = 0.0f;
        #pragma unroll
        for (int d = 0; d < 64; d += 4) {
            const float4 w4 = *(const float4*)(wrow + d);
            s += w4.x * rc[d] + w4.y * rc[d + 1] + w4.z * rc[d + 2] + w4.w * rc[d + 3];
        }
        wrotAll[((size_t)L * 512 + f) * 32 + hh] = s;
    }
}

// ---------------------------------------------------------------------------
// rotated[8192][32] = xn[8192][512] @ wrot[512][32], all f32. grid 128.
__global__ __launch_bounds__(256)
void rot_gemm(const float* __restrict__ A, const float* __restrict__ Wr,
              float* __restrict__ C)
{
    __shared__ float As[64][36];
    __shared__ float Ws[32][36];
    const int m0 = blockIdx.x * 64;
    const int r = threadIdx.x >> 2, cg = threadIdx.x & 3;
    float acc[8] = {};
    for (int f0 = 0; f0 < 512; f0 += 32) {
        __syncthreads();
        {
            const int lr = threadIdx.x >> 2, lc = (threadIdx.x & 3) * 8;
            const float* ap = A + (size_t)(m0 + lr) * 512 + f0 + lc;
            *(float4*)&As[lr][lc]     = ((const float4*)ap)[0];
            *(float4*)&As[lr][lc + 4] = ((const float4*)ap)[1];
            const int wr = threadIdx.x >> 3, wc = (threadIdx.x & 7) * 4;
            *(float4*)&Ws[wr][wc] = *(const float4*)(Wr + (size_t)(f0 + wr) * 32 + wc);
        }
        __syncthreads();
        #pragma unroll
        for (int kk = 0; kk < 32; ++kk) {
            const float a = As[r][kk];
            #pragma unroll
            for (int c = 0; c < 8; ++c)
                acc[c] = fmaf(a, Ws[kk][cg * 8 + c], acc[c]);
        }
    }
    float* crow = C + (size_t)(m0 + r) * 32 + cg * 8;
    *(float4*)crow       = make_float4(acc[0], acc[1], acc[2], acc[3]);
    *(float4*)(crow + 4) = make_float4(acc[4], acc[5], acc[6], acc[7]);
}

// ---------------------------------------------------------------------------
// bf16 MFMA GEMM, templated tile, double-buffered LDS, 2-phase pipeline.
// QKV: merged qk+v output — n0<512 routes to per-head qkh (Cb); n0>=512
// routes to row-major vbh (Cf reinterpreted as u16*).
__device__ __forceinline__ float gelu1(float v) {
    return 0.5f * v * (1.0f + erff(v * 0.70710678118654752440f));
}
__device__ __forceinline__ int swz_row(int r, int BK) {
    return (BK == 32) ? ((r & 3) ^ ((r >> 2) & 3)) : (r & 7);
}

template<int BM, int BN, int BK, bool GELU, bool ADD, bool BIAS, bool OUTBF, bool QKV>
__global__ __launch_bounds__(256)
void gemm_bf16(const u16* __restrict__ A, const u16* __restrict__ WT,
               const float* __restrict__ bias, const float* __restrict__ addsrc,
               float* __restrict__ Cf, u16* __restrict__ Cb,
               int M, int N, int K)
{
    constexpr int NCH = BK / 8;
    constexpr int CPA = BM * NCH / 256;
    constexpr int CPB = BN * NCH / 256;
    constexpr int MR = BM / 32, NR = BN / 32, KR = BK / 32;
    __shared__ __align__(16) u16 Abuf[2][BM * BK];
    __shared__ __align__(16) u16 Bbuf[2][BN * BK];
    const int tid = threadIdx.x;
    const int m0 = blockIdx.x * BM, n0 = blockIdx.y * BN;

    const u16* aSrc[CPA]; const u16* bSrc[CPB];
    #pragma unroll
    for (int i = 0; i < CPA; ++i) {
        const int s = tid + i * 256, row = s / NCH, ch = s % NCH;
        aSrc[i] = A + (size_t)(m0 + row) * K + (ch ^ swz_row(row, BK)) * 8;
    }
    #pragma unroll
    for (int i = 0; i < CPB; ++i) {
        const int s = tid + i * 256, row = s / NCH, ch = s % NCH;
        bSrc[i] = WT + (size_t)(n0 + row) * K + (ch ^ swz_row(row, BK)) * 8;
    }

    auto STAGE = [&](int bufi, int koff) {
        #pragma unroll
        for (int i = 0; i < CPA; ++i)
            gload16(aSrc[i] + koff, &Abuf[bufi][(tid + i * 256) * 8]);
        #pragma unroll
        for (int i = 0; i < CPB; ++i)
            gload16(bSrc[i] + koff, &Bbuf[bufi][(tid + i * 256) * 8]);
    };

    const int l = tid & 63, wv_ = tid >> 6;
    const int wm = (wv_ >> 1) * (BM / 2);
    const int wn = (wv_ & 1) * (BN / 2);
    const int fr = l & 15, fc = l >> 4;

    f4x acc[MR][NR] = {};
    const int nK = K / BK;
    STAGE(0, 0);
    for (int ks = 0; ks < nK; ++ks) {
        __syncthreads();
        if (ks + 1 < nK) STAGE((ks + 1) & 1, (ks + 1) * BK);
        const u16* Ab = Abuf[ks & 1];
        const u16* Bb = Bbuf[ks & 1];
        FragU af[MR][KR], bf_[NR][KR];
        #pragma unroll
        for (int i = 0; i < MR; ++i)
            #pragma unroll
            for (int u = 0; u < KR; ++u) {
                const int r = wm + i * 16 + fr;
                af[i][u].v4 = *(const uint4*)((const char*)Ab +
                    (size_t)r * (2 * BK) + (((u * 4 + fc) ^ swz_row(r, BK)) << 4));
            }
        #pragma unroll
        for (int j = 0; j < NR; ++j)
            #pragma unroll
            for (int u = 0; u < KR; ++u) {
                const int r = wn + j * 16 + fr;
                bf_[j][u].v4 = *(const uint4*)((const char*)Bb +
                    (size_t)r * (2 * BK) + (((u * 4 + fc) ^ swz_row(r, BK)) << 4));
            }
        #pragma unroll
        for (int u = 0; u < KR; ++u)
            #pragma unroll
            for (int i = 0; i < MR; ++i)
                #pragma unroll
                for (int j = 0; j < NR; ++j)
                    acc[i][j] = __builtin_amdgcn_mfma_f32_16x16x32_bf16(
                        af[i][u].f, bf_[j][u].f, acc[i][j], 0, 0, 0);
    }

    #pragma unroll
    for (int i = 0; i < MR; ++i) {
        #pragma unroll
        for (int q = 0; q < 4; ++q) {
            const int row = m0 + wm + i * 16 + fc * 4 + q;
            #pragma unroll
            for (int j = 0; j < NR; ++j) {
                const int col = n0 + wn + j * 16 + fr;
                float vx = acc[i][j][q];
                if constexpr (BIAS) vx += bias[col];
                if constexpr (GELU) vx = gelu1(vx);
                if constexpr (ADD) vx += addsrc[(size_t)row * N + col];
                if constexpr (QKV) {
                    if (n0 < 512) {   // qk half -> per-head layout [(b*8+h)][t][d]
                        const int bq = row >> 9, tq = row & 511;
                        const int hq = col >> 6, dq = col & 63;
                        Cb[(((size_t)(bq * 8 + hq) * 512) + tq) * 64 + dq] = bf16_1(vx);
                    } else {          // v half -> row-major [row][512]
                        ((u16*)Cf)[(size_t)row * 512 + (col - 512)] = bf16_1(vx);
                    }
                } else if constexpr (OUTBF) {
                    Cb[(size_t)row * N + col] = bf16_1(vx);
                } else {
                    Cf[(size_t)row * N + col] = vx;
                }
            }
        }
    }
}

// ---------------------------------------------------------------------------
// MERGED knorm + bucket_sort (independent inputs, one dispatch).
// Blocks [0,512): bucket partition from rotated (f32, bit-identical math).
// Blocks [512,2560): K/Q pre-normalization, 32 rows/block @512 threads.
__global__ __launch_bounds__(512)
void knorm_bucket(const u16* __restrict__ qkh, const float* __restrict__ rotated,
                  u16* __restrict__ qkn, float* __restrict__ qnrm,
                  int* __restrict__ st)
{
    __shared__ int zcnt[8];
    const int id = blockIdx.x;
    const int t = threadIdx.x;
    if (id < 512) {
        const int h = id & 3, bh = id >> 2;
        const int b = bh >> 3, head = bh & 7;
        const float r = rotated[((size_t)(b * TT + t)) * 32 + head * 4 + h];
        const int bit = (r < 0.0f) ? 1 : 0;
        const int wid = t >> 6, lane = t & 63;
        const unsigned long long zm = __ballot(bit == 0);
        if (lane == 0) zcnt[wid] = __popcll(zm);
        __syncthreads();
        int zoff = 0, Z = 0;
        #pragma unroll
        for (int w = 0; w < 8; ++w) { const int cn = zcnt[w]; if (w < wid) zoff += cn; Z += cn; }
        const int zpre = __popcll(zm & ((1ull << lane) - 1ull));
        const int dst = (bit == 0) ? (zoff + zpre)
                                   : (Z + (wid * 64 - zoff) + (lane - zpre));
        st[((size_t)bh * NHASH + h) * TT + dst] = t;
    } else {
        const int g = (id - 512) * 32 + (t >> 4);  // bh*T + t
        const int li = t & 15;
        const uint2 raw = *(const uint2*)(qkh + (size_t)g * 64 + li * 4);
        const float v0 = b2f((u16)(raw.x & 0xffff)), v1 = b2f((u16)(raw.x >> 16));
        const float v2 = b2f((u16)(raw.y & 0xffff)), v3 = b2f((u16)(raw.y >> 16));
        float ss = v0 * v0 + v1 * v1 + v2 * v2 + v3 * v3;
        ss += __shfl_xor(ss, 1); ss += __shfl_xor(ss, 2);
        ss += __shfl_xor(ss, 4); ss += __shfl_xor(ss, 8);
        const float qn = sqrtf(ss);
        const float rv = 1.0f / fmaxf(qn, 1e-12f);
        uint2 o;
        o.x = cvt_pk(v0 * rv, v1 * rv);
        o.y = cvt_pk(v2 * rv, v3 * rv);
        *(uint2*)(qkn + (size_t)g * 64 + li * 4) = o;
        if (li == 0) qnrm[g] = qn;
    }
}

// ---------------------------------------------------------------------------
// MFMA LSH attention — R13 body + XCD-aware block remap (R14: FETCH 68->10MB).
__global__ __launch_bounds__(512, 4)
void lsh_attn_mfma(const u16* __restrict__ qkn, const u16* __restrict__ v,
                   const float* __restrict__ qnrm, const int* __restrict__ st,
                   __half* __restrict__ o_hash, float* __restrict__ lse_hash)
{
    const int lin = blockIdx.x;            // 0..1023
    const int xcd = lin & 7, slot = lin >> 3;
    const int bh = xcd * 16 + (slot & 15); // 16 bh per XCD
    const int cc = slot >> 4;              // chunk 0..7
    const int b = bh >> 3, head = bh & 7;
    const int h = cc >> 1, c = cc & 1;
    const int pcc = (cc + 7) & 7;
    const int hp = pcc >> 1, cp = pcc & 1;
    const int tid = threadIdx.x;
    const int w = tid >> 6;          // wave 0..7 -> queries w*32..+32
    const int lane = tid & 63;
    const int l31 = lane & 31;
    const int hi = lane >> 5;
    const int* stb = st + (size_t)bh * (NHASH * TT);
    const size_t vbase = ((size_t)b * TT) * DD + head * DHH;
    const u16* qknb = qkn + (size_t)bh * TT * DHH;

    __shared__ __align__(16) u16 Kbf[2][64 * 64];
    __shared__ __align__(16) u16 VTbf[2][64 * 64];
    __shared__ __align__(16) int ktl[2][64];

    // ---- Q fragment (one query per lane-column) ----
    const int q_t = stb[h * TT + c * CHUNKSZ + w * 32 + l31];
    const float qn = qnrm[(size_t)bh * TT + q_t];
    const float mnat = qn * 0.125f;
    const float aC = qn * 0.1803368801111137f;   // |q| * 0.125 * log2(e)
    uint4 QF4[4];
    {
        const u16* qrow = qknb + (size_t)q_t * DHH;
        #pragma unroll
        for (int ds = 0; ds < 4; ++ds)
            QF4[ds] = *(const uint4*)(qrow + ds * 16 + hi * 8);
    }

    f16x acc[2] = {};           // [dt] O^T tiles (32d x 32q)
    float lacc = 0.f;
    const int k8 = tid >> 3;    // key row 0..63 (8 lanes per 128B row)
    const int c8 = tid & 7;     // 16B chunk of the row
    // bit-reversed slot bases (constant per thread)
    const int brc = ((c8 & 1) << 2) | (c8 & 2) | ((c8 & 4) >> 2);   // bitrev3(c8)
    const int wSlot = ((k8 >> 3) + brc) & 7;                        // V write slot
    const int g2 = l31 >> 3;                                        // read row group
    const int brg = ((g2 & 1) << 2) | (g2 & 2);                     // bitrev3(g2), g2<4

    auto gather = [&](int t8, uint4& kc, uint4& vc, int& ktc) {
        const int kj = t8 * 64 + k8;
        const int k_t = (kj < CHUNKSZ) ? stb[h * TT + c * CHUNKSZ + kj]
                                       : stb[hp * TT + cp * CHUNKSZ + (kj - CHUNKSZ)];
        ktc = k_t;
        kc = *(const uint4*)(qknb + (size_t)k_t * DHH + c8 * 8);
        vc = *(const uint4*)(v + vbase + (size_t)k_t * DD + c8 * 8);
    };
    auto writeTile = [&](int bi, const uint4& kc, const uint4& vc, int ktc) {
        *(uint4*)((char*)Kbf[bi] + ((k8 * 128 + c8 * 16) ^ ((k8 & 7) << 4))) = kc;
        const unsigned vu[4] = {vc.x, vc.y, vc.z, vc.w};
        #pragma unroll
        for (int i = 0; i < 8; ++i) {
            const int d = c8 * 8 + i;
            const u16 hv = (u16)((i & 1) ? (vu[i >> 1] >> 16) : (vu[i >> 1] & 0xffff));
            *(u16*)((char*)VTbf[bi] + d * 128 + wSlot * 16 + (k8 & 7) * 2) = hv;
        }
        if (c8 == 0) ktl[bi][k8] = ktc;
    };

    uint4 kc, vc; int ktc;
    gather(0, kc, vc, ktc);
    writeTile(0, kc, vc, ktc);
    __syncthreads();

    for (int kt8 = 0; kt8 < 8; ++kt8) {
        const int cur = kt8 & 1;
        if (kt8 < 7) gather(kt8 + 1, kc, vc, ktc);
        const u16* Kb = Kbf[cur];
        const u16* Vb = VTbf[cur];
        const int* kl = ktl[cur];

        #pragma unroll
        for (int kt = 0; kt < 2; ++kt) {
            int4 kt4[4];
            #pragma unroll
            for (int j = 0; j < 4; ++j)
                kt4[j] = *(const int4*)&kl[kt * 32 + 8 * j + 4 * hi];
            const int* ktvp = (const int*)kt4;
            FragU KA[4];
            #pragma unroll
            for (int ds = 0; ds < 4; ++ds) {
                const int row = kt * 32 + l31;
                KA[ds].v4 = *(const uint4*)((const char*)Kb +
                    ((row * 128 + ds * 32 + hi * 16) ^ ((row & 7) << 4)));
            }
            FragU VA[2][2];
            #pragma unroll
            for (int dt = 0; dt < 2; ++dt)
                #pragma unroll
                for (int u = 0; u < 2; ++u) {
                    const int row = dt * 32 + l31;
                    const int cr = (kt * 2 + u) * 2 + hi;
                    const int slot = (cr + brg + dt) & 7;    // bitrev3(row>>3)=brg+dt
                    VA[dt][u].v4 = *(const uint4*)((const char*)Vb +
                        row * 128 + slot * 16);
                }
            f16x s = {0.f,0.f,0.f,0.f,0.f,0.f,0.f,0.f,
                      0.f,0.f,0.f,0.f,0.f,0.f,0.f,0.f};
            #pragma unroll
            for (int ds = 0; ds < 4; ++ds) {
                FragU qf; qf.v4 = QF4[ds];
                s = __builtin_amdgcn_mfma_f32_32x32x16_bf16(KA[ds].f, qf.f, s, 0, 0, 0);
            }
            float pv[16];
            #pragma unroll
            for (int i = 0; i < 16; ++i) {
                const float e = exp2f(fmaf(s[i], aC, -aC));   // exp(qn/8*(s-1))
                const float p = (q_t > ktvp[i]) ? e : 0.0f;
                pv[i] = p;
                lacc += p;
            }
            unsigned P2[8];
            #pragma unroll
            for (int g = 0; g < 4; ++g) {
                P2[2*g]   = cvt_pk(pv[4*g],   pv[4*g+1]);
                P2[2*g+1] = cvt_pk(pv[4*g+2], pv[4*g+3]);
            }
            #pragma unroll
            for (int u = 0; u < 2; ++u) {
                unsigned a0 = P2[4*u + 0], b0 = P2[4*u + 2];
                unsigned a1 = P2[4*u + 1], b1 = P2[4*u + 3];
                asm("v_permlane32_swap_b32 %0, %1" : "+v"(a0), "+v"(b0));
                asm("v_permlane32_swap_b32 %0, %1" : "+v"(a1), "+v"(b1));
                FragU bfv;
                bfv.u[0] = a0; bfv.u[1] = a1; bfv.u[2] = b0; bfv.u[3] = b1;
                #pragma unroll
                for (int dt = 0; dt < 2; ++dt)
                    acc[dt] = __builtin_amdgcn_mfma_f32_32x32x16_bf16(
                        VA[dt][u].f, bfv.f, acc[dt], 0, 0, 0);
            }
        }

        if (kt8 < 7) {
            writeTile(cur ^ 1, kc, vc, ktc);
            __syncthreads();
        }
    }

    // ---- finalize: l, lse, register-only epilogue ----
    const float lt = lacc + __shfl_xor(lacc, 32);
    const float invl = (lt > 0.f) ? 1.0f / lt : 0.0f;
    if (hi == 0) {
        const float lse = (lt > 0.f) ? (mnat + logf(lt)) : -5.0e4f;
        lse_hash[(size_t)(bh * NHASH + h) * TT + q_t] = lse;
    }
    unsigned wa[8], wb[8];
    #pragma unroll
    for (int m = 0; m < 8; ++m) {
        wa[m] = pkrtz(acc[0][2*m] * invl, acc[0][2*m+1] * invl);
        wb[m] = pkrtz(acc[1][2*m] * invl, acc[1][2*m+1] * invl);
    }
    #pragma unroll
    for (int m = 0; m < 8; ++m)
        asm("v_permlane32_swap_b32 %0, %1" : "+v"(wa[m]), "+v"(wb[m]));
    __half* orow = o_hash + ((size_t)(bh * NHASH + h) * TT + q_t) * DHH + hi * 32;
    if (lt > 0.f) {
        #pragma unroll
        for (int g = 0; g < 4; ++g) {
            uint4 o;
            o.x = wa[2*g]; o.y = wa[2*g+1];
            o.z = wb[2*g]; o.w = wb[2*g+1];
            ((uint4*)orow)[g] = o;
        }
    } else {
        const u16* vr = v + vbase + (size_t)q_t * DD + hi * 32;
        #pragma unroll
        for (int g = 0; g < 4; ++g) {
            uint4 o;
            o.x = pkrtz(b2f(vr[8*g+0]), b2f(vr[8*g+1]));
            o.y = pkrtz(b2f(vr[8*g+2]), b2f(vr[8*g+3]));
            o.z = pkrtz(b2f(vr[8*g+4]), b2f(vr[8*g+5]));
            o.w = pkrtz(b2f(vr[8*g+6]), b2f(vr[8*g+7]));
            ((uint4*)orow)[g] = o;
        }
    }
}

// ---------------------------------------------------------------------------
// Combine hash rounds — VECTORIZED (G13): 8 channels/thread via uint4 f16
// loads; per-channel math identical to scalar version (bit-exact output).
// grid 2048 x 256.
__global__ __launch_bounds__(256)
void combine_kernel(const __half* __restrict__ o_hash, const float* __restrict__ lse_hash,
                    u16* __restrict__ am)
{
    const int gt = blockIdx.x * 256 + threadIdx.x;
    const int row = gt >> 3;               // bh*T + t
    const int seg = (gt & 7) * 8;          // channel start
    const int bh = row >> 9, t = row & 511;
    const int b = bh >> 3, head = bh & 7;
    const float ls0 = lse_hash[(size_t)(bh * NHASH + 0) * TT + t];
    const float ls1 = lse_hash[(size_t)(bh * NHASH + 1) * TT + t];
    const float ls2 = lse_hash[(size_t)(bh * NHASH + 2) * TT + t];
    const float ls3 = lse_hash[(size_t)(bh * NHASH + 3) * TT + t];
    const float M = fmaxf(fmaxf(ls0, ls1), fmaxf(ls2, ls3));
    const float e0 = __expf(ls0 - M), e1 = __expf(ls1 - M);
    const float e2 = __expf(ls2 - M), e3 = __expf(ls3 - M);
    const float inv = 1.0f / (e0 + e1 + e2 + e3);
    const size_t base = (size_t)(bh * NHASH) * TT * DHH + (size_t)t * DHH + seg;
    const uint4 r0 = *(const uint4*)((const u16*)o_hash + base);
    const uint4 r1 = *(const uint4*)((const u16*)o_hash + base + (size_t)TT * DHH);
    const uint4 r2 = *(const uint4*)((const u16*)o_hash + base + (size_t)2 * TT * DHH);
    const uint4 r3 = *(const uint4*)((const u16*)o_hash + base + (size_t)3 * TT * DHH);
    const unsigned w0[4] = {r0.x, r0.y, r0.z, r0.w};
    const unsigned w1[4] = {r1.x, r1.y, r1.z, r1.w};
    const unsigned w2[4] = {r2.x, r2.y, r2.z, r2.w};
    const unsigned w3[4] = {r3.x, r3.y, r3.z, r3.w};
    unsigned outw[4];
    #pragma unroll
    for (int j = 0; j < 4; ++j) {
        const float alo = (e0 * h2f((u16)(w0[j] & 0xffff)) +
                           e1 * h2f((u16)(w1[j] & 0xffff)) +
                           e2 * h2f((u16)(w2[j] & 0xffff)) +
                           e3 * h2f((u16)(w3[j] & 0xffff))) * inv;
        const float ahi = (e0 * h2f((u16)(w0[j] >> 16)) +
                           e1 * h2f((u16)(w1[j] >> 16)) +
                           e2 * h2f((u16)(w2[j] >> 16)) +
                           e3 * h2f((u16)(w3[j] >> 16))) * inv;
        outw[j] = (unsigned)bf16_1(alo) | ((unsigned)bf16_1(ahi) << 16);
    }
    uint4 ov; ov.x = outw[0]; ov.y = outw[1]; ov.z = outw[2]; ov.w = outw[3];
    *(uint4*)(am + ((size_t)(b * TT + t)) * DD + head * DHH + seg) = ov;
}

// ---------------------------------------------------------------------------
// Final head
__device__ __forceinline__ float block_sum256(float v, volatile float* red)
{
    const int lane = threadIdx.x & 63, wid = threadIdx.x >> 6;
    #pragma unroll
    for (int o = 1; o < 64; o <<= 1) v += __shfl_xor(v, o);
    __syncthreads();
    if (lane == 0) red[wid] = v;
    __syncthreads();
    return red[0] + red[1] + red[2] + red[3];
}

__global__ __launch_bounds__(256)
void head_kernel(const float* __restrict__ x1, const float* __restrict__ x2,
                 const float* __restrict__ lnfg, const float* __restrict__ lnfb,
                 const float* __restrict__ hw1, const float* __restrict__ hb1,
                 const float* __restrict__ hlng, const float* __restrict__ hlnb,
                 const float* __restrict__ hw2, const float* __restrict__ hb2,
                 float* __restrict__ out)
{
    __shared__ float nrow[512];
    __shared__ float red[4];
    const int b = blockIdx.x, tid = threadIdx.x;
    const size_t roff = ((size_t)b * TT + (TT - 1)) * DD;
    const float v0 = 0.5f * (x1[roff + tid] + x2[roff + tid]);
    const float v1 = 0.5f * (x1[roff + 256 + tid] + x2[roff + 256 + tid]);
    const float mean = block_sum256(v0 + v1, red) * (1.0f / 512.0f);
    const float d0 = v0 - mean, d1 = v1 - mean;
    const float var = block_sum256(d0 * d0 + d1 * d1, red) * (1.0f / 512.0f);
    const float rstd = rsqrtf(var + 1e-5f);
    nrow[tid]       = d0 * rstd * lnfg[tid] + lnfb[tid];
    nrow[tid + 256] = d1 * rstd * lnfg[tid + 256] + lnfb[tid + 256];
    __syncthreads();
    float a = hb1[tid];
    for (int k = 0; k < 512; ++k) a = fmaf(nrow[k], hw1[(size_t)k * 256 + tid], a);
    const float m2 = block_sum256(a, red) * (1.0f / 256.0f);
    const float dd = a - m2;
    const float var2 = block_sum256(dd * dd, red) * (1.0f / 256.0f);
    float y = dd * rsqrtf(var2 + 1e-5f) * hlng[tid] + hlnb[tid];
    y = fmaxf(y, 0.0f);
    const float osum = block_sum256(y * hw2[tid], red);
    if (tid == 0) out[b] = osum + hb2[0];
}

// ---------------------------------------------------------------------------
extern "C" void kernel_launch(void* const* d_in, const int* in_sizes, int n_in,
                              void* d_out, int out_size, void* d_ws, size_t ws_size,
                              hipStream_t stream)
{
    (void)in_sizes; (void)n_in; (void)out_size; (void)ws_size;
    const float* x    = (const float*)d_in[0];
    const float* embw = (const float*)d_in[1];
    const float* embb = (const float*)d_in[2];
    const float* pos  = (const float*)d_in[3];
    const float* ln1g = (const float*)d_in[4];
    const float* ln1b = (const float*)d_in[5];
    const float* wqk  = (const float*)d_in[6];
    const float* wv   = (const float*)d_in[7];
    const float* wo   = (const float*)d_in[8];
    const float* wob  = (const float*)d_in[9];
    const float* ln2g = (const float*)d_in[10];
    const float* ln2b = (const float*)d_in[11];
    const float* ffw1 = (const float*)d_in[12];
    const float* ffb1 = (const float*)d_in[13];
    const float* ffw2 = (const float*)d_in[14];
    const float* ffb2 = (const float*)d_in[15];
    const float* rot  = (const float*)d_in[16];
    const float* lnfg = (const float*)d_in[17];
    const float* lnfb = (const float*)d_in[18];
    const float* hw1  = (const float*)d_in[19];
    const float* hb1  = (const float*)d_in[20];
    const float* hlng = (const float*)d_in[21];
    const float* hlnb = (const float*)d_in[22];
    const float* hw2  = (const float*)d_in[23];
    const float* hb2  = (const float*)d_in[24];
    float* out = (float*)d_out;

    const size_t SZ_BTD = (size_t)BB * TT * DD;            // 4,194,304
    const size_t SZ_OH  = (size_t)BHH * NHASH * TT * DHH;  // 16,777,216

    char* p = (char*)d_ws;
    float* x1b = (float*)p;  p += SZ_BTD * 4;
    float* x2b = (float*)p;  p += SZ_BTD * 4;
    float* xnb = (float*)p;  p += SZ_BTD * 4;              // also amb (bf16) late
    u16*   vbh = (u16*)p;    p += SZ_BTD * 2;
    u16*   xnbh = (u16*)p;   p += SZ_BTD * 2;
    u16*   qkh  = (u16*)p;   p += SZ_BTD * 2;              // bf16 qk, per-head layout
    u16*   qknb = (u16*)p;   p += (size_t)BHH * TT * DHH * 2;
    float* qnrm = (float*)p; p += (size_t)BHH * TT * 4;
    float* rotated = (float*)p; p += (size_t)BB * TT * 32 * 4;
    __half* ohash = (__half*)p;                  // 33.5MB region
    u16*    ffmid = (u16*)p;                     // temporal alias (disjoint life)
    p += SZ_OH * 2;
    float* lseb  = (float*)p; p += (size_t)BHH * NHASH * TT * 4;
    int*   stb   = (int*)p;   p += (size_t)BHH * NHASH * TT * 4;
    u16* wqkvT = (u16*)p; p += (size_t)NLAYER * 1024 * 512 * 2;
    u16* woT   = (u16*)p; p += (size_t)NLAYER * DD * DD * 2;
    u16* w1T   = (u16*)p; p += (size_t)NLAYER * DD * FFD * 2;
    u16* w2T   = (u16*)p; p += (size_t)NLAYER * FFD * DD * 2;
    float* wrotAll = (float*)p; p += (size_t)NLAYER * DD * 32 * 4;
    u16* amb = (u16*)xnb;                        // alias (xnb dead after GEMMs)

    // ---- one-time weight prep (all layers) ----
    prep_weights<<<11264, 256, 0, stream>>>(wqk, wv, wo, ffw1, ffw2,
                                            wqkvT, woT, w1T, w2T);
    wrot_kernel<<<dim3(32, NLAYER), 256, 0, stream>>>(wqk, rot, wrotAll);

    embed_kernel<<<BB * TT, 256, 0, stream>>>(x, embw, embb, pos, x1b, x2b);

    for (int L = 0; L < NLAYER; ++L) {
        const size_t w512 = (size_t)L * DD * DD;
        const size_t wff  = (size_t)L * DD * FFD;

        // x1 += attn(ln(x2))
        ln_kernel<false><<<2048, 256, 0, stream>>>(x2b, ln1g + L * DD, ln1b + L * DD, xnb, xnbh);
        rot_gemm<<<128, 256, 0, stream>>>(xnb, wrotAll + (size_t)L * DD * 32, rotated);
        gemm_bf16<128, 128, 32, false, false, false, false, true><<<dim3(64, 8), 256, 0, stream>>>(
            xnbh, wqkvT + (size_t)L * 1024 * 512, nullptr, nullptr,
            (float*)vbh, qkh, BB * TT, 1024, DD);
        knorm_bucket<<<2560, 512, 0, stream>>>(qkh, rotated, qknb, qnrm, stb);
        lsh_attn_mfma<<<1024, 512, 0, stream>>>(
            qknb, vbh, qnrm, stb, ohash, lseb);
        combine_kernel<<<2048, 256, 0, stream>>>(ohash, lseb, amb);
        gemm_bf16<128, 64, 64, false, true, true, false, false><<<dim3(64, 8), 256, 0, stream>>>(
            amb, woT + w512, wob + L * DD, x1b, x1b, nullptr, BB * TT, DD, DD);

        // x2 += ff(ln(x1))
        ln_kernel<true><<<2048, 256, 0, stream>>>(x1b, ln2g + L * DD, ln2b + L * DD, nullptr, xnbh);
        gemm_bf16<128, 128, 32, true, false, true, true, false><<<dim3(64, 16), 256, 0, stream>>>(
            xnbh, w1T + wff, ffb1 + L * FFD, nullptr, nullptr, ffmid, BB * TT, FFD, DD);
        gemm_bf16<128, 64, 64, false, true, true, false, false><<<dim3(64, 8), 256, 0, stream>>>(
            ffmid, w2T + wff, ffb2 + L * DD, x2b, x2b, nullptr, BB * TT, DD, FFD);
    }

    head_kernel<<<16, 256, 0, stream>>>(x1b, x2b, lnfg, lnfb, hw1, hb1,
                                        hlng, hlnb, hw2, hb2, out);
}